// Round 1
// baseline (1230.553 us; speedup 1.0000x reference)
//
#include <hip/hip_runtime.h>
#include <hip/hip_bf16.h>
#include <stdint.h>

#define N 100000
#define E_ 1600000
#define D 128
#define C_ 256
#define HID 64
#define KSEL 80000
#define NB 4096
#define CHUNK 1024
#define NCHUNK ((N + CHUNK - 1) / CHUNK)   // 98

// ---- ordered-float encoding (monotonic increasing uint) ----
__device__ __forceinline__ unsigned enc_f(float f) {
  unsigned b = __float_as_uint(f);
  return (b & 0x80000000u) ? ~b : (b | 0x80000000u);
}
__device__ __forceinline__ float dec_f(unsigned u) {
  unsigned b = (u & 0x80000000u) ? (u ^ 0x80000000u) : ~u;
  return __uint_as_float(b);
}

// ======================= cluster CSR + means =======================
__global__ __launch_bounds__(256) void k_hist_cluster(const int* __restrict__ cid, int* __restrict__ ccount) {
  int n = blockIdx.x * 256 + threadIdx.x;
  if (n < N) atomicAdd(&ccount[cid[n]], 1);
}

__global__ __launch_bounds__(1024) void k_scan_small(const int* __restrict__ in, int* __restrict__ out, int n) {
  __shared__ int sums[1024];
  int t = threadIdx.x;
  int per = (n + 1023) / 1024;
  int base = t * per;
  int loc = 0;
  for (int k = 0; k < per; ++k) { int i = base + k; if (i < n) loc += in[i]; }
  sums[t] = loc; __syncthreads();
  for (int off = 1; off < 1024; off <<= 1) {
    int v = (t >= off) ? sums[t - off] : 0;
    __syncthreads();
    sums[t] += v;
    __syncthreads();
  }
  int run = (t == 0) ? 0 : sums[t - 1];
  for (int k = 0; k < per; ++k) { int i = base + k; if (i < n) { out[i] = run; run += in[i]; } }
}

__global__ __launch_bounds__(256) void k_scatter_cluster(const int* __restrict__ cid, const int* __restrict__ cstart,
                                                         int* __restrict__ ccur, int* __restrict__ cslot) {
  int n = blockIdx.x * 256 + threadIdx.x;
  if (n < N) {
    int c = cid[n];
    int p = cstart[c] + atomicAdd(&ccur[c], 1);
    cslot[p] = n;
  }
}

__global__ __launch_bounds__(128) void k_cluster_mean(const float* __restrict__ x, const int* __restrict__ cstart,
                                                      const int* __restrict__ ccount, const int* __restrict__ cslot,
                                                      float* __restrict__ Hc) {
  int c = blockIdx.x;
  int d = threadIdx.x;
  int st = cstart[c], cnt = ccount[c];
  float s = 0.f;
  for (int k = 0; k < cnt; ++k) {
    int n = cslot[st + k];
    s += x[(size_t)n * D + d];
  }
  Hc[c * D + d] = s / (float)(cnt > 0 ? cnt : 1);
}

__global__ __launch_bounds__(64) void k_gdot(const float* __restrict__ Hc, const float* __restrict__ wb,
                                             float* __restrict__ gdot) {
  int c = blockIdx.x; int l = threadIdx.x;
  float v = Hc[c * D + l] * wb[l] + Hc[c * D + 64 + l] * wb[64 + l];
  for (int off = 32; off; off >>= 1) v += __shfl_down(v, off);
  if (l == 0) gdot[c] = v;
}

__global__ __launch_bounds__(128) void k_S(const float* __restrict__ Hc, float* __restrict__ S) {
  int d = threadIdx.x;
  float s = 0.f;
  for (int c = 0; c < C_; ++c) s += Hc[c * D + d];
  S[d] = s;
}

// block 0 -> SW = S @ tw ; blocks 1..C_ -> HW[b-1] = Hc[b-1] @ tw
__global__ __launch_bounds__(128) void k_SW_HW(const float* __restrict__ S, const float* __restrict__ Hc,
                                               const float* __restrict__ tw, float* __restrict__ SW,
                                               float* __restrict__ HW) {
  int c = threadIdx.x;
  int b = blockIdx.x;
  const float* src = (b == 0) ? S : (Hc + (size_t)(b - 1) * D);
  float acc = 0.f;
  for (int d = 0; d < D; ++d) acc = fmaf(src[d], tw[d * D + c], acc);
  if (b == 0) SW[c] = acc; else HW[(size_t)(b - 1) * D + c] = acc;
}

// ======================= feature score (MLP) =======================
__global__ __launch_bounds__(256) void k_feat_score(const float* __restrict__ x, const float* __restrict__ w1,
                                                    const float* __restrict__ b1, const float* __restrict__ w2,
                                                    const float* __restrict__ b2, float* __restrict__ scoreF) {
  __shared__ float w1ld[D * HID];
  __shared__ float xld[16 * D];
  __shared__ float w2ld[HID];
  __shared__ float b1ld[HID];
  int tid = threadIdx.x;
  for (int i = tid; i < D * HID / 4; i += 256) ((float4*)w1ld)[i] = ((const float4*)w1)[i];
  if (tid < HID) { w2ld[tid] = w2[tid]; b1ld[tid] = b1[tid]; }
  int nb = blockIdx.x * 16;
  for (int i = tid; i < 16 * D / 4; i += 256)
    ((float4*)xld)[i] = ((const float4*)(x + (size_t)nb * D))[i];
  __syncthreads();
  int lane = tid & 63, wv = tid >> 6;
  float a0, a1, a2, a3;
  a0 = a1 = a2 = a3 = b1ld[lane];
  const float* xr = xld + wv * 4 * D;
  for (int d = 0; d < D; ++d) {
    float w = w1ld[d * HID + lane];
    a0 = fmaf(xr[d], w, a0);
    a1 = fmaf(xr[D + d], w, a1);
    a2 = fmaf(xr[2 * D + d], w, a2);
    a3 = fmaf(xr[3 * D + d], w, a3);
  }
  float wv2 = w2ld[lane];
  float s0 = fmaxf(a0, 0.f) * wv2, s1 = fmaxf(a1, 0.f) * wv2;
  float s2 = fmaxf(a2, 0.f) * wv2, s3 = fmaxf(a3, 0.f) * wv2;
  for (int off = 32; off; off >>= 1) {
    s0 += __shfl_down(s0, off); s1 += __shfl_down(s1, off);
    s2 += __shfl_down(s2, off); s3 += __shfl_down(s3, off);
  }
  if (lane == 0) {
    float bb = b2[0];
    int n0 = nb + wv * 4;
    scoreF[n0] = s0 + bb; scoreF[n0 + 1] = s1 + bb;
    scoreF[n0 + 2] = s2 + bb; scoreF[n0 + 3] = s3 + bb;
  }
}

// ======================= GAT score =======================
__global__ __launch_bounds__(256) void k_gat_h(const float* __restrict__ x, const float* __restrict__ gw,
                                               const float* __restrict__ wa, float* __restrict__ hg,
                                               float* __restrict__ aDot) {
  int tid = threadIdx.x; int lane = tid & 63, wv = tid >> 6;
  int n = blockIdx.x * 4 + wv;
  const float* xr = x + (size_t)n * D;
  float x0 = xr[lane], x1 = xr[64 + lane];
  float hp = x0 * gw[lane] + x1 * gw[64 + lane];
  float ap = x0 * wa[lane] + x1 * wa[64 + lane];
  for (int off = 32; off; off >>= 1) { hp += __shfl_down(hp, off); ap += __shfl_down(ap, off); }
  if (lane == 0) { hg[n] = hp; aDot[n] = ap; }
}

__global__ __launch_bounds__(256) void k_edge_e(const int* __restrict__ ei, const float* __restrict__ hg,
                                                const float* __restrict__ asrc, const float* __restrict__ adst,
                                                float* __restrict__ earr, unsigned* __restrict__ menc) {
  int e = blockIdx.x * 256 + threadIdx.x;
  if (e >= E_) return;
  int s = ei[e], d2 = ei[E_ + e];
  float z = asrc[0] * hg[s] + adst[0] * hg[d2];
  float ev = (z > 0.f) ? z : 0.2f * z;
  earr[e] = ev;
  atomicMax(&menc[d2], enc_f(ev));
}

__global__ __launch_bounds__(256) void k_edge_soft(const int* __restrict__ ei, const float* __restrict__ hg,
                                                   const float* __restrict__ earr, const unsigned* __restrict__ menc,
                                                   float* __restrict__ den, float* __restrict__ num) {
  int e = blockIdx.x * 256 + threadIdx.x;
  if (e >= E_) return;
  int s = ei[e], d2 = ei[E_ + e];
  float ex = expf(earr[e] - dec_f(menc[d2]));
  atomicAdd(&den[d2], ex);
  atomicAdd(&num[d2], ex * hg[s]);
}

__global__ __launch_bounds__(256) void k_local_score(const float* __restrict__ num, const float* __restrict__ den,
                                                     const float* __restrict__ gb, float* __restrict__ scoreL) {
  int n = blockIdx.x * 256 + threadIdx.x;
  if (n < N) scoreL[n] = num[n] / fmaxf(den[n], 1e-16f) + gb[0];
}

// ======================= exact top-k ranking =======================
__global__ __launch_bounds__(256) void k_minmax(const float* __restrict__ sc, unsigned* __restrict__ mm) {
  __shared__ unsigned smx[256], smn[256];
  int t = threadIdx.x; int n = blockIdx.x * 256 + t;
  unsigned v = (n < N) ? enc_f(sc[n]) : 0u;
  smx[t] = (n < N) ? v : 0u;
  smn[t] = (n < N) ? v : 0xFFFFFFFFu;
  __syncthreads();
  for (int off = 128; off; off >>= 1) {
    if (t < off) {
      smx[t] = max(smx[t], smx[t + off]);
      smn[t] = min(smn[t], smn[t + off]);
    }
    __syncthreads();
  }
  if (t == 0) { atomicMax(&mm[0], smx[0]); atomicMin(&mm[1], smn[0]); }
}

__global__ __launch_bounds__(256) void k_bucket_hist(const float* __restrict__ sc, const unsigned* __restrict__ mm,
                                                     int* __restrict__ bucket, int* __restrict__ hist) {
  int n = blockIdx.x * 256 + threadIdx.x;
  if (n >= N) return;
  float smax = dec_f(mm[0]), smin = dec_f(mm[1]);
  float range = smax - smin;
  float scale = (range > 0.f) ? ((float)NB / range) : 0.f;
  float t = (smax - sc[n]) * scale;
  int b = (int)t;
  b = b < 0 ? 0 : (b > NB - 1 ? NB - 1 : b);
  bucket[n] = b;
  atomicAdd(&hist[b], 1);
}

__global__ __launch_bounds__(256) void k_bucket_scatter(const int* __restrict__ bucket, const int* __restrict__ start,
                                                        int* __restrict__ cur, int* __restrict__ slot) {
  int n = blockIdx.x * 256 + threadIdx.x;
  if (n >= N) return;
  int b = bucket[n];
  slot[start[b] + atomicAdd(&cur[b], 1)] = n;
}

__global__ __launch_bounds__(256) void k_bucket_rank(const float* __restrict__ sc, const int* __restrict__ bucket,
                                                     const int* __restrict__ start, const int* __restrict__ hist,
                                                     const int* __restrict__ slot, int* __restrict__ rank,
                                                     int* __restrict__ sorted) {
  int n = blockIdx.x * 256 + threadIdx.x;
  if (n >= N) return;
  int b = bucket[n];
  int st = start[b], cnt = hist[b];
  unsigned long long mykey = (((unsigned long long)(~enc_f(sc[n]))) << 32) | (unsigned)n;
  int r = 0;
  for (int j = 0; j < cnt; ++j) {
    int m = slot[st + j];
    unsigned long long k = (((unsigned long long)(~enc_f(sc[m]))) << 32) | (unsigned)m;
    r += (k < mykey) ? 1 : 0;
  }
  rank[n] = st + r;
  sorted[st + r] = n;
}

// ======================= union mapping =======================
__global__ __launch_bounds__(1024) void k_union_chunksum(const int* __restrict__ rankF, const int* __restrict__ rankL,
                                                         int* __restrict__ csum) {
  __shared__ int red[1024];
  int t = threadIdx.x; int i = blockIdx.x * 1024 + t;
  int u = (i < N) ? (((rankF[i] < KSEL) || (rankL[i] < KSEL)) ? 1 : 0) : 0;
  red[t] = u; __syncthreads();
  for (int off = 512; off; off >>= 1) { if (t < off) red[t] += red[t + off]; __syncthreads(); }
  if (t == 0) csum[blockIdx.x] = red[0];
}

__global__ __launch_bounds__(1024) void k_union_map(const int* __restrict__ rankF, const int* __restrict__ rankL,
                                                    const int* __restrict__ cstart, const int* __restrict__ batch,
                                                    int* __restrict__ mapping, float* __restrict__ outBatch) {
  __shared__ int sums[1024];
  int t = threadIdx.x; int i = blockIdx.x * 1024 + t;
  int u = (i < N) ? (((rankF[i] < KSEL) || (rankL[i] < KSEL)) ? 1 : 0) : 0;
  sums[t] = u; __syncthreads();
  for (int off = 1; off < 1024; off <<= 1) {
    int v = (t >= off) ? sums[t - off] : 0;
    __syncthreads();
    sums[t] += v;
    __syncthreads();
  }
  if (i < N) {
    mapping[i] = u ? (cstart[blockIdx.x] + sums[t] - 1) : -1;
    outBatch[i] = u ? (float)batch[i] : -1.0f;
  }
}

__global__ __launch_bounds__(256) void k_edge_out(const int* __restrict__ ei, const int* __restrict__ mapping,
                                                  float* __restrict__ outE) {
  int e = blockIdx.x * 256 + threadIdx.x;
  if (e >= E_) return;
  int m0 = mapping[ei[e]], m1 = mapping[ei[E_ + e]];
  bool valid = (m0 >= 0) && (m1 >= 0);
  outE[e] = valid ? (float)m0 : -1.f;
  outE[E_ + e] = valid ? (float)m1 : -1.f;
}

// ======================= fused GCN transform + scatter =======================
// Fp[tgtL[i]] += relu( x[srcL[i]] @ tw + tb + q*SW + (p-q)*HW[cid[srcL[i]]] )
__global__ __launch_bounds__(256) void k_fuse(const float* __restrict__ x, const float* __restrict__ tw,
                                              const float* __restrict__ tb, const float* __restrict__ SW,
                                              const float* __restrict__ HW, const float* __restrict__ gdot,
                                              const float* __restrict__ aDot, const int* __restrict__ cid,
                                              const int* __restrict__ srcL, const int* __restrict__ tgtL,
                                              const float* __restrict__ attb, float* __restrict__ Fp) {
  __shared__ float xld[16 * D];
  __shared__ float pql[16 * 2];
  __shared__ int meta[16 * 2];  // [r][0]=cid(src), [r][1]=tgt
  int tid = threadIdx.x;
  int g = tid >> 7, c = tid & 127;
  float ab0 = attb[0];
  float tbc = tb[c];
  float swc = SW[c];
  int iters = KSEL / 16;
  for (int it = blockIdx.x; it < iters; it += gridDim.x) {
    int base = it * 16;
    __syncthreads();  // protect LDS from previous iteration readers
    if (tid < 16) {
      int ws = srcL[base + tid];
      int cc = cid[ws];
      meta[tid * 2] = cc;
      meta[tid * 2 + 1] = tgtL[base + tid];
      float s = aDot[ws] + gdot[cc] + ab0;
      float mx = fmaxf(s, 0.f);
      float esm = expf(s - mx), eom = expf(-mx);
      float dn = esm + 255.f * eom;
      pql[tid * 2] = esm / dn;
      pql[tid * 2 + 1] = eom / dn;
    }
    // stage 16 x-rows (512 float4, 2 per thread)
    {
      int i0 = tid * 2;
#pragma unroll
      for (int k = 0; k < 2; ++k) {
        int i = i0 + k;
        int r = i >> 5;
        int off = i & 31;
        int ws = srcL[base + r];
        ((float4*)xld)[r * 32 + off] = ((const float4*)(x + (size_t)ws * D))[off];
      }
    }
    __syncthreads();
    float acc[8];
#pragma unroll
    for (int r = 0; r < 8; ++r) acc[r] = 0.f;
    const float* xb = xld + g * 8 * D;
    for (int d4 = 0; d4 < D; d4 += 4) {
      float4 xv[8];
#pragma unroll
      for (int r = 0; r < 8; ++r) xv[r] = *(const float4*)(xb + r * D + d4);
#pragma unroll
      for (int dd = 0; dd < 4; ++dd) {
        float w = tw[(d4 + dd) * D + c];
#pragma unroll
        for (int r = 0; r < 8; ++r) {
          float xs = (dd == 0) ? xv[r].x : (dd == 1) ? xv[r].y : (dd == 2) ? xv[r].z : xv[r].w;
          acc[r] = fmaf(xs, w, acc[r]);
        }
      }
    }
#pragma unroll
    for (int r = 0; r < 8; ++r) {
      int row = g * 8 + r;
      float p = pql[row * 2], q = pql[row * 2 + 1];
      int cc = meta[row * 2];
      int tgt = meta[row * 2 + 1];
      float o = acc[r] + tbc + q * swc + (p - q) * HW[(size_t)cc * D + c];
      o = fmaxf(o, 0.f);
      Fp[(size_t)tgt * D + c] += o;
    }
  }
}

__global__ __launch_bounds__(256) void k_half(const int* __restrict__ rankF, const int* __restrict__ rankL,
                                              float* __restrict__ Fp) {
  int i = blockIdx.x * 256 + threadIdx.x;  // over N*D
  int n = i >> 7;
  if ((rankF[n] < KSEL) && (rankL[n] < KSEL)) Fp[i] *= 0.5f;
}

// ======================= launcher =======================
extern "C" void kernel_launch(void* const* d_in, const int* in_sizes, int n_in,
                              void* d_out, int out_size, void* d_ws, size_t ws_size,
                              hipStream_t stream) {
  const float* x   = (const float*)d_in[0];
  const int* ei    = (const int*)d_in[1];
  const int* batch = (const int*)d_in[2];
  const int* cid   = (const int*)d_in[3];
  const float* w1  = (const float*)d_in[4];
  const float* b1  = (const float*)d_in[5];
  const float* w2  = (const float*)d_in[6];
  const float* b2  = (const float*)d_in[7];
  const float* gw  = (const float*)d_in[8];
  const float* gas = (const float*)d_in[9];
  const float* gad = (const float*)d_in[10];
  const float* gb  = (const float*)d_in[11];
  const float* wa  = (const float*)d_in[12];
  const float* wb  = (const float*)d_in[13];
  const float* ab  = (const float*)d_in[14];
  const float* tw  = (const float*)d_in[15];
  const float* tb  = (const float*)d_in[16];
  (void)in_sizes; (void)n_in; (void)ws_size;

  char* p = (char*)d_ws;
  auto alloc = [&](size_t bytes) -> char* {
    char* r = p;
    p += (bytes + 255) & ~(size_t)255;
    return r;
  };
  // ---- zero-init region (memset below covers up to zeroBytes) ----
  int* ccount    = (int*)alloc(C_ * 4);
  int* ccur      = (int*)alloc(C_ * 4);
  unsigned* menc = (unsigned*)alloc((size_t)N * 4);
  float* den     = (float*)alloc((size_t)N * 4);
  float* num     = (float*)alloc((size_t)N * 4);
  unsigned* mmF  = (unsigned*)alloc(16);
  unsigned* mmL  = (unsigned*)alloc(16);
  int* histF     = (int*)alloc(NB * 4);
  int* histL     = (int*)alloc(NB * 4);
  int* curF      = (int*)alloc(NB * 4);
  int* curL      = (int*)alloc(NB * 4);
  size_t zeroBytes = (size_t)(p - (char*)d_ws);
  // ---- rest (fully written before read) ----
  int* cstart   = (int*)alloc(C_ * 4);
  int* cslot    = (int*)alloc((size_t)N * 4);
  float* Hc     = (float*)alloc((size_t)C_ * D * 4);
  float* gdot   = (float*)alloc(C_ * 4);
  float* S      = (float*)alloc(D * 4);
  float* SW     = (float*)alloc(D * 4);
  float* HW     = (float*)alloc((size_t)C_ * D * 4);
  float* scoreF = (float*)alloc((size_t)N * 4);
  float* scoreL = (float*)alloc((size_t)N * 4);
  float* hg     = (float*)alloc((size_t)N * 4);
  float* aDot   = (float*)alloc((size_t)N * 4);
  float* earr   = (float*)alloc((size_t)E_ * 4);
  int* bucketF  = (int*)alloc((size_t)N * 4);
  int* bucketL  = (int*)alloc((size_t)N * 4);
  int* startF   = (int*)alloc(NB * 4);
  int* startL   = (int*)alloc(NB * 4);
  int* slotF    = (int*)alloc((size_t)N * 4);
  int* slotL    = (int*)alloc((size_t)N * 4);
  int* sortedF  = (int*)alloc((size_t)N * 4);
  int* sortedL  = (int*)alloc((size_t)N * 4);
  int* rankF    = (int*)alloc((size_t)N * 4);
  int* rankL    = (int*)alloc((size_t)N * 4);
  int* csums    = (int*)alloc(NCHUNK * 4);
  int* cstarts  = (int*)alloc(NCHUNK * 4);
  int* mapping  = (int*)alloc((size_t)N * 4);

  float* outF = (float*)d_out;             // [N, D]
  float* outE = outF + (size_t)N * D;      // [2, E]
  float* outB = outE + (size_t)2 * E_;     // [N]

  hipMemsetAsync(d_ws, 0, zeroBytes, stream);
  hipMemsetAsync(d_out, 0, (size_t)out_size * sizeof(float), stream);
  hipMemsetAsync(mmF + 1, 0xFF, 4, stream);  // min slot -> 0xFFFFFFFF
  hipMemsetAsync(mmL + 1, 0xFF, 4, stream);

  // cluster means + derived
  k_hist_cluster<<<(N + 255) / 256, 256, 0, stream>>>(cid, ccount);
  k_scan_small<<<1, 1024, 0, stream>>>(ccount, cstart, C_);
  k_scatter_cluster<<<(N + 255) / 256, 256, 0, stream>>>(cid, cstart, ccur, cslot);
  k_cluster_mean<<<C_, 128, 0, stream>>>(x, cstart, ccount, cslot, Hc);
  k_gdot<<<C_, 64, 0, stream>>>(Hc, wb, gdot);
  k_S<<<1, 128, 0, stream>>>(Hc, S);
  k_SW_HW<<<C_ + 1, 128, 0, stream>>>(S, Hc, tw, SW, HW);

  // scores
  k_feat_score<<<N / 16, 256, 0, stream>>>(x, w1, b1, w2, b2, scoreF);
  k_gat_h<<<N / 4, 256, 0, stream>>>(x, gw, wa, hg, aDot);
  k_edge_e<<<(E_ + 255) / 256, 256, 0, stream>>>(ei, hg, gas, gad, earr, menc);
  k_edge_soft<<<(E_ + 255) / 256, 256, 0, stream>>>(ei, hg, earr, menc, den, num);
  k_local_score<<<(N + 255) / 256, 256, 0, stream>>>(num, den, gb, scoreL);

  // exact ranking, feature view
  k_minmax<<<(N + 255) / 256, 256, 0, stream>>>(scoreF, mmF);
  k_bucket_hist<<<(N + 255) / 256, 256, 0, stream>>>(scoreF, mmF, bucketF, histF);
  k_scan_small<<<1, 1024, 0, stream>>>(histF, startF, NB);
  k_bucket_scatter<<<(N + 255) / 256, 256, 0, stream>>>(bucketF, startF, curF, slotF);
  k_bucket_rank<<<(N + 255) / 256, 256, 0, stream>>>(scoreF, bucketF, startF, histF, slotF, rankF, sortedF);
  // exact ranking, local view
  k_minmax<<<(N + 255) / 256, 256, 0, stream>>>(scoreL, mmL);
  k_bucket_hist<<<(N + 255) / 256, 256, 0, stream>>>(scoreL, mmL, bucketL, histL);
  k_scan_small<<<1, 1024, 0, stream>>>(histL, startL, NB);
  k_bucket_scatter<<<(N + 255) / 256, 256, 0, stream>>>(bucketL, startL, curL, slotL);
  k_bucket_rank<<<(N + 255) / 256, 256, 0, stream>>>(scoreL, bucketL, startL, histL, slotL, rankL, sortedL);

  // union mapping + edge remap + batch
  k_union_chunksum<<<NCHUNK, 1024, 0, stream>>>(rankF, rankL, csums);
  k_scan_small<<<1, 1024, 0, stream>>>(csums, cstarts, NCHUNK);
  k_union_map<<<NCHUNK, 1024, 0, stream>>>(rankF, rankL, cstarts, batch, mapping, outB);
  k_edge_out<<<(E_ + 255) / 256, 256, 0, stream>>>(ei, mapping, outE);

  // fused features: A[feat_idx[i]] = fuse2[i] (src=local), B[local_idx[i]] = fuse1[i] (src=feat)
  k_fuse<<<1280, 256, 0, stream>>>(x, tw, tb, SW, HW, gdot, aDot, cid, sortedL, sortedF, ab, outF);
  k_fuse<<<1280, 256, 0, stream>>>(x, tw, tb, SW, HW, gdot, aDot, cid, sortedF, sortedL, ab, outF);
  k_half<<<(N * D) / 256, 256, 0, stream>>>(rankF, rankL, outF);
}

// Round 2
// 1079.804 us; speedup vs baseline: 1.1396x; 1.1396x over previous
//
#include <hip/hip_runtime.h>
#include <hip/hip_bf16.h>
#include <stdint.h>

#define N 100000
#define E_ 1600000
#define D 128
#define C_ 256
#define HID 64
#define KSEL 80000
#define NB 4096
#define CHUNK 1024
#define NCHUNK ((N + CHUNK - 1) / CHUNK)   // 98
#define CSEG 32                            // segments per cluster for mean reduction

// ---- ordered-float encoding (monotonic increasing uint) ----
__device__ __forceinline__ unsigned enc_f(float f) {
  unsigned b = __float_as_uint(f);
  return (b & 0x80000000u) ? ~b : (b | 0x80000000u);
}
__device__ __forceinline__ float dec_f(unsigned u) {
  unsigned b = (u & 0x80000000u) ? (u ^ 0x80000000u) : ~u;
  return __uint_as_float(b);
}

// ======================= cluster CSR + means =======================
__global__ __launch_bounds__(256) void k_hist_cluster(const int* __restrict__ cid, int* __restrict__ ccount) {
  int n = blockIdx.x * 256 + threadIdx.x;
  if (n < N) atomicAdd(&ccount[cid[n]], 1);
}

__global__ __launch_bounds__(1024) void k_scan_small(const int* __restrict__ in, int* __restrict__ out, int n) {
  __shared__ int sums[1024];
  int t = threadIdx.x;
  int per = (n + 1023) / 1024;
  int base = t * per;
  int loc = 0;
  for (int k = 0; k < per; ++k) { int i = base + k; if (i < n) loc += in[i]; }
  sums[t] = loc; __syncthreads();
  for (int off = 1; off < 1024; off <<= 1) {
    int v = (t >= off) ? sums[t - off] : 0;
    __syncthreads();
    sums[t] += v;
    __syncthreads();
  }
  int run = (t == 0) ? 0 : sums[t - 1];
  for (int k = 0; k < per; ++k) { int i = base + k; if (i < n) { out[i] = run; run += in[i]; } }
}

__global__ __launch_bounds__(256) void k_scatter_cluster(const int* __restrict__ cid, const int* __restrict__ cstart,
                                                         int* __restrict__ ccur, int* __restrict__ cslot) {
  int n = blockIdx.x * 256 + threadIdx.x;
  if (n < N) {
    int c = cid[n];
    int p = cstart[c] + atomicAdd(&ccur[c], 1);
    cslot[p] = n;
  }
}

// Parallel cluster mean: CSEG segment-blocks per cluster accumulate partial
// sums in registers, then one float atomicAdd per (c,d) into zeroed Hc.
// 8192 blocks -> full occupancy vs the old 256-block serial loop (189us, 5% occ).
__global__ __launch_bounds__(128) void k_cluster_partial(const float* __restrict__ x, const int* __restrict__ cstart,
                                                         const int* __restrict__ ccount, const int* __restrict__ cslot,
                                                         float* __restrict__ Hc) {
  int c = blockIdx.x >> 5;
  int s = blockIdx.x & (CSEG - 1);
  int d = threadIdx.x;
  int st = cstart[c], cnt = ccount[c];
  int seg = (cnt + CSEG - 1) / CSEG;
  int lo = s * seg;
  int hi = min(cnt, lo + seg);
  if (lo >= hi) return;
  float acc = 0.f;
  int k = lo;
  for (; k + 2 <= hi; k += 2) {            // 2-deep to overlap gather latency
    int n0 = cslot[st + k], n1 = cslot[st + k + 1];
    float v0 = x[(size_t)n0 * D + d];
    float v1 = x[(size_t)n1 * D + d];
    acc += v0 + v1;
  }
  if (k < hi) acc += x[(size_t)cslot[st + k] * D + d];
  atomicAdd(&Hc[(size_t)c * D + d], acc);
}

__global__ __launch_bounds__(256) void k_mean_div(const int* __restrict__ ccount, float* __restrict__ Hc) {
  int i = blockIdx.x * 256 + threadIdx.x;  // over C_*D
  int c = i >> 7;
  Hc[i] /= (float)max(ccount[c], 1);
}

__global__ __launch_bounds__(64) void k_gdot(const float* __restrict__ Hc, const float* __restrict__ wb,
                                             float* __restrict__ gdot) {
  int c = blockIdx.x; int l = threadIdx.x;
  float v = Hc[c * D + l] * wb[l] + Hc[c * D + 64 + l] * wb[64 + l];
  for (int off = 32; off; off >>= 1) v += __shfl_down(v, off);
  if (l == 0) gdot[c] = v;
}

__global__ __launch_bounds__(128) void k_S(const float* __restrict__ Hc, float* __restrict__ S) {
  int d = threadIdx.x;
  float s = 0.f;
  for (int c = 0; c < C_; ++c) s += Hc[c * D + d];
  S[d] = s;
}

// block 0 -> SW = S @ tw ; blocks 1..C_ -> HW[b-1] = Hc[b-1] @ tw
__global__ __launch_bounds__(128) void k_SW_HW(const float* __restrict__ S, const float* __restrict__ Hc,
                                               const float* __restrict__ tw, float* __restrict__ SW,
                                               float* __restrict__ HW) {
  int c = threadIdx.x;
  int b = blockIdx.x;
  const float* src = (b == 0) ? S : (Hc + (size_t)(b - 1) * D);
  float acc = 0.f;
  for (int d = 0; d < D; ++d) acc = fmaf(src[d], tw[d * D + c], acc);
  if (b == 0) SW[c] = acc; else HW[(size_t)(b - 1) * D + c] = acc;
}

// ======================= feature score (MLP) =======================
__global__ __launch_bounds__(256) void k_feat_score(const float* __restrict__ x, const float* __restrict__ w1,
                                                    const float* __restrict__ b1, const float* __restrict__ w2,
                                                    const float* __restrict__ b2, float* __restrict__ scoreF) {
  __shared__ float w1ld[D * HID];
  __shared__ float xld[16 * D];
  __shared__ float w2ld[HID];
  __shared__ float b1ld[HID];
  int tid = threadIdx.x;
  for (int i = tid; i < D * HID / 4; i += 256) ((float4*)w1ld)[i] = ((const float4*)w1)[i];
  if (tid < HID) { w2ld[tid] = w2[tid]; b1ld[tid] = b1[tid]; }
  int nb = blockIdx.x * 16;
  for (int i = tid; i < 16 * D / 4; i += 256)
    ((float4*)xld)[i] = ((const float4*)(x + (size_t)nb * D))[i];
  __syncthreads();
  int lane = tid & 63, wv = tid >> 6;
  float a0, a1, a2, a3;
  a0 = a1 = a2 = a3 = b1ld[lane];
  const float* xr = xld + wv * 4 * D;
  for (int d = 0; d < D; ++d) {
    float w = w1ld[d * HID + lane];
    a0 = fmaf(xr[d], w, a0);
    a1 = fmaf(xr[D + d], w, a1);
    a2 = fmaf(xr[2 * D + d], w, a2);
    a3 = fmaf(xr[3 * D + d], w, a3);
  }
  float wv2 = w2ld[lane];
  float s0 = fmaxf(a0, 0.f) * wv2, s1 = fmaxf(a1, 0.f) * wv2;
  float s2 = fmaxf(a2, 0.f) * wv2, s3 = fmaxf(a3, 0.f) * wv2;
  for (int off = 32; off; off >>= 1) {
    s0 += __shfl_down(s0, off); s1 += __shfl_down(s1, off);
    s2 += __shfl_down(s2, off); s3 += __shfl_down(s3, off);
  }
  if (lane == 0) {
    float bb = b2[0];
    int n0 = nb + wv * 4;
    scoreF[n0] = s0 + bb; scoreF[n0 + 1] = s1 + bb;
    scoreF[n0 + 2] = s2 + bb; scoreF[n0 + 3] = s3 + bb;
  }
}

// ======================= GAT score =======================
__global__ __launch_bounds__(256) void k_gat_h(const float* __restrict__ x, const float* __restrict__ gw,
                                               const float* __restrict__ wa, float* __restrict__ hg,
                                               float* __restrict__ aDot) {
  int tid = threadIdx.x; int lane = tid & 63, wv = tid >> 6;
  int n = blockIdx.x * 4 + wv;
  const float* xr = x + (size_t)n * D;
  float x0 = xr[lane], x1 = xr[64 + lane];
  float hp = x0 * gw[lane] + x1 * gw[64 + lane];
  float ap = x0 * wa[lane] + x1 * wa[64 + lane];
  for (int off = 32; off; off >>= 1) { hp += __shfl_down(hp, off); ap += __shfl_down(ap, off); }
  if (lane == 0) { hg[n] = hp; aDot[n] = ap; }
}

__global__ __launch_bounds__(256) void k_edge_e(const int* __restrict__ ei, const float* __restrict__ hg,
                                                const float* __restrict__ asrc, const float* __restrict__ adst,
                                                float* __restrict__ earr, unsigned* __restrict__ menc) {
  int e = blockIdx.x * 256 + threadIdx.x;
  if (e >= E_) return;
  int s = ei[e], d2 = ei[E_ + e];
  float z = asrc[0] * hg[s] + adst[0] * hg[d2];
  float ev = (z > 0.f) ? z : 0.2f * z;
  earr[e] = ev;
  atomicMax(&menc[d2], enc_f(ev));
}

__global__ __launch_bounds__(256) void k_edge_soft(const int* __restrict__ ei, const float* __restrict__ hg,
                                                   const float* __restrict__ earr, const unsigned* __restrict__ menc,
                                                   float* __restrict__ den, float* __restrict__ num) {
  int e = blockIdx.x * 256 + threadIdx.x;
  if (e >= E_) return;
  int s = ei[e], d2 = ei[E_ + e];
  float ex = expf(earr[e] - dec_f(menc[d2]));
  atomicAdd(&den[d2], ex);
  atomicAdd(&num[d2], ex * hg[s]);
}

__global__ __launch_bounds__(256) void k_local_score(const float* __restrict__ num, const float* __restrict__ den,
                                                     const float* __restrict__ gb, float* __restrict__ scoreL) {
  int n = blockIdx.x * 256 + threadIdx.x;
  if (n < N) scoreL[n] = num[n] / fmaxf(den[n], 1e-16f) + gb[0];
}

// ======================= exact top-k ranking =======================
__global__ __launch_bounds__(256) void k_minmax(const float* __restrict__ sc, unsigned* __restrict__ mm) {
  __shared__ unsigned smx[256], smn[256];
  int t = threadIdx.x; int n = blockIdx.x * 256 + t;
  unsigned v = (n < N) ? enc_f(sc[n]) : 0u;
  smx[t] = (n < N) ? v : 0u;
  smn[t] = (n < N) ? v : 0xFFFFFFFFu;
  __syncthreads();
  for (int off = 128; off; off >>= 1) {
    if (t < off) {
      smx[t] = max(smx[t], smx[t + off]);
      smn[t] = min(smn[t], smn[t + off]);
    }
    __syncthreads();
  }
  if (t == 0) { atomicMax(&mm[0], smx[0]); atomicMin(&mm[1], smn[0]); }
}

__global__ __launch_bounds__(256) void k_bucket_hist(const float* __restrict__ sc, const unsigned* __restrict__ mm,
                                                     int* __restrict__ bucket, int* __restrict__ hist) {
  int n = blockIdx.x * 256 + threadIdx.x;
  if (n >= N) return;
  float smax = dec_f(mm[0]), smin = dec_f(mm[1]);
  float range = smax - smin;
  float scale = (range > 0.f) ? ((float)NB / range) : 0.f;
  float t = (smax - sc[n]) * scale;
  int b = (int)t;
  b = b < 0 ? 0 : (b > NB - 1 ? NB - 1 : b);
  bucket[n] = b;
  atomicAdd(&hist[b], 1);
}

__global__ __launch_bounds__(256) void k_bucket_scatter(const int* __restrict__ bucket, const int* __restrict__ start,
                                                        int* __restrict__ cur, int* __restrict__ slot) {
  int n = blockIdx.x * 256 + threadIdx.x;
  if (n >= N) return;
  int b = bucket[n];
  slot[start[b] + atomicAdd(&cur[b], 1)] = n;
}

__global__ __launch_bounds__(256) void k_bucket_rank(const float* __restrict__ sc, const int* __restrict__ bucket,
                                                     const int* __restrict__ start, const int* __restrict__ hist,
                                                     const int* __restrict__ slot, int* __restrict__ rank,
                                                     int* __restrict__ sorted) {
  int n = blockIdx.x * 256 + threadIdx.x;
  if (n >= N) return;
  int b = bucket[n];
  int st = start[b], cnt = hist[b];
  unsigned long long mykey = (((unsigned long long)(~enc_f(sc[n]))) << 32) | (unsigned)n;
  int r = 0;
  for (int j = 0; j < cnt; ++j) {
    int m = slot[st + j];
    unsigned long long k = (((unsigned long long)(~enc_f(sc[m]))) << 32) | (unsigned)m;
    r += (k < mykey) ? 1 : 0;
  }
  rank[n] = st + r;
  sorted[st + r] = n;
}

// ======================= union mapping =======================
__global__ __launch_bounds__(1024) void k_union_chunksum(const int* __restrict__ rankF, const int* __restrict__ rankL,
                                                         int* __restrict__ csum) {
  __shared__ int red[1024];
  int t = threadIdx.x; int i = blockIdx.x * 1024 + t;
  int u = (i < N) ? (((rankF[i] < KSEL) || (rankL[i] < KSEL)) ? 1 : 0) : 0;
  red[t] = u; __syncthreads();
  for (int off = 512; off; off >>= 1) { if (t < off) red[t] += red[t + off]; __syncthreads(); }
  if (t == 0) csum[blockIdx.x] = red[0];
}

__global__ __launch_bounds__(1024) void k_union_map(const int* __restrict__ rankF, const int* __restrict__ rankL,
                                                    const int* __restrict__ cstart, const int* __restrict__ batch,
                                                    int* __restrict__ mapping, float* __restrict__ outBatch) {
  __shared__ int sums[1024];
  int t = threadIdx.x; int i = blockIdx.x * 1024 + t;
  int u = (i < N) ? (((rankF[i] < KSEL) || (rankL[i] < KSEL)) ? 1 : 0) : 0;
  sums[t] = u; __syncthreads();
  for (int off = 1; off < 1024; off <<= 1) {
    int v = (t >= off) ? sums[t - off] : 0;
    __syncthreads();
    sums[t] += v;
    __syncthreads();
  }
  if (i < N) {
    mapping[i] = u ? (cstart[blockIdx.x] + sums[t] - 1) : -1;
    outBatch[i] = u ? (float)batch[i] : -1.0f;
  }
}

__global__ __launch_bounds__(256) void k_edge_out(const int* __restrict__ ei, const int* __restrict__ mapping,
                                                  float* __restrict__ outE) {
  int e = blockIdx.x * 256 + threadIdx.x;
  if (e >= E_) return;
  int m0 = mapping[ei[e]], m1 = mapping[ei[E_ + e]];
  bool valid = (m0 >= 0) && (m1 >= 0);
  outE[e] = valid ? (float)m0 : -1.f;
  outE[E_ + e] = valid ? (float)m1 : -1.f;
}

// ======================= fused GCN transform + scatter =======================
// Fp[tgtL[i]] += relu( x[srcL[i]] @ tw + tb + q*SW + (p-q)*HW[cid[srcL[i]]] )
__global__ __launch_bounds__(256) void k_fuse(const float* __restrict__ x, const float* __restrict__ tw,
                                              const float* __restrict__ tb, const float* __restrict__ SW,
                                              const float* __restrict__ HW, const float* __restrict__ gdot,
                                              const float* __restrict__ aDot, const int* __restrict__ cid,
                                              const int* __restrict__ srcL, const int* __restrict__ tgtL,
                                              const float* __restrict__ attb, float* __restrict__ Fp) {
  __shared__ float xld[16 * D];
  __shared__ float pql[16 * 2];
  __shared__ int meta[16 * 2];  // [r][0]=cid(src), [r][1]=tgt
  int tid = threadIdx.x;
  int g = tid >> 7, c = tid & 127;
  float ab0 = attb[0];
  float tbc = tb[c];
  float swc = SW[c];
  int iters = KSEL / 16;
  for (int it = blockIdx.x; it < iters; it += gridDim.x) {
    int base = it * 16;
    __syncthreads();  // protect LDS from previous iteration readers
    if (tid < 16) {
      int ws = srcL[base + tid];
      int cc = cid[ws];
      meta[tid * 2] = cc;
      meta[tid * 2 + 1] = tgtL[base + tid];
      float s = aDot[ws] + gdot[cc] + ab0;
      float mx = fmaxf(s, 0.f);
      float esm = expf(s - mx), eom = expf(-mx);
      float dn = esm + 255.f * eom;
      pql[tid * 2] = esm / dn;
      pql[tid * 2 + 1] = eom / dn;
    }
    // stage 16 x-rows (512 float4, 2 per thread)
    {
      int i0 = tid * 2;
#pragma unroll
      for (int k = 0; k < 2; ++k) {
        int i = i0 + k;
        int r = i >> 5;
        int off = i & 31;
        int ws = srcL[base + r];
        ((float4*)xld)[r * 32 + off] = ((const float4*)(x + (size_t)ws * D))[off];
      }
    }
    __syncthreads();
    float acc[8];
#pragma unroll
    for (int r = 0; r < 8; ++r) acc[r] = 0.f;
    const float* xb = xld + g * 8 * D;
    for (int d4 = 0; d4 < D; d4 += 4) {
      float4 xv[8];
#pragma unroll
      for (int r = 0; r < 8; ++r) xv[r] = *(const float4*)(xb + r * D + d4);
#pragma unroll
      for (int dd = 0; dd < 4; ++dd) {
        float w = tw[(d4 + dd) * D + c];
#pragma unroll
        for (int r = 0; r < 8; ++r) {
          float xs = (dd == 0) ? xv[r].x : (dd == 1) ? xv[r].y : (dd == 2) ? xv[r].z : xv[r].w;
          acc[r] = fmaf(xs, w, acc[r]);
        }
      }
    }
#pragma unroll
    for (int r = 0; r < 8; ++r) {
      int row = g * 8 + r;
      float p = pql[row * 2], q = pql[row * 2 + 1];
      int cc = meta[row * 2];
      int tgt = meta[row * 2 + 1];
      float o = acc[r] + tbc + q * swc + (p - q) * HW[(size_t)cc * D + c];
      o = fmaxf(o, 0.f);
      Fp[(size_t)tgt * D + c] += o;
    }
  }
}

__global__ __launch_bounds__(256) void k_half(const int* __restrict__ rankF, const int* __restrict__ rankL,
                                              float* __restrict__ Fp) {
  int i = blockIdx.x * 256 + threadIdx.x;  // over N*D
  int n = i >> 7;
  if ((rankF[n] < KSEL) && (rankL[n] < KSEL)) Fp[i] *= 0.5f;
}

// ======================= launcher =======================
extern "C" void kernel_launch(void* const* d_in, const int* in_sizes, int n_in,
                              void* d_out, int out_size, void* d_ws, size_t ws_size,
                              hipStream_t stream) {
  const float* x   = (const float*)d_in[0];
  const int* ei    = (const int*)d_in[1];
  const int* batch = (const int*)d_in[2];
  const int* cid   = (const int*)d_in[3];
  const float* w1  = (const float*)d_in[4];
  const float* b1  = (const float*)d_in[5];
  const float* w2  = (const float*)d_in[6];
  const float* b2  = (const float*)d_in[7];
  const float* gw  = (const float*)d_in[8];
  const float* gas = (const float*)d_in[9];
  const float* gad = (const float*)d_in[10];
  const float* gb  = (const float*)d_in[11];
  const float* wa  = (const float*)d_in[12];
  const float* wb  = (const float*)d_in[13];
  const float* ab  = (const float*)d_in[14];
  const float* tw  = (const float*)d_in[15];
  const float* tb  = (const float*)d_in[16];
  (void)in_sizes; (void)n_in; (void)ws_size;

  char* p = (char*)d_ws;
  auto alloc = [&](size_t bytes) -> char* {
    char* r = p;
    p += (bytes + 255) & ~(size_t)255;
    return r;
  };
  // ---- zero-init region (memset below covers up to zeroBytes) ----
  int* ccount    = (int*)alloc(C_ * 4);
  int* ccur      = (int*)alloc(C_ * 4);
  unsigned* menc = (unsigned*)alloc((size_t)N * 4);
  float* den     = (float*)alloc((size_t)N * 4);
  float* num     = (float*)alloc((size_t)N * 4);
  unsigned* mmF  = (unsigned*)alloc(16);
  unsigned* mmL  = (unsigned*)alloc(16);
  int* histF     = (int*)alloc(NB * 4);
  int* histL     = (int*)alloc(NB * 4);
  int* curF      = (int*)alloc(NB * 4);
  int* curL      = (int*)alloc(NB * 4);
  float* Hc      = (float*)alloc((size_t)C_ * D * 4);   // atomic accumulator -> must be zeroed
  size_t zeroBytes = (size_t)(p - (char*)d_ws);
  // ---- rest (fully written before read) ----
  int* cstart   = (int*)alloc(C_ * 4);
  int* cslot    = (int*)alloc((size_t)N * 4);
  float* gdot   = (float*)alloc(C_ * 4);
  float* S      = (float*)alloc(D * 4);
  float* SW     = (float*)alloc(D * 4);
  float* HW     = (float*)alloc((size_t)C_ * D * 4);
  float* scoreF = (float*)alloc((size_t)N * 4);
  float* scoreL = (float*)alloc((size_t)N * 4);
  float* hg     = (float*)alloc((size_t)N * 4);
  float* aDot   = (float*)alloc((size_t)N * 4);
  float* earr   = (float*)alloc((size_t)E_ * 4);
  int* bucketF  = (int*)alloc((size_t)N * 4);
  int* bucketL  = (int*)alloc((size_t)N * 4);
  int* startF   = (int*)alloc(NB * 4);
  int* startL   = (int*)alloc(NB * 4);
  int* slotF    = (int*)alloc((size_t)N * 4);
  int* slotL    = (int*)alloc((size_t)N * 4);
  int* sortedF  = (int*)alloc((size_t)N * 4);
  int* sortedL  = (int*)alloc((size_t)N * 4);
  int* rankF    = (int*)alloc((size_t)N * 4);
  int* rankL    = (int*)alloc((size_t)N * 4);
  int* csums    = (int*)alloc(NCHUNK * 4);
  int* cstarts  = (int*)alloc(NCHUNK * 4);
  int* mapping  = (int*)alloc((size_t)N * 4);

  float* outF = (float*)d_out;             // [N, D]
  float* outE = outF + (size_t)N * D;      // [2, E]
  float* outB = outE + (size_t)2 * E_;     // [N]

  hipMemsetAsync(d_ws, 0, zeroBytes, stream);
  hipMemsetAsync(d_out, 0, (size_t)out_size * sizeof(float), stream);
  hipMemsetAsync(mmF + 1, 0xFF, 4, stream);  // min slot -> 0xFFFFFFFF
  hipMemsetAsync(mmL + 1, 0xFF, 4, stream);

  // cluster means + derived
  k_hist_cluster<<<(N + 255) / 256, 256, 0, stream>>>(cid, ccount);
  k_scan_small<<<1, 1024, 0, stream>>>(ccount, cstart, C_);
  k_scatter_cluster<<<(N + 255) / 256, 256, 0, stream>>>(cid, cstart, ccur, cslot);
  k_cluster_partial<<<C_ * CSEG, 128, 0, stream>>>(x, cstart, ccount, cslot, Hc);
  k_mean_div<<<(C_ * D) / 256, 256, 0, stream>>>(ccount, Hc);
  k_gdot<<<C_, 64, 0, stream>>>(Hc, wb, gdot);
  k_S<<<1, 128, 0, stream>>>(Hc, S);
  k_SW_HW<<<C_ + 1, 128, 0, stream>>>(S, Hc, tw, SW, HW);

  // scores
  k_feat_score<<<N / 16, 256, 0, stream>>>(x, w1, b1, w2, b2, scoreF);
  k_gat_h<<<N / 4, 256, 0, stream>>>(x, gw, wa, hg, aDot);
  k_edge_e<<<(E_ + 255) / 256, 256, 0, stream>>>(ei, hg, gas, gad, earr, menc);
  k_edge_soft<<<(E_ + 255) / 256, 256, 0, stream>>>(ei, hg, earr, menc, den, num);
  k_local_score<<<(N + 255) / 256, 256, 0, stream>>>(num, den, gb, scoreL);

  // exact ranking, feature view
  k_minmax<<<(N + 255) / 256, 256, 0, stream>>>(scoreF, mmF);
  k_bucket_hist<<<(N + 255) / 256, 256, 0, stream>>>(scoreF, mmF, bucketF, histF);
  k_scan_small<<<1, 1024, 0, stream>>>(histF, startF, NB);
  k_bucket_scatter<<<(N + 255) / 256, 256, 0, stream>>>(bucketF, startF, curF, slotF);
  k_bucket_rank<<<(N + 255) / 256, 256, 0, stream>>>(scoreF, bucketF, startF, histF, slotF, rankF, sortedF);
  // exact ranking, local view
  k_minmax<<<(N + 255) / 256, 256, 0, stream>>>(scoreL, mmL);
  k_bucket_hist<<<(N + 255) / 256, 256, 0, stream>>>(scoreL, mmL, bucketL, histL);
  k_scan_small<<<1, 1024, 0, stream>>>(histL, startL, NB);
  k_bucket_scatter<<<(N + 255) / 256, 256, 0, stream>>>(bucketL, startL, curL, slotL);
  k_bucket_rank<<<(N + 255) / 256, 256, 0, stream>>>(scoreL, bucketL, startL, histL, slotL, rankL, sortedL);

  // union mapping + edge remap + batch
  k_union_chunksum<<<NCHUNK, 1024, 0, stream>>>(rankF, rankL, csums);
  k_scan_small<<<1, 1024, 0, stream>>>(csums, cstarts, NCHUNK);
  k_union_map<<<NCHUNK, 1024, 0, stream>>>(rankF, rankL, cstarts, batch, mapping, outB);
  k_edge_out<<<(E_ + 255) / 256, 256, 0, stream>>>(ei, mapping, outE);

  // fused features: A[feat_idx[i]] = fuse2[i] (src=local), B[local_idx[i]] = fuse1[i] (src=feat)
  k_fuse<<<1280, 256, 0, stream>>>(x, tw, tb, SW, HW, gdot, aDot, cid, sortedL, sortedF, ab, outF);
  k_fuse<<<1280, 256, 0, stream>>>(x, tw, tb, SW, HW, gdot, aDot, cid, sortedF, sortedL, ab, outF);
  k_half<<<(N * D) / 256, 256, 0, stream>>>(rankF, rankL, outF);
}

// Round 3
// 899.319 us; speedup vs baseline: 1.3683x; 1.2007x over previous
//
#include <hip/hip_runtime.h>
#include <hip/hip_bf16.h>
#include <stdint.h>

#define N 100000
#define E_ 1600000
#define D 128
#define C_ 256
#define HID 64
#define KSEL 80000
#define NB 4096
#define CHUNK 1024
#define NCHUNK ((N + CHUNK - 1) / CHUNK)   // 98
#define CSEG 32                            // segments per cluster for mean reduction
#define NBK 782                            // ceil(N/128) dst-buckets of 128 nodes
#define BCAP 2560                          // per-bucket capacity (avg 2046 + >11 sigma)

// ---- ordered-float encoding (monotonic increasing uint) ----
__device__ __forceinline__ unsigned enc_f(float f) {
  unsigned b = __float_as_uint(f);
  return (b & 0x80000000u) ? ~b : (b | 0x80000000u);
}
__device__ __forceinline__ float dec_f(unsigned u) {
  unsigned b = (u & 0x80000000u) ? (u ^ 0x80000000u) : ~u;
  return __uint_as_float(b);
}

// ======================= cluster CSR + means =======================
__global__ __launch_bounds__(256) void k_hist_cluster(const int* __restrict__ cid, int* __restrict__ ccount) {
  int n = blockIdx.x * 256 + threadIdx.x;
  if (n < N) atomicAdd(&ccount[cid[n]], 1);
}

__global__ __launch_bounds__(1024) void k_scan_small(const int* __restrict__ in, int* __restrict__ out, int n) {
  __shared__ int sums[1024];
  int t = threadIdx.x;
  int per = (n + 1023) / 1024;
  int base = t * per;
  int loc = 0;
  for (int k = 0; k < per; ++k) { int i = base + k; if (i < n) loc += in[i]; }
  sums[t] = loc; __syncthreads();
  for (int off = 1; off < 1024; off <<= 1) {
    int v = (t >= off) ? sums[t - off] : 0;
    __syncthreads();
    sums[t] += v;
    __syncthreads();
  }
  int run = (t == 0) ? 0 : sums[t - 1];
  for (int k = 0; k < per; ++k) { int i = base + k; if (i < n) { out[i] = run; run += in[i]; } }
}

__global__ __launch_bounds__(256) void k_scatter_cluster(const int* __restrict__ cid, const int* __restrict__ cstart,
                                                         int* __restrict__ ccur, int* __restrict__ cslot) {
  int n = blockIdx.x * 256 + threadIdx.x;
  if (n < N) {
    int c = cid[n];
    int p = cstart[c] + atomicAdd(&ccur[c], 1);
    cslot[p] = n;
  }
}

// Parallel cluster mean: CSEG segment-blocks per cluster -> register partials
// -> one float atomicAdd per (c,d) into zeroed Hc.
__global__ __launch_bounds__(128) void k_cluster_partial(const float* __restrict__ x, const int* __restrict__ cstart,
                                                         const int* __restrict__ ccount, const int* __restrict__ cslot,
                                                         float* __restrict__ Hc) {
  int c = blockIdx.x >> 5;
  int s = blockIdx.x & (CSEG - 1);
  int d = threadIdx.x;
  int st = cstart[c], cnt = ccount[c];
  int seg = (cnt + CSEG - 1) / CSEG;
  int lo = s * seg;
  int hi = min(cnt, lo + seg);
  if (lo >= hi) return;
  float acc = 0.f;
  int k = lo;
  for (; k + 2 <= hi; k += 2) {
    int n0 = cslot[st + k], n1 = cslot[st + k + 1];
    float v0 = x[(size_t)n0 * D + d];
    float v1 = x[(size_t)n1 * D + d];
    acc += v0 + v1;
  }
  if (k < hi) acc += x[(size_t)cslot[st + k] * D + d];
  atomicAdd(&Hc[(size_t)c * D + d], acc);
}

__global__ __launch_bounds__(256) void k_mean_div(const int* __restrict__ ccount, float* __restrict__ Hc) {
  int i = blockIdx.x * 256 + threadIdx.x;  // over C_*D
  int c = i >> 7;
  Hc[i] /= (float)max(ccount[c], 1);
}

__global__ __launch_bounds__(64) void k_gdot(const float* __restrict__ Hc, const float* __restrict__ wb,
                                             float* __restrict__ gdot) {
  int c = blockIdx.x; int l = threadIdx.x;
  float v = Hc[c * D + l] * wb[l] + Hc[c * D + 64 + l] * wb[64 + l];
  for (int off = 32; off; off >>= 1) v += __shfl_down(v, off);
  if (l == 0) gdot[c] = v;
}

__global__ __launch_bounds__(128) void k_S(const float* __restrict__ Hc, float* __restrict__ S) {
  int d = threadIdx.x;
  float s = 0.f;
  for (int c = 0; c < C_; ++c) s += Hc[c * D + d];
  S[d] = s;
}

// block 0 -> SW = S @ tw ; blocks 1..C_ -> HW[b-1] = Hc[b-1] @ tw
__global__ __launch_bounds__(128) void k_SW_HW(const float* __restrict__ S, const float* __restrict__ Hc,
                                               const float* __restrict__ tw, float* __restrict__ SW,
                                               float* __restrict__ HW) {
  int c = threadIdx.x;
  int b = blockIdx.x;
  const float* src = (b == 0) ? S : (Hc + (size_t)(b - 1) * D);
  float acc = 0.f;
  for (int d = 0; d < D; ++d) acc = fmaf(src[d], tw[d * D + c], acc);
  if (b == 0) SW[c] = acc; else HW[(size_t)(b - 1) * D + c] = acc;
}

// ======================= feature score (MLP) =======================
__global__ __launch_bounds__(256) void k_feat_score(const float* __restrict__ x, const float* __restrict__ w1,
                                                    const float* __restrict__ b1, const float* __restrict__ w2,
                                                    const float* __restrict__ b2, float* __restrict__ scoreF) {
  __shared__ float w1ld[D * HID];
  __shared__ float xld[16 * D];
  __shared__ float w2ld[HID];
  __shared__ float b1ld[HID];
  int tid = threadIdx.x;
  for (int i = tid; i < D * HID / 4; i += 256) ((float4*)w1ld)[i] = ((const float4*)w1)[i];
  if (tid < HID) { w2ld[tid] = w2[tid]; b1ld[tid] = b1[tid]; }
  int nb = blockIdx.x * 16;
  for (int i = tid; i < 16 * D / 4; i += 256)
    ((float4*)xld)[i] = ((const float4*)(x + (size_t)nb * D))[i];
  __syncthreads();
  int lane = tid & 63, wv = tid >> 6;
  float a0, a1, a2, a3;
  a0 = a1 = a2 = a3 = b1ld[lane];
  const float* xr = xld + wv * 4 * D;
  for (int d = 0; d < D; ++d) {
    float w = w1ld[d * HID + lane];
    a0 = fmaf(xr[d], w, a0);
    a1 = fmaf(xr[D + d], w, a1);
    a2 = fmaf(xr[2 * D + d], w, a2);
    a3 = fmaf(xr[3 * D + d], w, a3);
  }
  float wv2 = w2ld[lane];
  float s0 = fmaxf(a0, 0.f) * wv2, s1 = fmaxf(a1, 0.f) * wv2;
  float s2 = fmaxf(a2, 0.f) * wv2, s3 = fmaxf(a3, 0.f) * wv2;
  for (int off = 32; off; off >>= 1) {
    s0 += __shfl_down(s0, off); s1 += __shfl_down(s1, off);
    s2 += __shfl_down(s2, off); s3 += __shfl_down(s3, off);
  }
  if (lane == 0) {
    float bb = b2[0];
    int n0 = nb + wv * 4;
    scoreF[n0] = s0 + bb; scoreF[n0 + 1] = s1 + bb;
    scoreF[n0 + 2] = s2 + bb; scoreF[n0 + 3] = s3 + bb;
  }
}

// ======================= GAT score =======================
__global__ __launch_bounds__(256) void k_gat_h(const float* __restrict__ x, const float* __restrict__ gw,
                                               const float* __restrict__ wa, float* __restrict__ hg,
                                               float* __restrict__ aDot) {
  int tid = threadIdx.x; int lane = tid & 63, wv = tid >> 6;
  int n = blockIdx.x * 4 + wv;
  const float* xr = x + (size_t)n * D;
  float x0 = xr[lane], x1 = xr[64 + lane];
  float hp = x0 * gw[lane] + x1 * gw[64 + lane];
  float ap = x0 * wa[lane] + x1 * wa[64 + lane];
  for (int off = 32; off; off >>= 1) { hp += __shfl_down(hp, off); ap += __shfl_down(ap, off); }
  if (lane == 0) { hg[n] = hp; aDot[n] = ap; }
}

// Bucket edges by dst>>7 into fixed-CAP regions. LDS-aggregated reservation:
// ~150k global atomics total instead of 4.8M (which write through at 32B each).
// Record: .x = bits(e), .y = src | (dstloc << 24).
__global__ __launch_bounds__(1024) void k_escatter(const int* __restrict__ ei, const float* __restrict__ hg,
                                                   const float* __restrict__ asrc, const float* __restrict__ adst,
                                                   int* __restrict__ gcnt, uint2* __restrict__ payload) {
  __shared__ int lcnt[NBK];
  __shared__ int lbase[NBK];
  int tid = threadIdx.x;
  for (int i = tid; i < NBK; i += 1024) lcnt[i] = 0;
  int e0 = blockIdx.x * 8192;
  int es[8], ed[8];
#pragma unroll
  for (int k = 0; k < 8; ++k) {
    int e = e0 + k * 1024 + tid;
    bool v = (e < E_);
    es[k] = v ? ei[e] : -1;
    ed[k] = v ? ei[E_ + e] : -1;
  }
  __syncthreads();
#pragma unroll
  for (int k = 0; k < 8; ++k)
    if (ed[k] >= 0) atomicAdd(&lcnt[ed[k] >> 7], 1);
  __syncthreads();
  for (int i = tid; i < NBK; i += 1024) {
    int c = lcnt[i];
    lbase[i] = c ? atomicAdd(&gcnt[i], c) : 0;
    lcnt[i] = 0;
  }
  __syncthreads();
  float as = asrc[0], ad = adst[0];
#pragma unroll
  for (int k = 0; k < 8; ++k) {
    if (ed[k] < 0) continue;
    int s = es[k], d = ed[k];
    int b = d >> 7, dl = d & 127;
    float z = as * hg[s] + ad * hg[d];
    float ev = (z > 0.f) ? z : 0.2f * z;
    int pos = lbase[b] + atomicAdd(&lcnt[b], 1);
    if (pos < BCAP) {
      uint2 rec;
      rec.x = __float_as_uint(ev);
      rec.y = (unsigned)s | ((unsigned)dl << 24);
      payload[(size_t)b * BCAP + pos] = rec;
    }
  }
}

// Per-bucket GAT softmax entirely in LDS: max -> den -> alpha*h; writes scoreL.
__global__ __launch_bounds__(256) void k_esoftmax(const uint2* __restrict__ payload, const int* __restrict__ gcnt,
                                                  const float* __restrict__ hg, const float* __restrict__ gb,
                                                  float* __restrict__ scoreL) {
  __shared__ unsigned mS[128];
  __shared__ float dS[128];
  __shared__ float nS[128];
  int b = blockIdx.x;
  int tid = threadIdx.x;
  if (tid < 128) { mS[tid] = 0u; dS[tid] = 0.f; nS[tid] = 0.f; }
  __syncthreads();
  int cnt = min(gcnt[b], BCAP);
  const uint2* bp = payload + (size_t)b * BCAP;
  for (int i = tid; i < cnt; i += 256) {
    uint2 r = bp[i];
    atomicMax(&mS[r.y >> 24], enc_f(__uint_as_float(r.x)));
  }
  __syncthreads();
  for (int i = tid; i < cnt; i += 256) {
    uint2 r = bp[i];
    int d = r.y >> 24;
    float ex = expf(__uint_as_float(r.x) - dec_f(mS[d]));
    atomicAdd(&dS[d], ex);
  }
  __syncthreads();
  for (int i = tid; i < cnt; i += 256) {
    uint2 r = bp[i];
    int d = r.y >> 24;
    float ex = expf(__uint_as_float(r.x) - dec_f(mS[d]));
    float alpha = ex / fmaxf(dS[d], 1e-16f);
    float h = hg[r.y & 0xFFFFFFu];
    atomicAdd(&nS[d], alpha * h);
  }
  __syncthreads();
  if (tid < 128) {
    int dst = b * 128 + tid;
    if (dst < N) scoreL[dst] = nS[tid] + gb[0];
  }
}

// ======================= exact top-k ranking =======================
__global__ __launch_bounds__(256) void k_minmax(const float* __restrict__ sc, unsigned* __restrict__ mm) {
  __shared__ unsigned smx[256], smn[256];
  int t = threadIdx.x; int n = blockIdx.x * 256 + t;
  unsigned v = (n < N) ? enc_f(sc[n]) : 0u;
  smx[t] = (n < N) ? v : 0u;
  smn[t] = (n < N) ? v : 0xFFFFFFFFu;
  __syncthreads();
  for (int off = 128; off; off >>= 1) {
    if (t < off) {
      smx[t] = max(smx[t], smx[t + off]);
      smn[t] = min(smn[t], smn[t + off]);
    }
    __syncthreads();
  }
  if (t == 0) { atomicMax(&mm[0], smx[0]); atomicMin(&mm[1], smn[0]); }
}

__global__ __launch_bounds__(256) void k_bucket_hist(const float* __restrict__ sc, const unsigned* __restrict__ mm,
                                                     int* __restrict__ bucket, int* __restrict__ hist) {
  int n = blockIdx.x * 256 + threadIdx.x;
  if (n >= N) return;
  float smax = dec_f(mm[0]), smin = dec_f(mm[1]);
  float range = smax - smin;
  float scale = (range > 0.f) ? ((float)NB / range) : 0.f;
  float t = (smax - sc[n]) * scale;
  int b = (int)t;
  b = b < 0 ? 0 : (b > NB - 1 ? NB - 1 : b);
  bucket[n] = b;
  atomicAdd(&hist[b], 1);
}

__global__ __launch_bounds__(256) void k_bucket_scatter(const int* __restrict__ bucket, const int* __restrict__ start,
                                                        int* __restrict__ cur, int* __restrict__ slot) {
  int n = blockIdx.x * 256 + threadIdx.x;
  if (n >= N) return;
  int b = bucket[n];
  slot[start[b] + atomicAdd(&cur[b], 1)] = n;
}

__global__ __launch_bounds__(256) void k_bucket_rank(const float* __restrict__ sc, const int* __restrict__ bucket,
                                                     const int* __restrict__ start, const int* __restrict__ hist,
                                                     const int* __restrict__ slot, int* __restrict__ rank,
                                                     int* __restrict__ sorted) {
  int n = blockIdx.x * 256 + threadIdx.x;
  if (n >= N) return;
  int b = bucket[n];
  int st = start[b], cnt = hist[b];
  unsigned long long mykey = (((unsigned long long)(~enc_f(sc[n]))) << 32) | (unsigned)n;
  int r = 0;
  for (int j = 0; j < cnt; ++j) {
    int m = slot[st + j];
    unsigned long long k = (((unsigned long long)(~enc_f(sc[m]))) << 32) | (unsigned)m;
    r += (k < mykey) ? 1 : 0;
  }
  rank[n] = st + r;
  sorted[st + r] = n;
}

// ======================= union mapping =======================
__global__ __launch_bounds__(1024) void k_union_chunksum(const int* __restrict__ rankF, const int* __restrict__ rankL,
                                                         int* __restrict__ csum) {
  __shared__ int red[1024];
  int t = threadIdx.x; int i = blockIdx.x * 1024 + t;
  int u = (i < N) ? (((rankF[i] < KSEL) || (rankL[i] < KSEL)) ? 1 : 0) : 0;
  red[t] = u; __syncthreads();
  for (int off = 512; off; off >>= 1) { if (t < off) red[t] += red[t + off]; __syncthreads(); }
  if (t == 0) csum[blockIdx.x] = red[0];
}

__global__ __launch_bounds__(1024) void k_union_map(const int* __restrict__ rankF, const int* __restrict__ rankL,
                                                    const int* __restrict__ cstart, const int* __restrict__ batch,
                                                    int* __restrict__ mapping, float* __restrict__ outBatch) {
  __shared__ int sums[1024];
  int t = threadIdx.x; int i = blockIdx.x * 1024 + t;
  int u = (i < N) ? (((rankF[i] < KSEL) || (rankL[i] < KSEL)) ? 1 : 0) : 0;
  sums[t] = u; __syncthreads();
  for (int off = 1; off < 1024; off <<= 1) {
    int v = (t >= off) ? sums[t - off] : 0;
    __syncthreads();
    sums[t] += v;
    __syncthreads();
  }
  if (i < N) {
    mapping[i] = u ? (cstart[blockIdx.x] + sums[t] - 1) : -1;
    outBatch[i] = u ? (float)batch[i] : -1.0f;
  }
}

__global__ __launch_bounds__(256) void k_edge_out(const int* __restrict__ ei, const int* __restrict__ mapping,
                                                  float* __restrict__ outE) {
  int e = blockIdx.x * 256 + threadIdx.x;
  if (e >= E_) return;
  int m0 = mapping[ei[e]], m1 = mapping[ei[E_ + e]];
  bool valid = (m0 >= 0) && (m1 >= 0);
  outE[e] = valid ? (float)m0 : -1.f;
  outE[E_ + e] = valid ? (float)m1 : -1.f;
}

// ======================= fused GCN transform + scatter =======================
// Fp[tgtL[i]] += relu( x[srcL[i]] @ tw + tb + q*SW + (p-q)*HW[cid[srcL[i]]] )
__global__ __launch_bounds__(256) void k_fuse(const float* __restrict__ x, const float* __restrict__ tw,
                                              const float* __restrict__ tb, const float* __restrict__ SW,
                                              const float* __restrict__ HW, const float* __restrict__ gdot,
                                              const float* __restrict__ aDot, const int* __restrict__ cid,
                                              const int* __restrict__ srcL, const int* __restrict__ tgtL,
                                              const float* __restrict__ attb, float* __restrict__ Fp) {
  __shared__ float xld[16 * D];
  __shared__ float pql[16 * 2];
  __shared__ int meta[16 * 2];  // [r][0]=cid(src), [r][1]=tgt
  int tid = threadIdx.x;
  int g = tid >> 7, c = tid & 127;
  float ab0 = attb[0];
  float tbc = tb[c];
  float swc = SW[c];
  int iters = KSEL / 16;
  for (int it = blockIdx.x; it < iters; it += gridDim.x) {
    int base = it * 16;
    __syncthreads();  // protect LDS from previous iteration readers
    if (tid < 16) {
      int ws = srcL[base + tid];
      int cc = cid[ws];
      meta[tid * 2] = cc;
      meta[tid * 2 + 1] = tgtL[base + tid];
      float s = aDot[ws] + gdot[cc] + ab0;
      float mx = fmaxf(s, 0.f);
      float esm = expf(s - mx), eom = expf(-mx);
      float dn = esm + 255.f * eom;
      pql[tid * 2] = esm / dn;
      pql[tid * 2 + 1] = eom / dn;
    }
    // stage 16 x-rows (512 float4, 2 per thread)
    {
      int i0 = tid * 2;
#pragma unroll
      for (int k = 0; k < 2; ++k) {
        int i = i0 + k;
        int r = i >> 5;
        int off = i & 31;
        int ws = srcL[base + r];
        ((float4*)xld)[r * 32 + off] = ((const float4*)(x + (size_t)ws * D))[off];
      }
    }
    __syncthreads();
    float acc[8];
#pragma unroll
    for (int r = 0; r < 8; ++r) acc[r] = 0.f;
    const float* xb = xld + g * 8 * D;
    for (int d4 = 0; d4 < D; d4 += 4) {
      float4 xv[8];
#pragma unroll
      for (int r = 0; r < 8; ++r) xv[r] = *(const float4*)(xb + r * D + d4);
#pragma unroll
      for (int dd = 0; dd < 4; ++dd) {
        float w = tw[(d4 + dd) * D + c];
#pragma unroll
        for (int r = 0; r < 8; ++r) {
          float xs = (dd == 0) ? xv[r].x : (dd == 1) ? xv[r].y : (dd == 2) ? xv[r].z : xv[r].w;
          acc[r] = fmaf(xs, w, acc[r]);
        }
      }
    }
#pragma unroll
    for (int r = 0; r < 8; ++r) {
      int row = g * 8 + r;
      float p = pql[row * 2], q = pql[row * 2 + 1];
      int cc = meta[row * 2];
      int tgt = meta[row * 2 + 1];
      float o = acc[r] + tbc + q * swc + (p - q) * HW[(size_t)cc * D + c];
      o = fmaxf(o, 0.f);
      Fp[(size_t)tgt * D + c] += o;
    }
  }
}

__global__ __launch_bounds__(256) void k_half(const int* __restrict__ rankF, const int* __restrict__ rankL,
                                              float* __restrict__ Fp) {
  int i = blockIdx.x * 256 + threadIdx.x;  // over N*D
  int n = i >> 7;
  if ((rankF[n] < KSEL) && (rankL[n] < KSEL)) Fp[i] *= 0.5f;
}

// ======================= launcher =======================
extern "C" void kernel_launch(void* const* d_in, const int* in_sizes, int n_in,
                              void* d_out, int out_size, void* d_ws, size_t ws_size,
                              hipStream_t stream) {
  const float* x   = (const float*)d_in[0];
  const int* ei    = (const int*)d_in[1];
  const int* batch = (const int*)d_in[2];
  const int* cid   = (const int*)d_in[3];
  const float* w1  = (const float*)d_in[4];
  const float* b1  = (const float*)d_in[5];
  const float* w2  = (const float*)d_in[6];
  const float* b2  = (const float*)d_in[7];
  const float* gw  = (const float*)d_in[8];
  const float* gas = (const float*)d_in[9];
  const float* gad = (const float*)d_in[10];
  const float* gb  = (const float*)d_in[11];
  const float* wa  = (const float*)d_in[12];
  const float* wb  = (const float*)d_in[13];
  const float* ab  = (const float*)d_in[14];
  const float* tw  = (const float*)d_in[15];
  const float* tb  = (const float*)d_in[16];
  (void)in_sizes; (void)n_in; (void)ws_size;

  char* p = (char*)d_ws;
  auto alloc = [&](size_t bytes) -> char* {
    char* r = p;
    p += (bytes + 255) & ~(size_t)255;
    return r;
  };
  // ---- zero-init region (memset below covers up to zeroBytes) ----
  int* ccount    = (int*)alloc(C_ * 4);
  int* ccur      = (int*)alloc(C_ * 4);
  unsigned* mmF  = (unsigned*)alloc(16);
  unsigned* mmL  = (unsigned*)alloc(16);
  int* histF     = (int*)alloc(NB * 4);
  int* histL     = (int*)alloc(NB * 4);
  int* curF      = (int*)alloc(NB * 4);
  int* curL      = (int*)alloc(NB * 4);
  float* Hc      = (float*)alloc((size_t)C_ * D * 4);   // atomic accumulator -> must be zeroed
  int* gcnt      = (int*)alloc(NBK * 4);                // bucket cursors
  size_t zeroBytes = (size_t)(p - (char*)d_ws);
  // ---- rest (fully written before read) ----
  int* cstart   = (int*)alloc(C_ * 4);
  int* cslot    = (int*)alloc((size_t)N * 4);
  float* gdot   = (float*)alloc(C_ * 4);
  float* S      = (float*)alloc(D * 4);
  float* SW     = (float*)alloc(D * 4);
  float* HW     = (float*)alloc((size_t)C_ * D * 4);
  float* scoreF = (float*)alloc((size_t)N * 4);
  float* scoreL = (float*)alloc((size_t)N * 4);
  float* hg     = (float*)alloc((size_t)N * 4);
  float* aDot   = (float*)alloc((size_t)N * 4);
  uint2* payload = (uint2*)alloc((size_t)NBK * BCAP * 8);
  int* bucketF  = (int*)alloc((size_t)N * 4);
  int* bucketL  = (int*)alloc((size_t)N * 4);
  int* startF   = (int*)alloc(NB * 4);
  int* startL   = (int*)alloc(NB * 4);
  int* slotF    = (int*)alloc((size_t)N * 4);
  int* slotL    = (int*)alloc((size_t)N * 4);
  int* sortedF  = (int*)alloc((size_t)N * 4);
  int* sortedL  = (int*)alloc((size_t)N * 4);
  int* rankF    = (int*)alloc((size_t)N * 4);
  int* rankL    = (int*)alloc((size_t)N * 4);
  int* csums    = (int*)alloc(NCHUNK * 4);
  int* cstarts  = (int*)alloc(NCHUNK * 4);
  int* mapping  = (int*)alloc((size_t)N * 4);

  float* outF = (float*)d_out;             // [N, D]
  float* outE = outF + (size_t)N * D;      // [2, E]
  float* outB = outE + (size_t)2 * E_;     // [N]

  hipMemsetAsync(d_ws, 0, zeroBytes, stream);
  hipMemsetAsync(d_out, 0, (size_t)out_size * sizeof(float), stream);
  hipMemsetAsync(mmF + 1, 0xFF, 4, stream);  // min slot -> 0xFFFFFFFF
  hipMemsetAsync(mmL + 1, 0xFF, 4, stream);

  // cluster means + derived
  k_hist_cluster<<<(N + 255) / 256, 256, 0, stream>>>(cid, ccount);
  k_scan_small<<<1, 1024, 0, stream>>>(ccount, cstart, C_);
  k_scatter_cluster<<<(N + 255) / 256, 256, 0, stream>>>(cid, cstart, ccur, cslot);
  k_cluster_partial<<<C_ * CSEG, 128, 0, stream>>>(x, cstart, ccount, cslot, Hc);
  k_mean_div<<<(C_ * D) / 256, 256, 0, stream>>>(ccount, Hc);
  k_gdot<<<C_, 64, 0, stream>>>(Hc, wb, gdot);
  k_S<<<1, 128, 0, stream>>>(Hc, S);
  k_SW_HW<<<C_ + 1, 128, 0, stream>>>(S, Hc, tw, SW, HW);

  // scores
  k_feat_score<<<N / 16, 256, 0, stream>>>(x, w1, b1, w2, b2, scoreF);
  k_gat_h<<<N / 4, 256, 0, stream>>>(x, gw, wa, hg, aDot);
  k_escatter<<<(E_ + 8191) / 8192, 1024, 0, stream>>>(ei, hg, gas, gad, gcnt, payload);
  k_esoftmax<<<NBK, 256, 0, stream>>>(payload, gcnt, hg, gb, scoreL);

  // exact ranking, feature view
  k_minmax<<<(N + 255) / 256, 256, 0, stream>>>(scoreF, mmF);
  k_bucket_hist<<<(N + 255) / 256, 256, 0, stream>>>(scoreF, mmF, bucketF, histF);
  k_scan_small<<<1, 1024, 0, stream>>>(histF, startF, NB);
  k_bucket_scatter<<<(N + 255) / 256, 256, 0, stream>>>(bucketF, startF, curF, slotF);
  k_bucket_rank<<<(N + 255) / 256, 256, 0, stream>>>(scoreF, bucketF, startF, histF, slotF, rankF, sortedF);
  // exact ranking, local view
  k_minmax<<<(N + 255) / 256, 256, 0, stream>>>(scoreL, mmL);
  k_bucket_hist<<<(N + 255) / 256, 256, 0, stream>>>(scoreL, mmL, bucketL, histL);
  k_scan_small<<<1, 1024, 0, stream>>>(histL, startL, NB);
  k_bucket_scatter<<<(N + 255) / 256, 256, 0, stream>>>(bucketL, startL, curL, slotL);
  k_bucket_rank<<<(N + 255) / 256, 256, 0, stream>>>(scoreL, bucketL, startL, histL, slotL, rankL, sortedL);

  // union mapping + edge remap + batch
  k_union_chunksum<<<NCHUNK, 1024, 0, stream>>>(rankF, rankL, csums);
  k_scan_small<<<1, 1024, 0, stream>>>(csums, cstarts, NCHUNK);
  k_union_map<<<NCHUNK, 1024, 0, stream>>>(rankF, rankL, cstarts, batch, mapping, outB);
  k_edge_out<<<(E_ + 255) / 256, 256, 0, stream>>>(ei, mapping, outE);

  // fused features: A[feat_idx[i]] = fuse2[i] (src=local), B[local_idx[i]] = fuse1[i] (src=feat)
  k_fuse<<<1280, 256, 0, stream>>>(x, tw, tb, SW, HW, gdot, aDot, cid, sortedL, sortedF, ab, outF);
  k_fuse<<<1280, 256, 0, stream>>>(x, tw, tb, SW, HW, gdot, aDot, cid, sortedF, sortedL, ab, outF);
  k_half<<<(N * D) / 256, 256, 0, stream>>>(rankF, rankL, outF);
}

// Round 4
// 748.969 us; speedup vs baseline: 1.6430x; 1.2007x over previous
//
#include <hip/hip_runtime.h>
#include <hip/hip_bf16.h>
#include <stdint.h>

#define N 100000
#define E_ 1600000
#define D 128
#define C_ 256
#define HID 64
#define KSEL 80000
#define NB 4096
#define CHUNK 1024
#define NCHUNK ((N + CHUNK - 1) / CHUNK)   // 98
#define CSEG 32                            // segments per cluster for mean reduction
#define NBK 782                            // ceil(N/128) dst-buckets of 128 nodes
#define BCAP 2560                          // per-bucket capacity (avg 2046 + >11 sigma)

// ---- ordered-float encoding (monotonic increasing uint) ----
__device__ __forceinline__ unsigned enc_f(float f) {
  unsigned b = __float_as_uint(f);
  return (b & 0x80000000u) ? ~b : (b | 0x80000000u);
}
__device__ __forceinline__ float dec_f(unsigned u) {
  unsigned b = (u & 0x80000000u) ? (u ^ 0x80000000u) : ~u;
  return __uint_as_float(b);
}

// ======================= cluster CSR + means =======================
__global__ __launch_bounds__(256) void k_hist_cluster(const int* __restrict__ cid, int* __restrict__ ccount) {
  int n = blockIdx.x * 256 + threadIdx.x;
  if (n < N) atomicAdd(&ccount[cid[n]], 1);
}

__global__ __launch_bounds__(1024) void k_scan_small(const int* __restrict__ in, int* __restrict__ out, int n) {
  __shared__ int sums[1024];
  int t = threadIdx.x;
  int per = (n + 1023) / 1024;
  int base = t * per;
  int loc = 0;
  for (int k = 0; k < per; ++k) { int i = base + k; if (i < n) loc += in[i]; }
  sums[t] = loc; __syncthreads();
  for (int off = 1; off < 1024; off <<= 1) {
    int v = (t >= off) ? sums[t - off] : 0;
    __syncthreads();
    sums[t] += v;
    __syncthreads();
  }
  int run = (t == 0) ? 0 : sums[t - 1];
  for (int k = 0; k < per; ++k) { int i = base + k; if (i < n) { out[i] = run; run += in[i]; } }
}

__global__ __launch_bounds__(256) void k_scatter_cluster(const int* __restrict__ cid, const int* __restrict__ cstart,
                                                         int* __restrict__ ccur, int* __restrict__ cslot) {
  int n = blockIdx.x * 256 + threadIdx.x;
  if (n < N) {
    int c = cid[n];
    int p = cstart[c] + atomicAdd(&ccur[c], 1);
    cslot[p] = n;
  }
}

// Parallel cluster mean: CSEG segment-blocks per cluster -> register partials
// -> one float atomicAdd per (c,d) into zeroed Hc.
__global__ __launch_bounds__(128) void k_cluster_partial(const float* __restrict__ x, const int* __restrict__ cstart,
                                                         const int* __restrict__ ccount, const int* __restrict__ cslot,
                                                         float* __restrict__ Hc) {
  int c = blockIdx.x >> 5;
  int s = blockIdx.x & (CSEG - 1);
  int d = threadIdx.x;
  int st = cstart[c], cnt = ccount[c];
  int seg = (cnt + CSEG - 1) / CSEG;
  int lo = s * seg;
  int hi = min(cnt, lo + seg);
  if (lo >= hi) return;
  float acc = 0.f;
  int k = lo;
  for (; k + 2 <= hi; k += 2) {
    int n0 = cslot[st + k], n1 = cslot[st + k + 1];
    float v0 = x[(size_t)n0 * D + d];
    float v1 = x[(size_t)n1 * D + d];
    acc += v0 + v1;
  }
  if (k < hi) acc += x[(size_t)cslot[st + k] * D + d];
  atomicAdd(&Hc[(size_t)c * D + d], acc);
}

__global__ __launch_bounds__(256) void k_mean_div(const int* __restrict__ ccount, float* __restrict__ Hc) {
  int i = blockIdx.x * 256 + threadIdx.x;  // over C_*D
  int c = i >> 7;
  Hc[i] /= (float)max(ccount[c], 1);
}

__global__ __launch_bounds__(64) void k_gdot(const float* __restrict__ Hc, const float* __restrict__ wb,
                                             float* __restrict__ gdot) {
  int c = blockIdx.x; int l = threadIdx.x;
  float v = Hc[c * D + l] * wb[l] + Hc[c * D + 64 + l] * wb[64 + l];
  for (int off = 32; off; off >>= 1) v += __shfl_down(v, off);
  if (l == 0) gdot[c] = v;
}

__global__ __launch_bounds__(128) void k_S(const float* __restrict__ Hc, float* __restrict__ S) {
  int d = threadIdx.x;
  float s = 0.f;
  for (int c = 0; c < C_; ++c) s += Hc[c * D + d];
  S[d] = s;
}

// block 0 -> SW = S @ tw ; blocks 1..C_ -> HW[b-1] = Hc[b-1] @ tw
__global__ __launch_bounds__(128) void k_SW_HW(const float* __restrict__ S, const float* __restrict__ Hc,
                                               const float* __restrict__ tw, float* __restrict__ SW,
                                               float* __restrict__ HW) {
  int c = threadIdx.x;
  int b = blockIdx.x;
  const float* src = (b == 0) ? S : (Hc + (size_t)(b - 1) * D);
  float acc = 0.f;
  for (int d = 0; d < D; ++d) acc = fmaf(src[d], tw[d * D + c], acc);
  if (b == 0) SW[c] = acc; else HW[(size_t)(b - 1) * D + c] = acc;
}

// ======================= feature score (MLP) =======================
__global__ __launch_bounds__(256) void k_feat_score(const float* __restrict__ x, const float* __restrict__ w1,
                                                    const float* __restrict__ b1, const float* __restrict__ w2,
                                                    const float* __restrict__ b2, float* __restrict__ scoreF) {
  __shared__ float w1ld[D * HID];
  __shared__ float xld[16 * D];
  __shared__ float w2ld[HID];
  __shared__ float b1ld[HID];
  int tid = threadIdx.x;
  for (int i = tid; i < D * HID / 4; i += 256) ((float4*)w1ld)[i] = ((const float4*)w1)[i];
  if (tid < HID) { w2ld[tid] = w2[tid]; b1ld[tid] = b1[tid]; }
  int nb = blockIdx.x * 16;
  for (int i = tid; i < 16 * D / 4; i += 256)
    ((float4*)xld)[i] = ((const float4*)(x + (size_t)nb * D))[i];
  __syncthreads();
  int lane = tid & 63, wv = tid >> 6;
  float a0, a1, a2, a3;
  a0 = a1 = a2 = a3 = b1ld[lane];
  const float* xr = xld + wv * 4 * D;
  for (int d = 0; d < D; ++d) {
    float w = w1ld[d * HID + lane];
    a0 = fmaf(xr[d], w, a0);
    a1 = fmaf(xr[D + d], w, a1);
    a2 = fmaf(xr[2 * D + d], w, a2);
    a3 = fmaf(xr[3 * D + d], w, a3);
  }
  float wv2 = w2ld[lane];
  float s0 = fmaxf(a0, 0.f) * wv2, s1 = fmaxf(a1, 0.f) * wv2;
  float s2 = fmaxf(a2, 0.f) * wv2, s3 = fmaxf(a3, 0.f) * wv2;
  for (int off = 32; off; off >>= 1) {
    s0 += __shfl_down(s0, off); s1 += __shfl_down(s1, off);
    s2 += __shfl_down(s2, off); s3 += __shfl_down(s3, off);
  }
  if (lane == 0) {
    float bb = b2[0];
    int n0 = nb + wv * 4;
    scoreF[n0] = s0 + bb; scoreF[n0 + 1] = s1 + bb;
    scoreF[n0 + 2] = s2 + bb; scoreF[n0 + 3] = s3 + bb;
  }
}

// ======================= GAT score =======================
__global__ __launch_bounds__(256) void k_gat_h(const float* __restrict__ x, const float* __restrict__ gw,
                                               const float* __restrict__ wa, float* __restrict__ hg,
                                               float* __restrict__ aDot) {
  int tid = threadIdx.x; int lane = tid & 63, wv = tid >> 6;
  int n = blockIdx.x * 4 + wv;
  const float* xr = x + (size_t)n * D;
  float x0 = xr[lane], x1 = xr[64 + lane];
  float hp = x0 * gw[lane] + x1 * gw[64 + lane];
  float ap = x0 * wa[lane] + x1 * wa[64 + lane];
  for (int off = 32; off; off >>= 1) { hp += __shfl_down(hp, off); ap += __shfl_down(ap, off); }
  if (lane == 0) { hg[n] = hp; aDot[n] = ap; }
}

// Bucket edges by dst>>7 into fixed-CAP regions. LDS-aggregated reservation.
// Record: .x = bits(e), .y = src | (dstloc << 24).
__global__ __launch_bounds__(1024) void k_escatter(const int* __restrict__ ei, const float* __restrict__ hg,
                                                   const float* __restrict__ asrc, const float* __restrict__ adst,
                                                   int* __restrict__ gcnt, uint2* __restrict__ payload) {
  __shared__ int lcnt[NBK];
  __shared__ int lbase[NBK];
  int tid = threadIdx.x;
  for (int i = tid; i < NBK; i += 1024) lcnt[i] = 0;
  int e0 = blockIdx.x * 8192;
  int es[8], ed[8];
#pragma unroll
  for (int k = 0; k < 8; ++k) {
    int e = e0 + k * 1024 + tid;
    bool v = (e < E_);
    es[k] = v ? ei[e] : -1;
    ed[k] = v ? ei[E_ + e] : -1;
  }
  __syncthreads();
#pragma unroll
  for (int k = 0; k < 8; ++k)
    if (ed[k] >= 0) atomicAdd(&lcnt[ed[k] >> 7], 1);
  __syncthreads();
  for (int i = tid; i < NBK; i += 1024) {
    int c = lcnt[i];
    lbase[i] = c ? atomicAdd(&gcnt[i], c) : 0;
    lcnt[i] = 0;
  }
  __syncthreads();
  float as = asrc[0], ad = adst[0];
#pragma unroll
  for (int k = 0; k < 8; ++k) {
    if (ed[k] < 0) continue;
    int s = es[k], d = ed[k];
    int b = d >> 7, dl = d & 127;
    float z = as * hg[s] + ad * hg[d];
    float ev = (z > 0.f) ? z : 0.2f * z;
    int pos = lbase[b] + atomicAdd(&lcnt[b], 1);
    if (pos < BCAP) {
      uint2 rec;
      rec.x = __float_as_uint(ev);
      rec.y = (unsigned)s | ((unsigned)dl << 24);
      payload[(size_t)b * BCAP + pos] = rec;
    }
  }
}

// Per-bucket GAT softmax entirely in LDS: max -> den -> alpha*h; writes scoreL.
__global__ __launch_bounds__(256) void k_esoftmax(const uint2* __restrict__ payload, const int* __restrict__ gcnt,
                                                  const float* __restrict__ hg, const float* __restrict__ gb,
                                                  float* __restrict__ scoreL) {
  __shared__ unsigned mS[128];
  __shared__ float dS[128];
  __shared__ float nS[128];
  int b = blockIdx.x;
  int tid = threadIdx.x;
  if (tid < 128) { mS[tid] = 0u; dS[tid] = 0.f; nS[tid] = 0.f; }
  __syncthreads();
  int cnt = min(gcnt[b], BCAP);
  const uint2* bp = payload + (size_t)b * BCAP;
  for (int i = tid; i < cnt; i += 256) {
    uint2 r = bp[i];
    atomicMax(&mS[r.y >> 24], enc_f(__uint_as_float(r.x)));
  }
  __syncthreads();
  for (int i = tid; i < cnt; i += 256) {
    uint2 r = bp[i];
    int d = r.y >> 24;
    float ex = expf(__uint_as_float(r.x) - dec_f(mS[d]));
    atomicAdd(&dS[d], ex);
  }
  __syncthreads();
  for (int i = tid; i < cnt; i += 256) {
    uint2 r = bp[i];
    int d = r.y >> 24;
    float ex = expf(__uint_as_float(r.x) - dec_f(mS[d]));
    float alpha = ex / fmaxf(dS[d], 1e-16f);
    float h = hg[r.y & 0xFFFFFFu];
    atomicAdd(&nS[d], alpha * h);
  }
  __syncthreads();
  if (tid < 128) {
    int dst = b * 128 + tid;
    if (dst < N) scoreL[dst] = nS[tid] + gb[0];
  }
}

// ======================= exact top-k ranking =======================
__global__ __launch_bounds__(256) void k_minmax(const float* __restrict__ sc, unsigned* __restrict__ mm) {
  __shared__ unsigned smx[256], smn[256];
  int t = threadIdx.x; int n = blockIdx.x * 256 + t;
  unsigned v = (n < N) ? enc_f(sc[n]) : 0u;
  smx[t] = (n < N) ? v : 0u;
  smn[t] = (n < N) ? v : 0xFFFFFFFFu;
  __syncthreads();
  for (int off = 128; off; off >>= 1) {
    if (t < off) {
      smx[t] = max(smx[t], smx[t + off]);
      smn[t] = min(smn[t], smn[t + off]);
    }
    __syncthreads();
  }
  if (t == 0) { atomicMax(&mm[0], smx[0]); atomicMin(&mm[1], smn[0]); }
}

__global__ __launch_bounds__(256) void k_bucket_hist(const float* __restrict__ sc, const unsigned* __restrict__ mm,
                                                     int* __restrict__ bucket, int* __restrict__ hist) {
  int n = blockIdx.x * 256 + threadIdx.x;
  if (n >= N) return;
  float smax = dec_f(mm[0]), smin = dec_f(mm[1]);
  float range = smax - smin;
  float scale = (range > 0.f) ? ((float)NB / range) : 0.f;
  float t = (smax - sc[n]) * scale;
  int b = (int)t;
  b = b < 0 ? 0 : (b > NB - 1 ? NB - 1 : b);
  bucket[n] = b;
  atomicAdd(&hist[b], 1);
}

__global__ __launch_bounds__(256) void k_bucket_scatter(const int* __restrict__ bucket, const int* __restrict__ start,
                                                        int* __restrict__ cur, int* __restrict__ slot) {
  int n = blockIdx.x * 256 + threadIdx.x;
  if (n >= N) return;
  int b = bucket[n];
  slot[start[b] + atomicAdd(&cur[b], 1)] = n;
}

__global__ __launch_bounds__(256) void k_bucket_rank(const float* __restrict__ sc, const int* __restrict__ bucket,
                                                     const int* __restrict__ start, const int* __restrict__ hist,
                                                     const int* __restrict__ slot, int* __restrict__ rank,
                                                     int* __restrict__ sorted) {
  int n = blockIdx.x * 256 + threadIdx.x;
  if (n >= N) return;
  int b = bucket[n];
  int st = start[b], cnt = hist[b];
  unsigned long long mykey = (((unsigned long long)(~enc_f(sc[n]))) << 32) | (unsigned)n;
  int r = 0;
  for (int j = 0; j < cnt; ++j) {
    int m = slot[st + j];
    unsigned long long k = (((unsigned long long)(~enc_f(sc[m]))) << 32) | (unsigned)m;
    r += (k < mykey) ? 1 : 0;
  }
  rank[n] = st + r;
  sorted[st + r] = n;
}

// ======================= union mapping =======================
__global__ __launch_bounds__(1024) void k_union_chunksum(const int* __restrict__ rankF, const int* __restrict__ rankL,
                                                         int* __restrict__ csum) {
  __shared__ int red[1024];
  int t = threadIdx.x; int i = blockIdx.x * 1024 + t;
  int u = (i < N) ? (((rankF[i] < KSEL) || (rankL[i] < KSEL)) ? 1 : 0) : 0;
  red[t] = u; __syncthreads();
  for (int off = 512; off; off >>= 1) { if (t < off) red[t] += red[t + off]; __syncthreads(); }
  if (t == 0) csum[blockIdx.x] = red[0];
}

__global__ __launch_bounds__(1024) void k_union_map(const int* __restrict__ rankF, const int* __restrict__ rankL,
                                                    const int* __restrict__ cstart, const int* __restrict__ batch,
                                                    int* __restrict__ mapping, float* __restrict__ outBatch) {
  __shared__ int sums[1024];
  int t = threadIdx.x; int i = blockIdx.x * 1024 + t;
  int u = (i < N) ? (((rankF[i] < KSEL) || (rankL[i] < KSEL)) ? 1 : 0) : 0;
  sums[t] = u; __syncthreads();
  for (int off = 1; off < 1024; off <<= 1) {
    int v = (t >= off) ? sums[t - off] : 0;
    __syncthreads();
    sums[t] += v;
    __syncthreads();
  }
  if (i < N) {
    mapping[i] = u ? (cstart[blockIdx.x] + sums[t] - 1) : -1;
    outBatch[i] = u ? (float)batch[i] : -1.0f;
  }
}

__global__ __launch_bounds__(256) void k_edge_out(const int* __restrict__ ei, const int* __restrict__ mapping,
                                                  float* __restrict__ outE) {
  int e = blockIdx.x * 256 + threadIdx.x;
  if (e >= E_) return;
  int m0 = mapping[ei[e]], m1 = mapping[ei[E_ + e]];
  bool valid = (m0 >= 0) && (m1 >= 0);
  outE[e] = valid ? (float)m0 : -1.f;
  outE[E_ + e] = valid ? (float)m1 : -1.f;
}

// ======================= fused GCN transform + scatter =======================
// Fp[tgtL[i]] (+)= relu( x[srcL[i]] @ tw + tb + q*SW + (p-q)*HW[cid[srcL[i]]] )
// 64 rows/block, 8 rows x 4 cols per thread: 128 FMA per 12 LDS/VMEM b128 loads
// (old version: 4 FMA per ds_read_b128 -> LDS-pipe-bound at 30% VALUBusy).
__global__ __launch_bounds__(256, 4) void k_fuse64(const float* __restrict__ x, const float* __restrict__ tw,
                                                   const float* __restrict__ tb, const float* __restrict__ SW,
                                                   const float* __restrict__ HW, const float* __restrict__ gdot,
                                                   const float* __restrict__ aDot, const int* __restrict__ cid,
                                                   const int* __restrict__ srcL, const int* __restrict__ tgtL,
                                                   const float* __restrict__ attb, float* __restrict__ Fp,
                                                   int accum) {
  __shared__ float xld[64 * D];
  __shared__ float pq[64 * 2];
  __shared__ int mt[64 * 2];
  int tid = threadIdx.x;
  int base = blockIdx.x * 64;
  if (tid < 64) {
    int ws = srcL[base + tid];
    int cc = cid[ws];
    mt[tid * 2] = cc;
    mt[tid * 2 + 1] = tgtL[base + tid];
    float s = aDot[ws] + gdot[cc] + attb[0];
    float mx = fmaxf(s, 0.f);
    float esm = expf(s - mx), eom = expf(-mx);
    float dn = esm + 255.f * eom;
    pq[tid * 2] = esm / dn;
    pq[tid * 2 + 1] = eom / dn;
  }
  // stage 64 x-rows (2048 float4, 8 per thread)
#pragma unroll
  for (int k = 0; k < 8; ++k) {
    int i = k * 256 + tid;
    int r = i >> 5, off = i & 31;
    int ws = srcL[base + r];
    ((float4*)xld)[i] = ((const float4*)(x + (size_t)ws * D))[off];
  }
  __syncthreads();

  int rg = tid >> 5;        // 8 row-groups of 8 rows
  int c4 = (tid & 31) * 4;  // 32 col-groups of 4 cols
  float acc[8][4] = {};
  const float* xb = xld + rg * 8 * D;
  for (int d4 = 0; d4 < D; d4 += 4) {
    float4 t0 = *(const float4*)(tw + (size_t)(d4 + 0) * D + c4);
    float4 t1 = *(const float4*)(tw + (size_t)(d4 + 1) * D + c4);
    float4 t2 = *(const float4*)(tw + (size_t)(d4 + 2) * D + c4);
    float4 t3 = *(const float4*)(tw + (size_t)(d4 + 3) * D + c4);
#pragma unroll
    for (int r = 0; r < 8; ++r) {
      float4 xv = *(const float4*)(xb + r * D + d4);
      acc[r][0] = fmaf(xv.x, t0.x, acc[r][0]);
      acc[r][1] = fmaf(xv.x, t0.y, acc[r][1]);
      acc[r][2] = fmaf(xv.x, t0.z, acc[r][2]);
      acc[r][3] = fmaf(xv.x, t0.w, acc[r][3]);
      acc[r][0] = fmaf(xv.y, t1.x, acc[r][0]);
      acc[r][1] = fmaf(xv.y, t1.y, acc[r][1]);
      acc[r][2] = fmaf(xv.y, t1.z, acc[r][2]);
      acc[r][3] = fmaf(xv.y, t1.w, acc[r][3]);
      acc[r][0] = fmaf(xv.z, t2.x, acc[r][0]);
      acc[r][1] = fmaf(xv.z, t2.y, acc[r][1]);
      acc[r][2] = fmaf(xv.z, t2.z, acc[r][2]);
      acc[r][3] = fmaf(xv.z, t2.w, acc[r][3]);
      acc[r][0] = fmaf(xv.w, t3.x, acc[r][0]);
      acc[r][1] = fmaf(xv.w, t3.y, acc[r][1]);
      acc[r][2] = fmaf(xv.w, t3.z, acc[r][2]);
      acc[r][3] = fmaf(xv.w, t3.w, acc[r][3]);
    }
  }

  float4 tbv = *(const float4*)(tb + c4);
  float4 swv = *(const float4*)(SW + c4);
#pragma unroll
  for (int r = 0; r < 8; ++r) {
    int row = rg * 8 + r;
    float p = pq[row * 2], q = pq[row * 2 + 1];
    int cc = mt[row * 2];
    int tgt = mt[row * 2 + 1];
    float4 hw = *(const float4*)(HW + (size_t)cc * D + c4);
    float4 o;
    o.x = fmaxf(acc[r][0] + tbv.x + q * swv.x + (p - q) * hw.x, 0.f);
    o.y = fmaxf(acc[r][1] + tbv.y + q * swv.y + (p - q) * hw.y, 0.f);
    o.z = fmaxf(acc[r][2] + tbv.z + q * swv.z + (p - q) * hw.z, 0.f);
    o.w = fmaxf(acc[r][3] + tbv.w + q * swv.w + (p - q) * hw.w, 0.f);
    float4* dst = (float4*)(Fp + (size_t)tgt * D + c4);
    if (accum) {
      float4 old = *dst;
      o.x += old.x; o.y += old.y; o.z += old.z; o.w += old.w;
    }
    *dst = o;
  }
}

__global__ __launch_bounds__(256) void k_half(const int* __restrict__ rankF, const int* __restrict__ rankL,
                                              float* __restrict__ Fp) {
  int i = blockIdx.x * 256 + threadIdx.x;  // over N*D
  int n = i >> 7;
  if ((rankF[n] < KSEL) && (rankL[n] < KSEL)) Fp[i] *= 0.5f;
}

// ======================= launcher =======================
extern "C" void kernel_launch(void* const* d_in, const int* in_sizes, int n_in,
                              void* d_out, int out_size, void* d_ws, size_t ws_size,
                              hipStream_t stream) {
  const float* x   = (const float*)d_in[0];
  const int* ei    = (const int*)d_in[1];
  const int* batch = (const int*)d_in[2];
  const int* cid   = (const int*)d_in[3];
  const float* w1  = (const float*)d_in[4];
  const float* b1  = (const float*)d_in[5];
  const float* w2  = (const float*)d_in[6];
  const float* b2  = (const float*)d_in[7];
  const float* gw  = (const float*)d_in[8];
  const float* gas = (const float*)d_in[9];
  const float* gad = (const float*)d_in[10];
  const float* gb  = (const float*)d_in[11];
  const float* wa  = (const float*)d_in[12];
  const float* wb  = (const float*)d_in[13];
  const float* ab  = (const float*)d_in[14];
  const float* tw  = (const float*)d_in[15];
  const float* tb  = (const float*)d_in[16];
  (void)in_sizes; (void)n_in; (void)ws_size;

  char* p = (char*)d_ws;
  auto alloc = [&](size_t bytes) -> char* {
    char* r = p;
    p += (bytes + 255) & ~(size_t)255;
    return r;
  };
  // ---- zero-init region (memset below covers up to zeroBytes) ----
  int* ccount    = (int*)alloc(C_ * 4);
  int* ccur      = (int*)alloc(C_ * 4);
  unsigned* mmF  = (unsigned*)alloc(16);
  unsigned* mmL  = (unsigned*)alloc(16);
  int* histF     = (int*)alloc(NB * 4);
  int* histL     = (int*)alloc(NB * 4);
  int* curF      = (int*)alloc(NB * 4);
  int* curL      = (int*)alloc(NB * 4);
  float* Hc      = (float*)alloc((size_t)C_ * D * 4);   // atomic accumulator -> must be zeroed
  int* gcnt      = (int*)alloc(NBK * 4);                // bucket cursors
  size_t zeroBytes = (size_t)(p - (char*)d_ws);
  // ---- rest (fully written before read) ----
  int* cstart   = (int*)alloc(C_ * 4);
  int* cslot    = (int*)alloc((size_t)N * 4);
  float* gdot   = (float*)alloc(C_ * 4);
  float* S      = (float*)alloc(D * 4);
  float* SW     = (float*)alloc(D * 4);
  float* HW     = (float*)alloc((size_t)C_ * D * 4);
  float* scoreF = (float*)alloc((size_t)N * 4);
  float* scoreL = (float*)alloc((size_t)N * 4);
  float* hg     = (float*)alloc((size_t)N * 4);
  float* aDot   = (float*)alloc((size_t)N * 4);
  uint2* payload = (uint2*)alloc((size_t)NBK * BCAP * 8);
  int* bucketF  = (int*)alloc((size_t)N * 4);
  int* bucketL  = (int*)alloc((size_t)N * 4);
  int* startF   = (int*)alloc(NB * 4);
  int* startL   = (int*)alloc(NB * 4);
  int* slotF    = (int*)alloc((size_t)N * 4);
  int* slotL    = (int*)alloc((size_t)N * 4);
  int* sortedF  = (int*)alloc((size_t)N * 4);
  int* sortedL  = (int*)alloc((size_t)N * 4);
  int* rankF    = (int*)alloc((size_t)N * 4);
  int* rankL    = (int*)alloc((size_t)N * 4);
  int* csums    = (int*)alloc(NCHUNK * 4);
  int* cstarts  = (int*)alloc(NCHUNK * 4);
  int* mapping  = (int*)alloc((size_t)N * 4);

  float* outF = (float*)d_out;             // [N, D]
  float* outE = outF + (size_t)N * D;      // [2, E]
  float* outB = outE + (size_t)2 * E_;     // [N]

  hipMemsetAsync(d_ws, 0, zeroBytes, stream);
  hipMemsetAsync(d_out, 0, (size_t)out_size * sizeof(float), stream);
  hipMemsetAsync(mmF + 1, 0xFF, 4, stream);  // min slot -> 0xFFFFFFFF
  hipMemsetAsync(mmL + 1, 0xFF, 4, stream);

  // cluster means + derived
  k_hist_cluster<<<(N + 255) / 256, 256, 0, stream>>>(cid, ccount);
  k_scan_small<<<1, 1024, 0, stream>>>(ccount, cstart, C_);
  k_scatter_cluster<<<(N + 255) / 256, 256, 0, stream>>>(cid, cstart, ccur, cslot);
  k_cluster_partial<<<C_ * CSEG, 128, 0, stream>>>(x, cstart, ccount, cslot, Hc);
  k_mean_div<<<(C_ * D) / 256, 256, 0, stream>>>(ccount, Hc);
  k_gdot<<<C_, 64, 0, stream>>>(Hc, wb, gdot);
  k_S<<<1, 128, 0, stream>>>(Hc, S);
  k_SW_HW<<<C_ + 1, 128, 0, stream>>>(S, Hc, tw, SW, HW);

  // scores
  k_feat_score<<<N / 16, 256, 0, stream>>>(x, w1, b1, w2, b2, scoreF);
  k_gat_h<<<N / 4, 256, 0, stream>>>(x, gw, wa, hg, aDot);
  k_escatter<<<(E_ + 8191) / 8192, 1024, 0, stream>>>(ei, hg, gas, gad, gcnt, payload);
  k_esoftmax<<<NBK, 256, 0, stream>>>(payload, gcnt, hg, gb, scoreL);

  // exact ranking, feature view
  k_minmax<<<(N + 255) / 256, 256, 0, stream>>>(scoreF, mmF);
  k_bucket_hist<<<(N + 255) / 256, 256, 0, stream>>>(scoreF, mmF, bucketF, histF);
  k_scan_small<<<1, 1024, 0, stream>>>(histF, startF, NB);
  k_bucket_scatter<<<(N + 255) / 256, 256, 0, stream>>>(bucketF, startF, curF, slotF);
  k_bucket_rank<<<(N + 255) / 256, 256, 0, stream>>>(scoreF, bucketF, startF, histF, slotF, rankF, sortedF);
  // exact ranking, local view
  k_minmax<<<(N + 255) / 256, 256, 0, stream>>>(scoreL, mmL);
  k_bucket_hist<<<(N + 255) / 256, 256, 0, stream>>>(scoreL, mmL, bucketL, histL);
  k_scan_small<<<1, 1024, 0, stream>>>(histL, startL, NB);
  k_bucket_scatter<<<(N + 255) / 256, 256, 0, stream>>>(bucketL, startL, curL, slotL);
  k_bucket_rank<<<(N + 255) / 256, 256, 0, stream>>>(scoreL, bucketL, startL, histL, slotL, rankL, sortedL);

  // union mapping + edge remap + batch
  k_union_chunksum<<<NCHUNK, 1024, 0, stream>>>(rankF, rankL, csums);
  k_scan_small<<<1, 1024, 0, stream>>>(csums, cstarts, NCHUNK);
  k_union_map<<<NCHUNK, 1024, 0, stream>>>(rankF, rankL, cstarts, batch, mapping, outB);
  k_edge_out<<<(E_ + 255) / 256, 256, 0, stream>>>(ei, mapping, outE);

  // fused features: A[feat_idx[i]] = fuse2[i] (src=local), B[local_idx[i]] = fuse1[i] (src=feat)
  // launch 1 pure-stores (targets unique, d_out zeroed); launch 2 accumulates.
  k_fuse64<<<KSEL / 64, 256, 0, stream>>>(x, tw, tb, SW, HW, gdot, aDot, cid, sortedL, sortedF, ab, outF, 0);
  k_fuse64<<<KSEL / 64, 256, 0, stream>>>(x, tw, tb, SW, HW, gdot, aDot, cid, sortedF, sortedL, ab, outF, 1);
  k_half<<<(N * D) / 256, 256, 0, stream>>>(rankF, rankL, outF);
}

// Round 5
// 695.884 us; speedup vs baseline: 1.7683x; 1.0763x over previous
//
#include <hip/hip_runtime.h>
#include <hip/hip_bf16.h>
#include <stdint.h>

#define N 100000
#define E_ 1600000
#define D 128
#define C_ 256
#define HID 64
#define KSEL 80000
#define NB 4096
#define CHUNK 1024
#define NCHUNK ((N + CHUNK - 1) / CHUNK)   // 98
#define CSEG 32                            // segments per cluster for mean reduction
#define NBK 782                            // ceil(N/128) dst-buckets of 128 nodes
#define BCAP 2560                          // per-bucket capacity (avg 2046 + >11 sigma)

// ---- ordered-float encoding (monotonic increasing uint) ----
__device__ __forceinline__ unsigned enc_f(float f) {
  unsigned b = __float_as_uint(f);
  return (b & 0x80000000u) ? ~b : (b | 0x80000000u);
}
__device__ __forceinline__ float dec_f(unsigned u) {
  unsigned b = (u & 0x80000000u) ? (u ^ 0x80000000u) : ~u;
  return __uint_as_float(b);
}

// ======================= cluster CSR + means =======================
__global__ __launch_bounds__(256) void k_hist_cluster(const int* __restrict__ cid, int* __restrict__ ccount) {
  int n = blockIdx.x * 256 + threadIdx.x;
  if (n < N) atomicAdd(&ccount[cid[n]], 1);
}

__global__ __launch_bounds__(1024) void k_scan_small(const int* __restrict__ in, int* __restrict__ out, int n) {
  __shared__ int sums[1024];
  int t = threadIdx.x;
  int per = (n + 1023) / 1024;
  int base = t * per;
  int loc = 0;
  for (int k = 0; k < per; ++k) { int i = base + k; if (i < n) loc += in[i]; }
  sums[t] = loc; __syncthreads();
  for (int off = 1; off < 1024; off <<= 1) {
    int v = (t >= off) ? sums[t - off] : 0;
    __syncthreads();
    sums[t] += v;
    __syncthreads();
  }
  int run = (t == 0) ? 0 : sums[t - 1];
  for (int k = 0; k < per; ++k) { int i = base + k; if (i < n) { out[i] = run; run += in[i]; } }
}

__global__ __launch_bounds__(256) void k_scatter_cluster(const int* __restrict__ cid, const int* __restrict__ cstart,
                                                         int* __restrict__ ccur, int* __restrict__ cslot) {
  int n = blockIdx.x * 256 + threadIdx.x;
  if (n < N) {
    int c = cid[n];
    int p = cstart[c] + atomicAdd(&ccur[c], 1);
    cslot[p] = n;
  }
}

// Parallel cluster mean: CSEG segment-blocks per cluster -> register partials
// -> one float atomicAdd per (c,d) into zeroed Hc.
__global__ __launch_bounds__(128) void k_cluster_partial(const float* __restrict__ x, const int* __restrict__ cstart,
                                                         const int* __restrict__ ccount, const int* __restrict__ cslot,
                                                         float* __restrict__ Hc) {
  int c = blockIdx.x >> 5;
  int s = blockIdx.x & (CSEG - 1);
  int d = threadIdx.x;
  int st = cstart[c], cnt = ccount[c];
  int seg = (cnt + CSEG - 1) / CSEG;
  int lo = s * seg;
  int hi = min(cnt, lo + seg);
  if (lo >= hi) return;
  float acc = 0.f;
  int k = lo;
  for (; k + 2 <= hi; k += 2) {
    int n0 = cslot[st + k], n1 = cslot[st + k + 1];
    float v0 = x[(size_t)n0 * D + d];
    float v1 = x[(size_t)n1 * D + d];
    acc += v0 + v1;
  }
  if (k < hi) acc += x[(size_t)cslot[st + k] * D + d];
  atomicAdd(&Hc[(size_t)c * D + d], acc);
}

__global__ __launch_bounds__(256) void k_mean_div(const int* __restrict__ ccount, float* __restrict__ Hc) {
  int i = blockIdx.x * 256 + threadIdx.x;  // over C_*D
  int c = i >> 7;
  Hc[i] /= (float)max(ccount[c], 1);
}

__global__ __launch_bounds__(64) void k_gdot(const float* __restrict__ Hc, const float* __restrict__ wb,
                                             float* __restrict__ gdot) {
  int c = blockIdx.x; int l = threadIdx.x;
  float v = Hc[c * D + l] * wb[l] + Hc[c * D + 64 + l] * wb[64 + l];
  for (int off = 32; off; off >>= 1) v += __shfl_down(v, off);
  if (l == 0) gdot[c] = v;
}

__global__ __launch_bounds__(128) void k_S(const float* __restrict__ Hc, float* __restrict__ S) {
  int d = threadIdx.x;
  float s = 0.f;
  for (int c = 0; c < C_; ++c) s += Hc[c * D + d];
  S[d] = s;
}

// block 0 -> SW = S @ tw ; blocks 1..C_ -> HW[b-1] = Hc[b-1] @ tw
__global__ __launch_bounds__(128) void k_SW_HW(const float* __restrict__ S, const float* __restrict__ Hc,
                                               const float* __restrict__ tw, float* __restrict__ SW,
                                               float* __restrict__ HW) {
  int c = threadIdx.x;
  int b = blockIdx.x;
  const float* src = (b == 0) ? S : (Hc + (size_t)(b - 1) * D);
  float acc = 0.f;
  for (int d = 0; d < D; ++d) acc = fmaf(src[d], tw[d * D + c], acc);
  if (b == 0) SW[c] = acc; else HW[(size_t)(b - 1) * D + c] = acc;
}

// ======== fused per-node scores: MLP (feature view) + GAT h/aDot ========
// 64 rows/block staged in LDS; 8-row x 2-hid register tile per thread for the
// x@W1 GEMM (LDS reads are wave-broadcast b128, conflict-free); shfl_xor
// butterfly over the 32 col-lanes for the w2 contraction and the gw/wa dots.
__global__ __launch_bounds__(256, 4) void k_score64(const float* __restrict__ x, const float* __restrict__ w1,
                                                    const float* __restrict__ b1, const float* __restrict__ w2,
                                                    const float* __restrict__ b2, const float* __restrict__ gw,
                                                    const float* __restrict__ wa, float* __restrict__ scoreF,
                                                    float* __restrict__ hg, float* __restrict__ aDot) {
  __shared__ float xld[64 * D];  // 32 KB
  int tid = threadIdx.x;
  int base = blockIdx.x * 64;
  // stage 64 rows (2048 float4, 8 per thread)
#pragma unroll
  for (int k = 0; k < 8; ++k) {
    int i = k * 256 + tid;
    int r = i >> 5, off = i & 31;
    int n = base + r;
    float4 v = make_float4(0.f, 0.f, 0.f, 0.f);
    if (n < N) v = ((const float4*)(x + (size_t)n * D))[off];
    ((float4*)xld)[i] = v;
  }
  __syncthreads();

  int rg = tid >> 5;        // 8 row-groups of 8 rows
  int cg = tid & 31;        // 32 col-groups of 2 hid cols
  int c2 = cg * 2;
  float acc[8][2] = {};
  const float* xb = xld + rg * 8 * D;
  for (int d4 = 0; d4 < D; d4 += 4) {
    float2 wv0 = *(const float2*)(w1 + (size_t)(d4 + 0) * HID + c2);
    float2 wv1 = *(const float2*)(w1 + (size_t)(d4 + 1) * HID + c2);
    float2 wv2 = *(const float2*)(w1 + (size_t)(d4 + 2) * HID + c2);
    float2 wv3 = *(const float2*)(w1 + (size_t)(d4 + 3) * HID + c2);
#pragma unroll
    for (int r = 0; r < 8; ++r) {
      float4 xv = *(const float4*)(xb + r * D + d4);
      acc[r][0] = fmaf(xv.x, wv0.x, acc[r][0]);
      acc[r][1] = fmaf(xv.x, wv0.y, acc[r][1]);
      acc[r][0] = fmaf(xv.y, wv1.x, acc[r][0]);
      acc[r][1] = fmaf(xv.y, wv1.y, acc[r][1]);
      acc[r][0] = fmaf(xv.z, wv2.x, acc[r][0]);
      acc[r][1] = fmaf(xv.z, wv2.y, acc[r][1]);
      acc[r][0] = fmaf(xv.w, wv3.x, acc[r][0]);
      acc[r][1] = fmaf(xv.w, wv3.y, acc[r][1]);
    }
  }
  float2 b1v = *(const float2*)(b1 + c2);
  float2 w2v = *(const float2*)(w2 + c2);
  float bb = b2[0];
#pragma unroll
  for (int r = 0; r < 8; ++r) {
    float p = fmaxf(acc[r][0] + b1v.x, 0.f) * w2v.x + fmaxf(acc[r][1] + b1v.y, 0.f) * w2v.y;
#pragma unroll
    for (int off = 16; off; off >>= 1) p += __shfl_xor(p, off);
    if (cg == 0) {
      int n = base + rg * 8 + r;
      if (n < N) scoreF[n] = p + bb;
    }
  }
  // GAT projections from the same staged tile: lane cg covers d in [cg*4, cg*4+4)
  float4 gwv = *(const float4*)(gw + cg * 4);
  float4 wav = *(const float4*)(wa + cg * 4);
#pragma unroll
  for (int r = 0; r < 8; ++r) {
    int row = rg * 8 + r;
    float4 xv = *(const float4*)(xld + row * D + cg * 4);
    float hp = xv.x * gwv.x + xv.y * gwv.y + xv.z * gwv.z + xv.w * gwv.w;
    float ap = xv.x * wav.x + xv.y * wav.y + xv.z * wav.z + xv.w * wav.w;
#pragma unroll
    for (int off = 16; off; off >>= 1) {
      hp += __shfl_xor(hp, off);
      ap += __shfl_xor(ap, off);
    }
    if (cg == 0) {
      int n = base + row;
      if (n < N) { hg[n] = hp; aDot[n] = ap; }
    }
  }
}

// Bucket edges by dst>>7 into fixed-CAP regions. LDS-aggregated reservation.
// Record: .x = bits(e), .y = src | (dstloc << 24).
__global__ __launch_bounds__(1024) void k_escatter(const int* __restrict__ ei, const float* __restrict__ hg,
                                                   const float* __restrict__ asrc, const float* __restrict__ adst,
                                                   int* __restrict__ gcnt, uint2* __restrict__ payload) {
  __shared__ int lcnt[NBK];
  __shared__ int lbase[NBK];
  int tid = threadIdx.x;
  for (int i = tid; i < NBK; i += 1024) lcnt[i] = 0;
  int e0 = blockIdx.x * 8192;
  int es[8], ed[8];
#pragma unroll
  for (int k = 0; k < 8; ++k) {
    int e = e0 + k * 1024 + tid;
    bool v = (e < E_);
    es[k] = v ? ei[e] : -1;
    ed[k] = v ? ei[E_ + e] : -1;
  }
  __syncthreads();
#pragma unroll
  for (int k = 0; k < 8; ++k)
    if (ed[k] >= 0) atomicAdd(&lcnt[ed[k] >> 7], 1);
  __syncthreads();
  for (int i = tid; i < NBK; i += 1024) {
    int c = lcnt[i];
    lbase[i] = c ? atomicAdd(&gcnt[i], c) : 0;
    lcnt[i] = 0;
  }
  __syncthreads();
  float as = asrc[0], ad = adst[0];
#pragma unroll
  for (int k = 0; k < 8; ++k) {
    if (ed[k] < 0) continue;
    int s = es[k], d = ed[k];
    int b = d >> 7, dl = d & 127;
    float z = as * hg[s] + ad * hg[d];
    float ev = (z > 0.f) ? z : 0.2f * z;
    int pos = lbase[b] + atomicAdd(&lcnt[b], 1);
    if (pos < BCAP) {
      uint2 rec;
      rec.x = __float_as_uint(ev);
      rec.y = (unsigned)s | ((unsigned)dl << 24);
      payload[(size_t)b * BCAP + pos] = rec;
    }
  }
}

// Per-bucket GAT softmax entirely in LDS: max -> den -> alpha*h; writes scoreL.
__global__ __launch_bounds__(256) void k_esoftmax(const uint2* __restrict__ payload, const int* __restrict__ gcnt,
                                                  const float* __restrict__ hg, const float* __restrict__ gb,
                                                  float* __restrict__ scoreL) {
  __shared__ unsigned mS[128];
  __shared__ float dS[128];
  __shared__ float nS[128];
  int b = blockIdx.x;
  int tid = threadIdx.x;
  if (tid < 128) { mS[tid] = 0u; dS[tid] = 0.f; nS[tid] = 0.f; }
  __syncthreads();
  int cnt = min(gcnt[b], BCAP);
  const uint2* bp = payload + (size_t)b * BCAP;
  for (int i = tid; i < cnt; i += 256) {
    uint2 r = bp[i];
    atomicMax(&mS[r.y >> 24], enc_f(__uint_as_float(r.x)));
  }
  __syncthreads();
  for (int i = tid; i < cnt; i += 256) {
    uint2 r = bp[i];
    int d = r.y >> 24;
    float ex = expf(__uint_as_float(r.x) - dec_f(mS[d]));
    atomicAdd(&dS[d], ex);
  }
  __syncthreads();
  for (int i = tid; i < cnt; i += 256) {
    uint2 r = bp[i];
    int d = r.y >> 24;
    float ex = expf(__uint_as_float(r.x) - dec_f(mS[d]));
    float alpha = ex / fmaxf(dS[d], 1e-16f);
    float h = hg[r.y & 0xFFFFFFu];
    atomicAdd(&nS[d], alpha * h);
  }
  __syncthreads();
  if (tid < 128) {
    int dst = b * 128 + tid;
    if (dst < N) scoreL[dst] = nS[tid] + gb[0];
  }
}

// ======================= exact top-k ranking =======================
__global__ __launch_bounds__(256) void k_minmax(const float* __restrict__ sc, unsigned* __restrict__ mm) {
  __shared__ unsigned smx[256], smn[256];
  int t = threadIdx.x; int n = blockIdx.x * 256 + t;
  unsigned v = (n < N) ? enc_f(sc[n]) : 0u;
  smx[t] = (n < N) ? v : 0u;
  smn[t] = (n < N) ? v : 0xFFFFFFFFu;
  __syncthreads();
  for (int off = 128; off; off >>= 1) {
    if (t < off) {
      smx[t] = max(smx[t], smx[t + off]);
      smn[t] = min(smn[t], smn[t + off]);
    }
    __syncthreads();
  }
  if (t == 0) { atomicMax(&mm[0], smx[0]); atomicMin(&mm[1], smn[0]); }
}

__global__ __launch_bounds__(256) void k_bucket_hist(const float* __restrict__ sc, const unsigned* __restrict__ mm,
                                                     int* __restrict__ bucket, int* __restrict__ hist) {
  int n = blockIdx.x * 256 + threadIdx.x;
  if (n >= N) return;
  float smax = dec_f(mm[0]), smin = dec_f(mm[1]);
  float range = smax - smin;
  float scale = (range > 0.f) ? ((float)NB / range) : 0.f;
  float t = (smax - sc[n]) * scale;
  int b = (int)t;
  b = b < 0 ? 0 : (b > NB - 1 ? NB - 1 : b);
  bucket[n] = b;
  atomicAdd(&hist[b], 1);
}

__global__ __launch_bounds__(256) void k_bucket_scatter(const int* __restrict__ bucket, const int* __restrict__ start,
                                                        int* __restrict__ cur, int* __restrict__ slot) {
  int n = blockIdx.x * 256 + threadIdx.x;
  if (n >= N) return;
  int b = bucket[n];
  slot[start[b] + atomicAdd(&cur[b], 1)] = n;
}

__global__ __launch_bounds__(256) void k_bucket_rank(const float* __restrict__ sc, const int* __restrict__ bucket,
                                                     const int* __restrict__ start, const int* __restrict__ hist,
                                                     const int* __restrict__ slot, int* __restrict__ rank,
                                                     int* __restrict__ sorted) {
  int n = blockIdx.x * 256 + threadIdx.x;
  if (n >= N) return;
  int b = bucket[n];
  int st = start[b], cnt = hist[b];
  unsigned long long mykey = (((unsigned long long)(~enc_f(sc[n]))) << 32) | (unsigned)n;
  int r = 0;
  for (int j = 0; j < cnt; ++j) {
    int m = slot[st + j];
    unsigned long long k = (((unsigned long long)(~enc_f(sc[m]))) << 32) | (unsigned)m;
    r += (k < mykey) ? 1 : 0;
  }
  rank[n] = st + r;
  sorted[st + r] = n;
}

// ======================= union mapping =======================
__global__ __launch_bounds__(1024) void k_union_chunksum(const int* __restrict__ rankF, const int* __restrict__ rankL,
                                                         int* __restrict__ csum) {
  __shared__ int red[1024];
  int t = threadIdx.x; int i = blockIdx.x * 1024 + t;
  int u = (i < N) ? (((rankF[i] < KSEL) || (rankL[i] < KSEL)) ? 1 : 0) : 0;
  red[t] = u; __syncthreads();
  for (int off = 512; off; off >>= 1) { if (t < off) red[t] += red[t + off]; __syncthreads(); }
  if (t == 0) csum[blockIdx.x] = red[0];
}

__global__ __launch_bounds__(1024) void k_union_map(const int* __restrict__ rankF, const int* __restrict__ rankL,
                                                    const int* __restrict__ cstart, const int* __restrict__ batch,
                                                    int* __restrict__ mapping, float* __restrict__ outBatch) {
  __shared__ int sums[1024];
  int t = threadIdx.x; int i = blockIdx.x * 1024 + t;
  int u = (i < N) ? (((rankF[i] < KSEL) || (rankL[i] < KSEL)) ? 1 : 0) : 0;
  sums[t] = u; __syncthreads();
  for (int off = 1; off < 1024; off <<= 1) {
    int v = (t >= off) ? sums[t - off] : 0;
    __syncthreads();
    sums[t] += v;
    __syncthreads();
  }
  if (i < N) {
    mapping[i] = u ? (cstart[blockIdx.x] + sums[t] - 1) : -1;
    outBatch[i] = u ? (float)batch[i] : -1.0f;
  }
}

__global__ __launch_bounds__(256) void k_edge_out(const int* __restrict__ ei, const int* __restrict__ mapping,
                                                  float* __restrict__ outE) {
  int e = blockIdx.x * 256 + threadIdx.x;
  if (e >= E_) return;
  int m0 = mapping[ei[e]], m1 = mapping[ei[E_ + e]];
  bool valid = (m0 >= 0) && (m1 >= 0);
  outE[e] = valid ? (float)m0 : -1.f;
  outE[E_ + e] = valid ? (float)m1 : -1.f;
}

// ======================= fused GCN transform + scatter =======================
// Fp[tgtL[i]] (+)= relu( x[srcL[i]] @ tw + tb + q*SW + (p-q)*HW[cid[srcL[i]]] )
// accum launch also folds the "(A+B)*0.5 where both" step: in that launch every
// tgt has rankL<K, so both <=> rankF[tgt]<K.
__global__ __launch_bounds__(256, 4) void k_fuse64(const float* __restrict__ x, const float* __restrict__ tw,
                                                   const float* __restrict__ tb, const float* __restrict__ SW,
                                                   const float* __restrict__ HW, const float* __restrict__ gdot,
                                                   const float* __restrict__ aDot, const int* __restrict__ cid,
                                                   const int* __restrict__ srcL, const int* __restrict__ tgtL,
                                                   const float* __restrict__ attb, const int* __restrict__ rankF,
                                                   float* __restrict__ Fp, int accum) {
  __shared__ float xld[64 * D];
  __shared__ float pq[64 * 2];
  __shared__ int mt[64 * 2];
  int tid = threadIdx.x;
  int base = blockIdx.x * 64;
  if (tid < 64) {
    int ws = srcL[base + tid];
    int cc = cid[ws];
    mt[tid * 2] = cc;
    mt[tid * 2 + 1] = tgtL[base + tid];
    float s = aDot[ws] + gdot[cc] + attb[0];
    float mx = fmaxf(s, 0.f);
    float esm = expf(s - mx), eom = expf(-mx);
    float dn = esm + 255.f * eom;
    pq[tid * 2] = esm / dn;
    pq[tid * 2 + 1] = eom / dn;
  }
  // stage 64 x-rows (2048 float4, 8 per thread)
#pragma unroll
  for (int k = 0; k < 8; ++k) {
    int i = k * 256 + tid;
    int r = i >> 5, off = i & 31;
    int ws = srcL[base + r];
    ((float4*)xld)[i] = ((const float4*)(x + (size_t)ws * D))[off];
  }
  __syncthreads();

  int rg = tid >> 5;        // 8 row-groups of 8 rows
  int c4 = (tid & 31) * 4;  // 32 col-groups of 4 cols
  float acc[8][4] = {};
  const float* xb = xld + rg * 8 * D;
  for (int d4 = 0; d4 < D; d4 += 4) {
    float4 t0 = *(const float4*)(tw + (size_t)(d4 + 0) * D + c4);
    float4 t1 = *(const float4*)(tw + (size_t)(d4 + 1) * D + c4);
    float4 t2 = *(const float4*)(tw + (size_t)(d4 + 2) * D + c4);
    float4 t3 = *(const float4*)(tw + (size_t)(d4 + 3) * D + c4);
#pragma unroll
    for (int r = 0; r < 8; ++r) {
      float4 xv = *(const float4*)(xb + r * D + d4);
      acc[r][0] = fmaf(xv.x, t0.x, acc[r][0]);
      acc[r][1] = fmaf(xv.x, t0.y, acc[r][1]);
      acc[r][2] = fmaf(xv.x, t0.z, acc[r][2]);
      acc[r][3] = fmaf(xv.x, t0.w, acc[r][3]);
      acc[r][0] = fmaf(xv.y, t1.x, acc[r][0]);
      acc[r][1] = fmaf(xv.y, t1.y, acc[r][1]);
      acc[r][2] = fmaf(xv.y, t1.z, acc[r][2]);
      acc[r][3] = fmaf(xv.y, t1.w, acc[r][3]);
      acc[r][0] = fmaf(xv.z, t2.x, acc[r][0]);
      acc[r][1] = fmaf(xv.z, t2.y, acc[r][1]);
      acc[r][2] = fmaf(xv.z, t2.z, acc[r][2]);
      acc[r][3] = fmaf(xv.z, t2.w, acc[r][3]);
      acc[r][0] = fmaf(xv.w, t3.x, acc[r][0]);
      acc[r][1] = fmaf(xv.w, t3.y, acc[r][1]);
      acc[r][2] = fmaf(xv.w, t3.z, acc[r][2]);
      acc[r][3] = fmaf(xv.w, t3.w, acc[r][3]);
    }
  }

  float4 tbv = *(const float4*)(tb + c4);
  float4 swv = *(const float4*)(SW + c4);
#pragma unroll
  for (int r = 0; r < 8; ++r) {
    int row = rg * 8 + r;
    float p = pq[row * 2], q = pq[row * 2 + 1];
    int cc = mt[row * 2];
    int tgt = mt[row * 2 + 1];
    float4 hw = *(const float4*)(HW + (size_t)cc * D + c4);
    float4 o;
    o.x = fmaxf(acc[r][0] + tbv.x + q * swv.x + (p - q) * hw.x, 0.f);
    o.y = fmaxf(acc[r][1] + tbv.y + q * swv.y + (p - q) * hw.y, 0.f);
    o.z = fmaxf(acc[r][2] + tbv.z + q * swv.z + (p - q) * hw.z, 0.f);
    o.w = fmaxf(acc[r][3] + tbv.w + q * swv.w + (p - q) * hw.w, 0.f);
    float4* dst = (float4*)(Fp + (size_t)tgt * D + c4);
    if (accum) {
      float4 old = *dst;
      o.x += old.x; o.y += old.y; o.z += old.z; o.w += old.w;
      if (rankF[tgt] < KSEL) { o.x *= 0.5f; o.y *= 0.5f; o.z *= 0.5f; o.w *= 0.5f; }
    }
    *dst = o;
  }
}

// ======================= launcher =======================
extern "C" void kernel_launch(void* const* d_in, const int* in_sizes, int n_in,
                              void* d_out, int out_size, void* d_ws, size_t ws_size,
                              hipStream_t stream) {
  const float* x   = (const float*)d_in[0];
  const int* ei    = (const int*)d_in[1];
  const int* batch = (const int*)d_in[2];
  const int* cid   = (const int*)d_in[3];
  const float* w1  = (const float*)d_in[4];
  const float* b1  = (const float*)d_in[5];
  const float* w2  = (const float*)d_in[6];
  const float* b2  = (const float*)d_in[7];
  const float* gw  = (const float*)d_in[8];
  const float* gas = (const float*)d_in[9];
  const float* gad = (const float*)d_in[10];
  const float* gb  = (const float*)d_in[11];
  const float* wa  = (const float*)d_in[12];
  const float* wb  = (const float*)d_in[13];
  const float* ab  = (const float*)d_in[14];
  const float* tw  = (const float*)d_in[15];
  const float* tb  = (const float*)d_in[16];
  (void)in_sizes; (void)n_in; (void)ws_size;

  char* p = (char*)d_ws;
  auto alloc = [&](size_t bytes) -> char* {
    char* r = p;
    p += (bytes + 255) & ~(size_t)255;
    return r;
  };
  // ---- zero-init region (memset below covers up to zeroBytes) ----
  int* ccount    = (int*)alloc(C_ * 4);
  int* ccur      = (int*)alloc(C_ * 4);
  unsigned* mmF  = (unsigned*)alloc(16);
  unsigned* mmL  = (unsigned*)alloc(16);
  int* histF     = (int*)alloc(NB * 4);
  int* histL     = (int*)alloc(NB * 4);
  int* curF      = (int*)alloc(NB * 4);
  int* curL      = (int*)alloc(NB * 4);
  float* Hc      = (float*)alloc((size_t)C_ * D * 4);   // atomic accumulator -> must be zeroed
  int* gcnt      = (int*)alloc(NBK * 4);                // bucket cursors
  size_t zeroBytes = (size_t)(p - (char*)d_ws);
  // ---- rest (fully written before read) ----
  int* cstart   = (int*)alloc(C_ * 4);
  int* cslot    = (int*)alloc((size_t)N * 4);
  float* gdot   = (float*)alloc(C_ * 4);
  float* S      = (float*)alloc(D * 4);
  float* SW     = (float*)alloc(D * 4);
  float* HW     = (float*)alloc((size_t)C_ * D * 4);
  float* scoreF = (float*)alloc((size_t)N * 4);
  float* scoreL = (float*)alloc((size_t)N * 4);
  float* hg     = (float*)alloc((size_t)N * 4);
  float* aDot   = (float*)alloc((size_t)N * 4);
  uint2* payload = (uint2*)alloc((size_t)NBK * BCAP * 8);
  int* bucketF  = (int*)alloc((size_t)N * 4);
  int* bucketL  = (int*)alloc((size_t)N * 4);
  int* startF   = (int*)alloc(NB * 4);
  int* startL   = (int*)alloc(NB * 4);
  int* slotF    = (int*)alloc((size_t)N * 4);
  int* slotL    = (int*)alloc((size_t)N * 4);
  int* sortedF  = (int*)alloc((size_t)N * 4);
  int* sortedL  = (int*)alloc((size_t)N * 4);
  int* rankF    = (int*)alloc((size_t)N * 4);
  int* rankL    = (int*)alloc((size_t)N * 4);
  int* csums    = (int*)alloc(NCHUNK * 4);
  int* cstarts  = (int*)alloc(NCHUNK * 4);
  int* mapping  = (int*)alloc((size_t)N * 4);

  float* outF = (float*)d_out;             // [N, D]
  float* outE = outF + (size_t)N * D;      // [2, E]
  float* outB = outE + (size_t)2 * E_;     // [N]

  hipMemsetAsync(d_ws, 0, zeroBytes, stream);
  hipMemsetAsync(d_out, 0, (size_t)out_size * sizeof(float), stream);
  hipMemsetAsync(mmF + 1, 0xFF, 4, stream);  // min slot -> 0xFFFFFFFF
  hipMemsetAsync(mmL + 1, 0xFF, 4, stream);

  // cluster means + derived
  k_hist_cluster<<<(N + 255) / 256, 256, 0, stream>>>(cid, ccount);
  k_scan_small<<<1, 1024, 0, stream>>>(ccount, cstart, C_);
  k_scatter_cluster<<<(N + 255) / 256, 256, 0, stream>>>(cid, cstart, ccur, cslot);
  k_cluster_partial<<<C_ * CSEG, 128, 0, stream>>>(x, cstart, ccount, cslot, Hc);
  k_mean_div<<<(C_ * D) / 256, 256, 0, stream>>>(ccount, Hc);
  k_gdot<<<C_, 64, 0, stream>>>(Hc, wb, gdot);
  k_S<<<1, 128, 0, stream>>>(Hc, S);
  k_SW_HW<<<C_ + 1, 128, 0, stream>>>(S, Hc, tw, SW, HW);

  // fused per-node scores (MLP + GAT projections)
  k_score64<<<(N + 63) / 64, 256, 0, stream>>>(x, w1, b1, w2, b2, gw, wa, scoreF, hg, aDot);
  k_escatter<<<(E_ + 8191) / 8192, 1024, 0, stream>>>(ei, hg, gas, gad, gcnt, payload);
  k_esoftmax<<<NBK, 256, 0, stream>>>(payload, gcnt, hg, gb, scoreL);

  // exact ranking, feature view
  k_minmax<<<(N + 255) / 256, 256, 0, stream>>>(scoreF, mmF);
  k_bucket_hist<<<(N + 255) / 256, 256, 0, stream>>>(scoreF, mmF, bucketF, histF);
  k_scan_small<<<1, 1024, 0, stream>>>(histF, startF, NB);
  k_bucket_scatter<<<(N + 255) / 256, 256, 0, stream>>>(bucketF, startF, curF, slotF);
  k_bucket_rank<<<(N + 255) / 256, 256, 0, stream>>>(scoreF, bucketF, startF, histF, slotF, rankF, sortedF);
  // exact ranking, local view
  k_minmax<<<(N + 255) / 256, 256, 0, stream>>>(scoreL, mmL);
  k_bucket_hist<<<(N + 255) / 256, 256, 0, stream>>>(scoreL, mmL, bucketL, histL);
  k_scan_small<<<1, 1024, 0, stream>>>(histL, startL, NB);
  k_bucket_scatter<<<(N + 255) / 256, 256, 0, stream>>>(bucketL, startL, curL, slotL);
  k_bucket_rank<<<(N + 255) / 256, 256, 0, stream>>>(scoreL, bucketL, startL, histL, slotL, rankL, sortedL);

  // union mapping + edge remap + batch
  k_union_chunksum<<<NCHUNK, 1024, 0, stream>>>(rankF, rankL, csums);
  k_scan_small<<<1, 1024, 0, stream>>>(csums, cstarts, NCHUNK);
  k_union_map<<<NCHUNK, 1024, 0, stream>>>(rankF, rankL, cstarts, batch, mapping, outB);
  k_edge_out<<<(E_ + 255) / 256, 256, 0, stream>>>(ei, mapping, outE);

  // fused features: A[feat_idx[i]] = fuse2[i] (src=local), B[local_idx[i]] = fuse1[i] (src=feat)
  // launch 1 pure-stores (targets unique, d_out zeroed); launch 2 accumulates + folds *0.5.
  k_fuse64<<<KSEL / 64, 256, 0, stream>>>(x, tw, tb, SW, HW, gdot, aDot, cid, sortedL, sortedF, ab, rankF, outF, 0);
  k_fuse64<<<KSEL / 64, 256, 0, stream>>>(x, tw, tb, SW, HW, gdot, aDot, cid, sortedF, sortedL, ab, rankF, outF, 1);
}

// Round 6
// 666.738 us; speedup vs baseline: 1.8456x; 1.0437x over previous
//
#include <hip/hip_runtime.h>
#include <hip/hip_bf16.h>
#include <stdint.h>

#define N 100000
#define E_ 1600000
#define D 128
#define C_ 256
#define HID 64
#define KSEL 80000
#define NB 4096
#define CHUNK 1024
#define NCHUNK ((N + CHUNK - 1) / CHUNK)   // 98
#define CSEG 32                            // segments per cluster for mean reduction
#define NBK 782                            // ceil(N/128) dst-buckets of 128 nodes
#define BCAP 2560                          // per-bucket capacity (avg 2046 + >11 sigma)

// ---- ordered-float encoding (monotonic increasing uint) ----
__device__ __forceinline__ unsigned enc_f(float f) {
  unsigned b = __float_as_uint(f);
  return (b & 0x80000000u) ? ~b : (b | 0x80000000u);
}
__device__ __forceinline__ float dec_f(unsigned u) {
  unsigned b = (u & 0x80000000u) ? (u ^ 0x80000000u) : ~u;
  return __uint_as_float(b);
}

// ======================= cluster CSR + means =======================
__global__ __launch_bounds__(256) void k_hist_cluster(const int* __restrict__ cid, int* __restrict__ ccount) {
  int n = blockIdx.x * 256 + threadIdx.x;
  if (n < N) atomicAdd(&ccount[cid[n]], 1);
}

// generic small scan; block b scans in[b*n .. b*n+n) -> out exclusive
__global__ __launch_bounds__(1024) void k_scan_small(const int* __restrict__ in0, int* __restrict__ out0, int n) {
  __shared__ int sums[1024];
  const int* in = in0 + (size_t)blockIdx.x * n;
  int* out = out0 + (size_t)blockIdx.x * n;
  int t = threadIdx.x;
  int per = (n + 1023) / 1024;
  int base = t * per;
  int loc = 0;
  for (int k = 0; k < per; ++k) { int i = base + k; if (i < n) loc += in[i]; }
  sums[t] = loc; __syncthreads();
  for (int off = 1; off < 1024; off <<= 1) {
    int v = (t >= off) ? sums[t - off] : 0;
    __syncthreads();
    sums[t] += v;
    __syncthreads();
  }
  int run = (t == 0) ? 0 : sums[t - 1];
  for (int k = 0; k < per; ++k) { int i = base + k; if (i < n) { out[i] = run; run += in[i]; } }
}

__global__ __launch_bounds__(256) void k_scatter_cluster(const int* __restrict__ cid, const int* __restrict__ cstart,
                                                         int* __restrict__ ccur, int* __restrict__ cslot) {
  int n = blockIdx.x * 256 + threadIdx.x;
  if (n < N) {
    int c = cid[n];
    int p = cstart[c] + atomicAdd(&ccur[c], 1);
    cslot[p] = n;
  }
}

__global__ __launch_bounds__(128) void k_cluster_partial(const float* __restrict__ x, const int* __restrict__ cstart,
                                                         const int* __restrict__ ccount, const int* __restrict__ cslot,
                                                         float* __restrict__ Hc) {
  int c = blockIdx.x >> 5;
  int s = blockIdx.x & (CSEG - 1);
  int d = threadIdx.x;
  int st = cstart[c], cnt = ccount[c];
  int seg = (cnt + CSEG - 1) / CSEG;
  int lo = s * seg;
  int hi = min(cnt, lo + seg);
  if (lo >= hi) return;
  float acc = 0.f;
  int k = lo;
  for (; k + 2 <= hi; k += 2) {
    int n0 = cslot[st + k], n1 = cslot[st + k + 1];
    float v0 = x[(size_t)n0 * D + d];
    float v1 = x[(size_t)n1 * D + d];
    acc += v0 + v1;
  }
  if (k < hi) acc += x[(size_t)cslot[st + k] * D + d];
  atomicAdd(&Hc[(size_t)c * D + d], acc);
}

// divide Hc by counts, then gdot[c] = Hc[c] . wb  (merged, one launch)
__global__ __launch_bounds__(128) void k_mean_gdot(const int* __restrict__ ccount, const float* __restrict__ wb,
                                                   float* __restrict__ Hc, float* __restrict__ gdot) {
  __shared__ float red[128];
  int c = blockIdx.x, d = threadIdx.x;
  float hv = Hc[(size_t)c * D + d] / (float)max(ccount[c], 1);
  Hc[(size_t)c * D + d] = hv;
  red[d] = hv * wb[d];
  __syncthreads();
  if (d < 64) {
    float v = red[d] + red[d + 64];
    for (int off = 32; off; off >>= 1) v += __shfl_down(v, off);
    if (d == 0) gdot[c] = v;
  }
}

// block 0: S = sum_c Hc[c], SW = S @ tw ; blocks 1..C_: HW[b-1] = Hc[b-1] @ tw
__global__ __launch_bounds__(128) void k_S_SW_HW(const float* __restrict__ Hc, const float* __restrict__ tw,
                                                 float* __restrict__ SW, float* __restrict__ HW) {
  __shared__ float Sl[128];
  int b = blockIdx.x, t = threadIdx.x;
  if (b == 0) {
    float s = 0.f;
    for (int c = 0; c < C_; ++c) s += Hc[(size_t)c * D + t];
    Sl[t] = s;
    __syncthreads();
    float acc = 0.f;
    for (int d = 0; d < D; ++d) acc = fmaf(Sl[d], tw[(size_t)d * D + t], acc);
    SW[t] = acc;
  } else {
    const float* src = Hc + (size_t)(b - 1) * D;
    float acc = 0.f;
    for (int d = 0; d < D; ++d) acc = fmaf(src[d], tw[(size_t)d * D + t], acc);
    HW[(size_t)(b - 1) * D + t] = acc;
  }
}

// ======== fused per-node scores: MLP (feature view) + GAT h/aDot ========
__global__ __launch_bounds__(256, 4) void k_score64(const float* __restrict__ x, const float* __restrict__ w1,
                                                    const float* __restrict__ b1, const float* __restrict__ w2,
                                                    const float* __restrict__ b2, const float* __restrict__ gw,
                                                    const float* __restrict__ wa, float* __restrict__ scoreF,
                                                    float* __restrict__ hg, float* __restrict__ aDot) {
  __shared__ float xld[64 * D];  // 32 KB
  int tid = threadIdx.x;
  int base = blockIdx.x * 64;
#pragma unroll
  for (int k = 0; k < 8; ++k) {
    int i = k * 256 + tid;
    int r = i >> 5, off = i & 31;
    int n = base + r;
    float4 v = make_float4(0.f, 0.f, 0.f, 0.f);
    if (n < N) v = ((const float4*)(x + (size_t)n * D))[off];
    ((float4*)xld)[i] = v;
  }
  __syncthreads();

  int rg = tid >> 5;        // 8 row-groups of 8 rows
  int cg = tid & 31;        // 32 col-groups of 2 hid cols
  int c2 = cg * 2;
  float acc[8][2] = {};
  const float* xb = xld + rg * 8 * D;
  for (int d4 = 0; d4 < D; d4 += 4) {
    float2 wv0 = *(const float2*)(w1 + (size_t)(d4 + 0) * HID + c2);
    float2 wv1 = *(const float2*)(w1 + (size_t)(d4 + 1) * HID + c2);
    float2 wv2 = *(const float2*)(w1 + (size_t)(d4 + 2) * HID + c2);
    float2 wv3 = *(const float2*)(w1 + (size_t)(d4 + 3) * HID + c2);
#pragma unroll
    for (int r = 0; r < 8; ++r) {
      float4 xv = *(const float4*)(xb + r * D + d4);
      acc[r][0] = fmaf(xv.x, wv0.x, acc[r][0]);
      acc[r][1] = fmaf(xv.x, wv0.y, acc[r][1]);
      acc[r][0] = fmaf(xv.y, wv1.x, acc[r][0]);
      acc[r][1] = fmaf(xv.y, wv1.y, acc[r][1]);
      acc[r][0] = fmaf(xv.z, wv2.x, acc[r][0]);
      acc[r][1] = fmaf(xv.z, wv2.y, acc[r][1]);
      acc[r][0] = fmaf(xv.w, wv3.x, acc[r][0]);
      acc[r][1] = fmaf(xv.w, wv3.y, acc[r][1]);
    }
  }
  float2 b1v = *(const float2*)(b1 + c2);
  float2 w2v = *(const float2*)(w2 + c2);
  float bb = b2[0];
#pragma unroll
  for (int r = 0; r < 8; ++r) {
    float p = fmaxf(acc[r][0] + b1v.x, 0.f) * w2v.x + fmaxf(acc[r][1] + b1v.y, 0.f) * w2v.y;
#pragma unroll
    for (int off = 16; off; off >>= 1) p += __shfl_xor(p, off);
    if (cg == 0) {
      int n = base + rg * 8 + r;
      if (n < N) scoreF[n] = p + bb;
    }
  }
  float4 gwv = *(const float4*)(gw + cg * 4);
  float4 wav = *(const float4*)(wa + cg * 4);
#pragma unroll
  for (int r = 0; r < 8; ++r) {
    int row = rg * 8 + r;
    float4 xv = *(const float4*)(xld + row * D + cg * 4);
    float hp = xv.x * gwv.x + xv.y * gwv.y + xv.z * gwv.z + xv.w * gwv.w;
    float ap = xv.x * wav.x + xv.y * wav.y + xv.z * wav.z + xv.w * wav.w;
#pragma unroll
    for (int off = 16; off; off >>= 1) {
      hp += __shfl_xor(hp, off);
      ap += __shfl_xor(ap, off);
    }
    if (cg == 0) {
      int n = base + row;
      if (n < N) { hg[n] = hp; aDot[n] = ap; }
    }
  }
}

// Bucket edges by dst>>7 with LDS-aggregated reservation.
__global__ __launch_bounds__(1024) void k_escatter(const int* __restrict__ ei, const float* __restrict__ hg,
                                                   const float* __restrict__ asrc, const float* __restrict__ adst,
                                                   int* __restrict__ gcnt, uint2* __restrict__ payload) {
  __shared__ int lcnt[NBK];
  __shared__ int lbase[NBK];
  int tid = threadIdx.x;
  for (int i = tid; i < NBK; i += 1024) lcnt[i] = 0;
  int e0 = blockIdx.x * 8192;
  int es[8], ed[8];
#pragma unroll
  for (int k = 0; k < 8; ++k) {
    int e = e0 + k * 1024 + tid;
    bool v = (e < E_);
    es[k] = v ? ei[e] : -1;
    ed[k] = v ? ei[E_ + e] : -1;
  }
  __syncthreads();
#pragma unroll
  for (int k = 0; k < 8; ++k)
    if (ed[k] >= 0) atomicAdd(&lcnt[ed[k] >> 7], 1);
  __syncthreads();
  for (int i = tid; i < NBK; i += 1024) {
    int c = lcnt[i];
    lbase[i] = c ? atomicAdd(&gcnt[i], c) : 0;
    lcnt[i] = 0;
  }
  __syncthreads();
  float as = asrc[0], ad = adst[0];
#pragma unroll
  for (int k = 0; k < 8; ++k) {
    if (ed[k] < 0) continue;
    int s = es[k], d = ed[k];
    int b = d >> 7, dl = d & 127;
    float z = as * hg[s] + ad * hg[d];
    float ev = (z > 0.f) ? z : 0.2f * z;
    int pos = lbase[b] + atomicAdd(&lcnt[b], 1);
    if (pos < BCAP) {
      uint2 rec;
      rec.x = __float_as_uint(ev);
      rec.y = (unsigned)s | ((unsigned)dl << 24);
      payload[(size_t)b * BCAP + pos] = rec;
    }
  }
}

// Per-bucket GAT softmax in LDS; writes scoreL.
__global__ __launch_bounds__(256) void k_esoftmax(const uint2* __restrict__ payload, const int* __restrict__ gcnt,
                                                  const float* __restrict__ hg, const float* __restrict__ gb,
                                                  float* __restrict__ scoreL) {
  __shared__ unsigned mS[128];
  __shared__ float dS[128];
  __shared__ float nS[128];
  int b = blockIdx.x;
  int tid = threadIdx.x;
  if (tid < 128) { mS[tid] = 0u; dS[tid] = 0.f; nS[tid] = 0.f; }
  __syncthreads();
  int cnt = min(gcnt[b], BCAP);
  const uint2* bp = payload + (size_t)b * BCAP;
  for (int i = tid; i < cnt; i += 256) {
    uint2 r = bp[i];
    atomicMax(&mS[r.y >> 24], enc_f(__uint_as_float(r.x)));
  }
  __syncthreads();
  for (int i = tid; i < cnt; i += 256) {
    uint2 r = bp[i];
    int d = r.y >> 24;
    float ex = expf(__uint_as_float(r.x) - dec_f(mS[d]));
    atomicAdd(&dS[d], ex);
  }
  __syncthreads();
  for (int i = tid; i < cnt; i += 256) {
    uint2 r = bp[i];
    int d = r.y >> 24;
    float ex = expf(__uint_as_float(r.x) - dec_f(mS[d]));
    float alpha = ex / fmaxf(dS[d], 1e-16f);
    float h = hg[r.y & 0xFFFFFFu];
    atomicAdd(&nS[d], alpha * h);
  }
  __syncthreads();
  if (tid < 128) {
    int dst = b * 128 + tid;
    if (dst < N) scoreL[dst] = nS[tid] + gb[0];
  }
}

// ========== exact top-k ranking, both views per launch (blockIdx.y) ==========
// mm layout: [maxF, maxL, minF, minL]
__global__ __launch_bounds__(256) void k_minmax2(const float* __restrict__ sc2, unsigned* __restrict__ mm) {
  __shared__ unsigned smx[256], smn[256];
  int v = blockIdx.y;
  const float* sc = sc2 + (size_t)v * N;
  int t = threadIdx.x; int n = blockIdx.x * 256 + t;
  unsigned val = (n < N) ? enc_f(sc[n]) : 0u;
  smx[t] = (n < N) ? val : 0u;
  smn[t] = (n < N) ? val : 0xFFFFFFFFu;
  __syncthreads();
  for (int off = 128; off; off >>= 1) {
    if (t < off) {
      smx[t] = max(smx[t], smx[t + off]);
      smn[t] = min(smn[t], smn[t + off]);
    }
    __syncthreads();
  }
  if (t == 0) { atomicMax(&mm[v], smx[0]); atomicMin(&mm[2 + v], smn[0]); }
}

__global__ __launch_bounds__(256) void k_bucket_hist2(const float* __restrict__ sc2, const unsigned* __restrict__ mm,
                                                      int* __restrict__ bucket2, int* __restrict__ hist2) {
  int v = blockIdx.y;
  int n = blockIdx.x * 256 + threadIdx.x;
  if (n >= N) return;
  const float* sc = sc2 + (size_t)v * N;
  float smax = dec_f(mm[v]), smin = dec_f(mm[2 + v]);
  float range = smax - smin;
  float scale = (range > 0.f) ? ((float)NB / range) : 0.f;
  float t = (smax - sc[n]) * scale;
  int b = (int)t;
  b = b < 0 ? 0 : (b > NB - 1 ? NB - 1 : b);
  bucket2[(size_t)v * N + n] = b;
  atomicAdd(&hist2[v * NB + b], 1);
}

__global__ __launch_bounds__(256) void k_bucket_scatter2(const int* __restrict__ bucket2, const int* __restrict__ start2,
                                                         int* __restrict__ cur2, int* __restrict__ slot2) {
  int v = blockIdx.y;
  int n = blockIdx.x * 256 + threadIdx.x;
  if (n >= N) return;
  int b = bucket2[(size_t)v * N + n];
  slot2[(size_t)v * N + start2[v * NB + b] + atomicAdd(&cur2[v * NB + b], 1)] = n;
}

__global__ __launch_bounds__(256) void k_bucket_rank2(const float* __restrict__ sc2, const int* __restrict__ bucket2,
                                                      const int* __restrict__ start2, const int* __restrict__ hist2,
                                                      const int* __restrict__ slot2, int* __restrict__ rank2,
                                                      int* __restrict__ sorted2) {
  int v = blockIdx.y;
  int n = blockIdx.x * 256 + threadIdx.x;
  if (n >= N) return;
  const float* sc = sc2 + (size_t)v * N;
  int b = bucket2[(size_t)v * N + n];
  int st = start2[v * NB + b], cnt = hist2[v * NB + b];
  const int* slot = slot2 + (size_t)v * N;
  unsigned long long mykey = (((unsigned long long)(~enc_f(sc[n]))) << 32) | (unsigned)n;
  int r = 0;
  for (int j = 0; j < cnt; ++j) {
    int m = slot[st + j];
    unsigned long long k = (((unsigned long long)(~enc_f(sc[m]))) << 32) | (unsigned)m;
    r += (k < mykey) ? 1 : 0;
  }
  rank2[(size_t)v * N + n] = st + r;
  sorted2[(size_t)v * N + st + r] = n;
}

// ======================= union mapping =======================
__global__ __launch_bounds__(1024) void k_union_chunksum(const int* __restrict__ rankF, const int* __restrict__ rankL,
                                                         int* __restrict__ csum) {
  __shared__ int red[1024];
  int t = threadIdx.x; int i = blockIdx.x * 1024 + t;
  int u = (i < N) ? (((rankF[i] < KSEL) || (rankL[i] < KSEL)) ? 1 : 0) : 0;
  red[t] = u; __syncthreads();
  for (int off = 512; off; off >>= 1) { if (t < off) red[t] += red[t + off]; __syncthreads(); }
  if (t == 0) csum[blockIdx.x] = red[0];
}

__global__ __launch_bounds__(1024) void k_union_map(const int* __restrict__ rankF, const int* __restrict__ rankL,
                                                    const int* __restrict__ cstart, const int* __restrict__ batch,
                                                    int* __restrict__ mapping, float* __restrict__ outBatch) {
  __shared__ int sums[1024];
  int t = threadIdx.x; int i = blockIdx.x * 1024 + t;
  int u = (i < N) ? (((rankF[i] < KSEL) || (rankL[i] < KSEL)) ? 1 : 0) : 0;
  sums[t] = u; __syncthreads();
  for (int off = 1; off < 1024; off <<= 1) {
    int v = (t >= off) ? sums[t - off] : 0;
    __syncthreads();
    sums[t] += v;
    __syncthreads();
  }
  if (i < N) {
    mapping[i] = u ? (cstart[blockIdx.x] + sums[t] - 1) : -1;
    outBatch[i] = u ? (float)batch[i] : -1.0f;
  }
}

__global__ __launch_bounds__(256) void k_edge_out(const int* __restrict__ ei, const int* __restrict__ mapping,
                                                  float* __restrict__ outE) {
  int e = blockIdx.x * 256 + threadIdx.x;
  if (e >= E_) return;
  int m0 = mapping[ei[e]], m1 = mapping[ei[E_ + e]];
  bool valid = (m0 >= 0) && (m1 >= 0);
  outE[e] = valid ? (float)m0 : -1.f;
  outE[E_ + e] = valid ? (float)m1 : -1.f;
}

// ======================= fused GCN transform + scatter =======================
// Fp[tgtL[i]] (+)= relu( x[srcL[i]] @ tw + tb + q*SW + (p-q)*HW[cid[srcL[i]]] )
// 128 threads, 64 rows/block, 8x8 register tile: 256 FMA-inst per 16 loads
// (was 8x4: 128 per 12 -> issue-bound at 41% VALUBusy).
__global__ __launch_bounds__(128, 2) void k_fuse64(const float* __restrict__ x, const float* __restrict__ tw,
                                                   const float* __restrict__ tb, const float* __restrict__ SW,
                                                   const float* __restrict__ HW, const float* __restrict__ gdot,
                                                   const float* __restrict__ aDot, const int* __restrict__ cid,
                                                   const int* __restrict__ srcL, const int* __restrict__ tgtL,
                                                   const float* __restrict__ attb, const int* __restrict__ rankF,
                                                   float* __restrict__ Fp, int accum) {
  __shared__ float xld[64 * D];   // 32 KB
  __shared__ float pq[64 * 2];
  __shared__ int mt[64 * 2];
  int tid = threadIdx.x;
  int base = blockIdx.x * 64;
  if (tid < 64) {
    int ws = srcL[base + tid];
    int cc = cid[ws];
    mt[tid * 2] = cc;
    mt[tid * 2 + 1] = tgtL[base + tid];
    float s = aDot[ws] + gdot[cc] + attb[0];
    float mx = fmaxf(s, 0.f);
    float esm = expf(s - mx), eom = expf(-mx);
    float dn = esm + 255.f * eom;
    pq[tid * 2] = esm / dn;
    pq[tid * 2 + 1] = eom / dn;
  }
  // stage 64 x-rows (2048 float4, 16 per thread)
#pragma unroll
  for (int k = 0; k < 16; ++k) {
    int i = k * 128 + tid;
    int r = i >> 5, off = i & 31;
    int ws = srcL[base + r];
    ((float4*)xld)[i] = ((const float4*)(x + (size_t)ws * D))[off];
  }
  __syncthreads();

  int rg = tid >> 4;        // 8 row-groups of 8 rows
  int cg = tid & 15;        // 16 col-groups of 8 cols
  int c8 = cg * 8;
  float acc[8][8] = {};
  const float* xb = xld + rg * 8 * D;
  for (int d4 = 0; d4 < D; d4 += 4) {
    float tww[4][8];
#pragma unroll
    for (int dd = 0; dd < 4; ++dd) {
      *(float4*)&tww[dd][0] = *(const float4*)(tw + (size_t)(d4 + dd) * D + c8);
      *(float4*)&tww[dd][4] = *(const float4*)(tw + (size_t)(d4 + dd) * D + c8 + 4);
    }
#pragma unroll
    for (int r = 0; r < 8; ++r) {
      float4 xv = *(const float4*)(xb + r * D + d4);
      float xs[4] = {xv.x, xv.y, xv.z, xv.w};
#pragma unroll
      for (int dd = 0; dd < 4; ++dd)
#pragma unroll
        for (int c = 0; c < 8; ++c)
          acc[r][c] = fmaf(xs[dd], tww[dd][c], acc[r][c]);
    }
  }

  float4 tb0 = *(const float4*)(tb + c8);
  float4 tb1 = *(const float4*)(tb + c8 + 4);
  float4 sw0 = *(const float4*)(SW + c8);
  float4 sw1 = *(const float4*)(SW + c8 + 4);
#pragma unroll
  for (int r = 0; r < 8; ++r) {
    int row = rg * 8 + r;
    float p = pq[row * 2], q = pq[row * 2 + 1];
    int cc = mt[row * 2];
    int tgt = mt[row * 2 + 1];
    float4 hw0 = *(const float4*)(HW + (size_t)cc * D + c8);
    float4 hw1 = *(const float4*)(HW + (size_t)cc * D + c8 + 4);
    float4 o0, o1;
    o0.x = fmaxf(acc[r][0] + tb0.x + q * sw0.x + (p - q) * hw0.x, 0.f);
    o0.y = fmaxf(acc[r][1] + tb0.y + q * sw0.y + (p - q) * hw0.y, 0.f);
    o0.z = fmaxf(acc[r][2] + tb0.z + q * sw0.z + (p - q) * hw0.z, 0.f);
    o0.w = fmaxf(acc[r][3] + tb0.w + q * sw0.w + (p - q) * hw0.w, 0.f);
    o1.x = fmaxf(acc[r][4] + tb1.x + q * sw1.x + (p - q) * hw1.x, 0.f);
    o1.y = fmaxf(acc[r][5] + tb1.y + q * sw1.y + (p - q) * hw1.y, 0.f);
    o1.z = fmaxf(acc[r][6] + tb1.z + q * sw1.z + (p - q) * hw1.z, 0.f);
    o1.w = fmaxf(acc[r][7] + tb1.w + q * sw1.w + (p - q) * hw1.w, 0.f);
    float4* dst0 = (float4*)(Fp + (size_t)tgt * D + c8);
    float4* dst1 = (float4*)(Fp + (size_t)tgt * D + c8 + 4);
    if (accum) {
      float4 a0 = *dst0, a1 = *dst1;
      o0.x += a0.x; o0.y += a0.y; o0.z += a0.z; o0.w += a0.w;
      o1.x += a1.x; o1.y += a1.y; o1.z += a1.z; o1.w += a1.w;
      if (rankF[tgt] < KSEL) {
        o0.x *= 0.5f; o0.y *= 0.5f; o0.z *= 0.5f; o0.w *= 0.5f;
        o1.x *= 0.5f; o1.y *= 0.5f; o1.z *= 0.5f; o1.w *= 0.5f;
      }
    }
    *dst0 = o0;
    *dst1 = o1;
  }
}

// ======================= launcher =======================
extern "C" void kernel_launch(void* const* d_in, const int* in_sizes, int n_in,
                              void* d_out, int out_size, void* d_ws, size_t ws_size,
                              hipStream_t stream) {
  const float* x   = (const float*)d_in[0];
  const int* ei    = (const int*)d_in[1];
  const int* batch = (const int*)d_in[2];
  const int* cid   = (const int*)d_in[3];
  const float* w1  = (const float*)d_in[4];
  const float* b1  = (const float*)d_in[5];
  const float* w2  = (const float*)d_in[6];
  const float* b2  = (const float*)d_in[7];
  const float* gw  = (const float*)d_in[8];
  const float* gas = (const float*)d_in[9];
  const float* gad = (const float*)d_in[10];
  const float* gb  = (const float*)d_in[11];
  const float* wa  = (const float*)d_in[12];
  const float* wb  = (const float*)d_in[13];
  const float* ab  = (const float*)d_in[14];
  const float* tw  = (const float*)d_in[15];
  const float* tb  = (const float*)d_in[16];
  (void)in_sizes; (void)n_in; (void)ws_size; (void)out_size;

  char* p = (char*)d_ws;
  auto alloc = [&](size_t bytes) -> char* {
    char* r = p;
    p += (bytes + 255) & ~(size_t)255;
    return r;
  };
  // ---- zero-init region ----
  int* ccount    = (int*)alloc(C_ * 4);
  int* ccur      = (int*)alloc(C_ * 4);
  unsigned* mm   = (unsigned*)alloc(16);                // [maxF,maxL,minF,minL]
  int* hist2     = (int*)alloc(2 * NB * 4);
  int* cur2      = (int*)alloc(2 * NB * 4);
  float* Hc      = (float*)alloc((size_t)C_ * D * 4);   // atomic accumulator
  int* gcnt      = (int*)alloc(NBK * 4);
  size_t zeroBytes = (size_t)(p - (char*)d_ws);
  // ---- rest (fully written before read) ----
  int* cstart   = (int*)alloc(C_ * 4);
  int* cslot    = (int*)alloc((size_t)N * 4);
  float* gdot   = (float*)alloc(C_ * 4);
  float* SW     = (float*)alloc(D * 4);
  float* HW     = (float*)alloc((size_t)C_ * D * 4);
  float* score2 = (float*)alloc((size_t)2 * N * 4);     // [scoreF | scoreL]
  float* hg     = (float*)alloc((size_t)N * 4);
  float* aDot   = (float*)alloc((size_t)N * 4);
  uint2* payload = (uint2*)alloc((size_t)NBK * BCAP * 8);
  int* bucket2  = (int*)alloc((size_t)2 * N * 4);
  int* start2   = (int*)alloc(2 * NB * 4);
  int* slot2    = (int*)alloc((size_t)2 * N * 4);
  int* sorted2  = (int*)alloc((size_t)2 * N * 4);
  int* rank2    = (int*)alloc((size_t)2 * N * 4);
  int* csums    = (int*)alloc(NCHUNK * 4);
  int* cstarts  = (int*)alloc(NCHUNK * 4);
  int* mapping  = (int*)alloc((size_t)N * 4);

  float* scoreF = score2;
  float* scoreL = score2 + N;
  int* sortedF  = sorted2;
  int* sortedL  = sorted2 + N;
  int* rankF    = rank2;
  int* rankL    = rank2 + N;

  float* outF = (float*)d_out;             // [N, D]
  float* outE = outF + (size_t)N * D;      // [2, E]  (fully written by k_edge_out)
  float* outB = outE + (size_t)2 * E_;     // [N]     (fully written by k_union_map)

  hipMemsetAsync(d_ws, 0, zeroBytes, stream);
  hipMemsetAsync(outF, 0, (size_t)N * D * 4, stream);   // only outF needs zeroing
  hipMemsetAsync(mm + 2, 0xFF, 8, stream);              // minF,minL -> 0xFFFFFFFF

  // cluster means + derived (6 launches)
  k_hist_cluster<<<(N + 255) / 256, 256, 0, stream>>>(cid, ccount);
  k_scan_small<<<1, 1024, 0, stream>>>(ccount, cstart, C_);
  k_scatter_cluster<<<(N + 255) / 256, 256, 0, stream>>>(cid, cstart, ccur, cslot);
  k_cluster_partial<<<C_ * CSEG, 128, 0, stream>>>(x, cstart, ccount, cslot, Hc);
  k_mean_gdot<<<C_, 128, 0, stream>>>(ccount, wb, Hc, gdot);
  k_S_SW_HW<<<C_ + 1, 128, 0, stream>>>(Hc, tw, SW, HW);

  // fused per-node scores (MLP + GAT projections) + edge softmax
  k_score64<<<(N + 63) / 64, 256, 0, stream>>>(x, w1, b1, w2, b2, gw, wa, scoreF, hg, aDot);
  k_escatter<<<(E_ + 8191) / 8192, 1024, 0, stream>>>(ei, hg, gas, gad, gcnt, payload);
  k_esoftmax<<<NBK, 256, 0, stream>>>(payload, gcnt, hg, gb, scoreL);

  // exact ranking, both views per launch
  dim3 g2((N + 255) / 256, 2);
  k_minmax2<<<g2, 256, 0, stream>>>(score2, mm);
  k_bucket_hist2<<<g2, 256, 0, stream>>>(score2, mm, bucket2, hist2);
  k_scan_small<<<2, 1024, 0, stream>>>(hist2, start2, NB);
  k_bucket_scatter2<<<g2, 256, 0, stream>>>(bucket2, start2, cur2, slot2);
  k_bucket_rank2<<<g2, 256, 0, stream>>>(score2, bucket2, start2, hist2, slot2, rank2, sorted2);

  // union mapping + edge remap + batch
  k_union_chunksum<<<NCHUNK, 1024, 0, stream>>>(rankF, rankL, csums);
  k_scan_small<<<1, 1024, 0, stream>>>(csums, cstarts, NCHUNK);
  k_union_map<<<NCHUNK, 1024, 0, stream>>>(rankF, rankL, cstarts, batch, mapping, outB);
  k_edge_out<<<(E_ + 255) / 256, 256, 0, stream>>>(ei, mapping, outE);

  // fused features: launch 1 pure-stores; launch 2 accumulates + folds *0.5
  k_fuse64<<<KSEL / 64, 128, 0, stream>>>(x, tw, tb, SW, HW, gdot, aDot, cid, sortedL, sortedF, ab, rankF, outF, 0);
  k_fuse64<<<KSEL / 64, 128, 0, stream>>>(x, tw, tb, SW, HW, gdot, aDot, cid, sortedF, sortedL, ab, rankF, outF, 1);
}

// Round 7
// 589.179 us; speedup vs baseline: 2.0886x; 1.1316x over previous
//
#include <hip/hip_runtime.h>
#include <hip/hip_bf16.h>
#include <stdint.h>

#define N 100000
#define E_ 1600000
#define D 128
#define C_ 256
#define HID 64
#define KSEL 80000
#define NB 4096
#define CHUNK 1024
#define NCHUNK ((N + CHUNK - 1) / CHUNK)   // 98
#define CSEG 32                            // segments per cluster for mean reduction
#define NBK 782                            // ceil(N/128) dst-buckets of 128 nodes
#define BCAP 2560                          // per-bucket capacity (avg 2046 + >11 sigma)
#define RMAX 2048                          // LDS key capacity for in-bucket ranking

// ---- ordered-float encoding (monotonic increasing uint) ----
__device__ __forceinline__ unsigned enc_f(float f) {
  unsigned b = __float_as_uint(f);
  return (b & 0x80000000u) ? ~b : (b | 0x80000000u);
}
__device__ __forceinline__ float dec_f(unsigned u) {
  unsigned b = (u & 0x80000000u) ? (u ^ 0x80000000u) : ~u;
  return __uint_as_float(b);
}

// ======================= cluster CSR + means =======================
__global__ __launch_bounds__(256) void k_hist_cluster(const int* __restrict__ cid, int* __restrict__ ccount) {
  int n = blockIdx.x * 256 + threadIdx.x;
  if (n < N) atomicAdd(&ccount[cid[n]], 1);
}

// generic small scan; block b scans in[b*n .. b*n+n) -> out exclusive
__global__ __launch_bounds__(1024) void k_scan_small(const int* __restrict__ in0, int* __restrict__ out0, int n) {
  __shared__ int sums[1024];
  const int* in = in0 + (size_t)blockIdx.x * n;
  int* out = out0 + (size_t)blockIdx.x * n;
  int t = threadIdx.x;
  int per = (n + 1023) / 1024;
  int base = t * per;
  int loc = 0;
  for (int k = 0; k < per; ++k) { int i = base + k; if (i < n) loc += in[i]; }
  sums[t] = loc; __syncthreads();
  for (int off = 1; off < 1024; off <<= 1) {
    int v = (t >= off) ? sums[t - off] : 0;
    __syncthreads();
    sums[t] += v;
    __syncthreads();
  }
  int run = (t == 0) ? 0 : sums[t - 1];
  for (int k = 0; k < per; ++k) { int i = base + k; if (i < n) { out[i] = run; run += in[i]; } }
}

__global__ __launch_bounds__(256) void k_scatter_cluster(const int* __restrict__ cid, const int* __restrict__ cstart,
                                                         int* __restrict__ ccur, int* __restrict__ cslot) {
  int n = blockIdx.x * 256 + threadIdx.x;
  if (n < N) {
    int c = cid[n];
    int p = cstart[c] + atomicAdd(&ccur[c], 1);
    cslot[p] = n;
  }
}

__global__ __launch_bounds__(128) void k_cluster_partial(const float* __restrict__ x, const int* __restrict__ cstart,
                                                         const int* __restrict__ ccount, const int* __restrict__ cslot,
                                                         float* __restrict__ Hc) {
  int c = blockIdx.x >> 5;
  int s = blockIdx.x & (CSEG - 1);
  int d = threadIdx.x;
  int st = cstart[c], cnt = ccount[c];
  int seg = (cnt + CSEG - 1) / CSEG;
  int lo = s * seg;
  int hi = min(cnt, lo + seg);
  if (lo >= hi) return;
  float acc = 0.f;
  int k = lo;
  for (; k + 2 <= hi; k += 2) {
    int n0 = cslot[st + k], n1 = cslot[st + k + 1];
    float v0 = x[(size_t)n0 * D + d];
    float v1 = x[(size_t)n1 * D + d];
    acc += v0 + v1;
  }
  if (k < hi) acc += x[(size_t)cslot[st + k] * D + d];
  atomicAdd(&Hc[(size_t)c * D + d], acc);
}

// divide Hc by counts, then gdot[c] = Hc[c] . wb  (merged, one launch)
__global__ __launch_bounds__(128) void k_mean_gdot(const int* __restrict__ ccount, const float* __restrict__ wb,
                                                   float* __restrict__ Hc, float* __restrict__ gdot) {
  __shared__ float red[128];
  int c = blockIdx.x, d = threadIdx.x;
  float hv = Hc[(size_t)c * D + d] / (float)max(ccount[c], 1);
  Hc[(size_t)c * D + d] = hv;
  red[d] = hv * wb[d];
  __syncthreads();
  if (d < 64) {
    float v = red[d] + red[d + 64];
    for (int off = 32; off; off >>= 1) v += __shfl_down(v, off);
    if (d == 0) gdot[c] = v;
  }
}

// block 0: S = sum_c Hc[c], SW = S @ tw ; blocks 1..C_: HW[b-1] = Hc[b-1] @ tw
__global__ __launch_bounds__(128) void k_S_SW_HW(const float* __restrict__ Hc, const float* __restrict__ tw,
                                                 float* __restrict__ SW, float* __restrict__ HW) {
  __shared__ float Sl[128];
  int b = blockIdx.x, t = threadIdx.x;
  if (b == 0) {
    float s = 0.f;
    for (int c = 0; c < C_; ++c) s += Hc[(size_t)c * D + t];
    Sl[t] = s;
    __syncthreads();
    float acc = 0.f;
    for (int d = 0; d < D; ++d) acc = fmaf(Sl[d], tw[(size_t)d * D + t], acc);
    SW[t] = acc;
  } else {
    const float* src = Hc + (size_t)(b - 1) * D;
    float acc = 0.f;
    for (int d = 0; d < D; ++d) acc = fmaf(src[d], tw[(size_t)d * D + t], acc);
    HW[(size_t)(b - 1) * D + t] = acc;
  }
}

// ======== fused per-node scores: MLP (feature view) + GAT h/aDot ========
__global__ __launch_bounds__(256, 4) void k_score64(const float* __restrict__ x, const float* __restrict__ w1,
                                                    const float* __restrict__ b1, const float* __restrict__ w2,
                                                    const float* __restrict__ b2, const float* __restrict__ gw,
                                                    const float* __restrict__ wa, float* __restrict__ scoreF,
                                                    float* __restrict__ hg, float* __restrict__ aDot) {
  __shared__ float xld[64 * D];  // 32 KB
  int tid = threadIdx.x;
  int base = blockIdx.x * 64;
#pragma unroll
  for (int k = 0; k < 8; ++k) {
    int i = k * 256 + tid;
    int r = i >> 5, off = i & 31;
    int n = base + r;
    float4 v = make_float4(0.f, 0.f, 0.f, 0.f);
    if (n < N) v = ((const float4*)(x + (size_t)n * D))[off];
    ((float4*)xld)[i] = v;
  }
  __syncthreads();

  int rg = tid >> 5;        // 8 row-groups of 8 rows
  int cg = tid & 31;        // 32 col-groups of 2 hid cols
  int c2 = cg * 2;
  float acc[8][2] = {};
  const float* xb = xld + rg * 8 * D;
  for (int d4 = 0; d4 < D; d4 += 4) {
    float2 wv0 = *(const float2*)(w1 + (size_t)(d4 + 0) * HID + c2);
    float2 wv1 = *(const float2*)(w1 + (size_t)(d4 + 1) * HID + c2);
    float2 wv2 = *(const float2*)(w1 + (size_t)(d4 + 2) * HID + c2);
    float2 wv3 = *(const float2*)(w1 + (size_t)(d4 + 3) * HID + c2);
#pragma unroll
    for (int r = 0; r < 8; ++r) {
      float4 xv = *(const float4*)(xb + r * D + d4);
      acc[r][0] = fmaf(xv.x, wv0.x, acc[r][0]);
      acc[r][1] = fmaf(xv.x, wv0.y, acc[r][1]);
      acc[r][0] = fmaf(xv.y, wv1.x, acc[r][0]);
      acc[r][1] = fmaf(xv.y, wv1.y, acc[r][1]);
      acc[r][0] = fmaf(xv.z, wv2.x, acc[r][0]);
      acc[r][1] = fmaf(xv.z, wv2.y, acc[r][1]);
      acc[r][0] = fmaf(xv.w, wv3.x, acc[r][0]);
      acc[r][1] = fmaf(xv.w, wv3.y, acc[r][1]);
    }
  }
  float2 b1v = *(const float2*)(b1 + c2);
  float2 w2v = *(const float2*)(w2 + c2);
  float bb = b2[0];
#pragma unroll
  for (int r = 0; r < 8; ++r) {
    float p = fmaxf(acc[r][0] + b1v.x, 0.f) * w2v.x + fmaxf(acc[r][1] + b1v.y, 0.f) * w2v.y;
#pragma unroll
    for (int off = 16; off; off >>= 1) p += __shfl_xor(p, off);
    if (cg == 0) {
      int n = base + rg * 8 + r;
      if (n < N) scoreF[n] = p + bb;
    }
  }
  float4 gwv = *(const float4*)(gw + cg * 4);
  float4 wav = *(const float4*)(wa + cg * 4);
#pragma unroll
  for (int r = 0; r < 8; ++r) {
    int row = rg * 8 + r;
    float4 xv = *(const float4*)(xld + row * D + cg * 4);
    float hp = xv.x * gwv.x + xv.y * gwv.y + xv.z * gwv.z + xv.w * gwv.w;
    float ap = xv.x * wav.x + xv.y * wav.y + xv.z * wav.z + xv.w * wav.w;
#pragma unroll
    for (int off = 16; off; off >>= 1) {
      hp += __shfl_xor(hp, off);
      ap += __shfl_xor(ap, off);
    }
    if (cg == 0) {
      int n = base + row;
      if (n < N) { hg[n] = hp; aDot[n] = ap; }
    }
  }
}

// Bucket edges by dst>>7 with LDS-aggregated reservation.
__global__ __launch_bounds__(1024) void k_escatter(const int* __restrict__ ei, const float* __restrict__ hg,
                                                   const float* __restrict__ asrc, const float* __restrict__ adst,
                                                   int* __restrict__ gcnt, uint2* __restrict__ payload) {
  __shared__ int lcnt[NBK];
  __shared__ int lbase[NBK];
  int tid = threadIdx.x;
  for (int i = tid; i < NBK; i += 1024) lcnt[i] = 0;
  int e0 = blockIdx.x * 8192;
  int es[8], ed[8];
#pragma unroll
  for (int k = 0; k < 8; ++k) {
    int e = e0 + k * 1024 + tid;
    bool v = (e < E_);
    es[k] = v ? ei[e] : -1;
    ed[k] = v ? ei[E_ + e] : -1;
  }
  __syncthreads();
#pragma unroll
  for (int k = 0; k < 8; ++k)
    if (ed[k] >= 0) atomicAdd(&lcnt[ed[k] >> 7], 1);
  __syncthreads();
  for (int i = tid; i < NBK; i += 1024) {
    int c = lcnt[i];
    lbase[i] = c ? atomicAdd(&gcnt[i], c) : 0;
    lcnt[i] = 0;
  }
  __syncthreads();
  float as = asrc[0], ad = adst[0];
#pragma unroll
  for (int k = 0; k < 8; ++k) {
    if (ed[k] < 0) continue;
    int s = es[k], d = ed[k];
    int b = d >> 7, dl = d & 127;
    float z = as * hg[s] + ad * hg[d];
    float ev = (z > 0.f) ? z : 0.2f * z;
    int pos = lbase[b] + atomicAdd(&lcnt[b], 1);
    if (pos < BCAP) {
      uint2 rec;
      rec.x = __float_as_uint(ev);
      rec.y = (unsigned)s | ((unsigned)dl << 24);
      payload[(size_t)b * BCAP + pos] = rec;
    }
  }
}

// Per-bucket GAT softmax in LDS; writes scoreL.
__global__ __launch_bounds__(256) void k_esoftmax(const uint2* __restrict__ payload, const int* __restrict__ gcnt,
                                                  const float* __restrict__ hg, const float* __restrict__ gb,
                                                  float* __restrict__ scoreL) {
  __shared__ unsigned mS[128];
  __shared__ float dS[128];
  __shared__ float nS[128];
  int b = blockIdx.x;
  int tid = threadIdx.x;
  if (tid < 128) { mS[tid] = 0u; dS[tid] = 0.f; nS[tid] = 0.f; }
  __syncthreads();
  int cnt = min(gcnt[b], BCAP);
  const uint2* bp = payload + (size_t)b * BCAP;
  for (int i = tid; i < cnt; i += 256) {
    uint2 r = bp[i];
    atomicMax(&mS[r.y >> 24], enc_f(__uint_as_float(r.x)));
  }
  __syncthreads();
  for (int i = tid; i < cnt; i += 256) {
    uint2 r = bp[i];
    int d = r.y >> 24;
    float ex = expf(__uint_as_float(r.x) - dec_f(mS[d]));
    atomicAdd(&dS[d], ex);
  }
  __syncthreads();
  for (int i = tid; i < cnt; i += 256) {
    uint2 r = bp[i];
    int d = r.y >> 24;
    float ex = expf(__uint_as_float(r.x) - dec_f(mS[d]));
    float alpha = ex / fmaxf(dS[d], 1e-16f);
    float h = hg[r.y & 0xFFFFFFu];
    atomicAdd(&nS[d], alpha * h);
  }
  __syncthreads();
  if (tid < 128) {
    int dst = b * 128 + tid;
    if (dst < N) scoreL[dst] = nS[tid] + gb[0];
  }
}

// ========== exact top-k ranking, both views per launch (blockIdx.y) ==========
// mm layout: [maxF, maxL, minF, minL]
__global__ __launch_bounds__(256) void k_minmax2(const float* __restrict__ sc2, unsigned* __restrict__ mm) {
  __shared__ unsigned smx[256], smn[256];
  int v = blockIdx.y;
  const float* sc = sc2 + (size_t)v * N;
  int t = threadIdx.x; int n = blockIdx.x * 256 + t;
  unsigned val = (n < N) ? enc_f(sc[n]) : 0u;
  smx[t] = (n < N) ? val : 0u;
  smn[t] = (n < N) ? val : 0xFFFFFFFFu;
  __syncthreads();
  for (int off = 128; off; off >>= 1) {
    if (t < off) {
      smx[t] = max(smx[t], smx[t + off]);
      smn[t] = min(smn[t], smn[t + off]);
    }
    __syncthreads();
  }
  if (t == 0) { atomicMax(&mm[v], smx[0]); atomicMin(&mm[2 + v], smn[0]); }
}

__global__ __launch_bounds__(256) void k_bucket_hist2(const float* __restrict__ sc2, const unsigned* __restrict__ mm,
                                                      int* __restrict__ bucket2, int* __restrict__ hist2) {
  int v = blockIdx.y;
  int n = blockIdx.x * 256 + threadIdx.x;
  if (n >= N) return;
  const float* sc = sc2 + (size_t)v * N;
  float smax = dec_f(mm[v]), smin = dec_f(mm[2 + v]);
  float range = smax - smin;
  float scale = (range > 0.f) ? ((float)NB / range) : 0.f;
  float t = (smax - sc[n]) * scale;
  int b = (int)t;
  b = b < 0 ? 0 : (b > NB - 1 ? NB - 1 : b);
  bucket2[(size_t)v * N + n] = b;
  atomicAdd(&hist2[v * NB + b], 1);
}

__global__ __launch_bounds__(256) void k_bucket_scatter2(const int* __restrict__ bucket2, const int* __restrict__ start2,
                                                         int* __restrict__ cur2, int* __restrict__ slot2) {
  int v = blockIdx.y;
  int n = blockIdx.x * 256 + threadIdx.x;
  if (n >= N) return;
  int b = bucket2[(size_t)v * N + n];
  slot2[(size_t)v * N + start2[v * NB + b] + atomicAdd(&cur2[v * NB + b], 1)] = n;
}

// Bucket-centric exact ranking: one wave per bucket, keys staged in LDS once.
// Replaces the element-centric version (93us: each node re-gathered its whole
// bucket from global -> Sum(cnt^2) ~200-cyc gathers; now one gather/element +
// broadcast LDS compares).
__global__ __launch_bounds__(64) void k_bucket_rank3(const float* __restrict__ sc2, const int* __restrict__ start2,
                                                     const int* __restrict__ hist2, const int* __restrict__ slot2,
                                                     int* __restrict__ rank2, int* __restrict__ sorted2) {
  __shared__ unsigned long long keys[RMAX];
  int v = blockIdx.y;
  int b = blockIdx.x;
  int st = start2[v * NB + b], cnt = hist2[v * NB + b];
  if (cnt == 0) return;
  const float* sc = sc2 + (size_t)v * N;
  const int* slot = slot2 + (size_t)v * N;
  int* rank = rank2 + (size_t)v * N;
  int* sorted = sorted2 + (size_t)v * N;
  int tid = threadIdx.x;
  if (cnt <= RMAX) {
    for (int i = tid; i < cnt; i += 64) {
      int m = slot[st + i];
      keys[i] = (((unsigned long long)(~enc_f(sc[m]))) << 32) | (unsigned)m;
    }
    __syncthreads();
    for (int i = tid; i < cnt; i += 64) {
      unsigned long long mykey = keys[i];
      int r = 0;
      for (int j = 0; j < cnt; ++j) r += (keys[j] < mykey) ? 1 : 0;
      int m = (int)(mykey & 0xFFFFFFFFu);
      rank[m] = st + r;
      sorted[st + r] = m;
    }
  } else {  // degenerate-distribution fallback (not taken for normal scores)
    for (int i = tid; i < cnt; i += 64) {
      int m = slot[st + i];
      unsigned long long mykey = (((unsigned long long)(~enc_f(sc[m]))) << 32) | (unsigned)m;
      int r = 0;
      for (int j = 0; j < cnt; ++j) {
        int mj = slot[st + j];
        unsigned long long k = (((unsigned long long)(~enc_f(sc[mj]))) << 32) | (unsigned)mj;
        r += (k < mykey) ? 1 : 0;
      }
      rank[m] = st + r;
      sorted[st + r] = m;
    }
  }
}

// ======================= union mapping =======================
__global__ __launch_bounds__(1024) void k_union_chunksum(const int* __restrict__ rankF, const int* __restrict__ rankL,
                                                         int* __restrict__ csum) {
  __shared__ int red[1024];
  int t = threadIdx.x; int i = blockIdx.x * 1024 + t;
  int u = (i < N) ? (((rankF[i] < KSEL) || (rankL[i] < KSEL)) ? 1 : 0) : 0;
  red[t] = u; __syncthreads();
  for (int off = 512; off; off >>= 1) { if (t < off) red[t] += red[t + off]; __syncthreads(); }
  if (t == 0) csum[blockIdx.x] = red[0];
}

__global__ __launch_bounds__(1024) void k_union_map(const int* __restrict__ rankF, const int* __restrict__ rankL,
                                                    const int* __restrict__ cstart, const int* __restrict__ batch,
                                                    int* __restrict__ mapping, float* __restrict__ outBatch) {
  __shared__ int sums[1024];
  int t = threadIdx.x; int i = blockIdx.x * 1024 + t;
  int u = (i < N) ? (((rankF[i] < KSEL) || (rankL[i] < KSEL)) ? 1 : 0) : 0;
  sums[t] = u; __syncthreads();
  for (int off = 1; off < 1024; off <<= 1) {
    int v = (t >= off) ? sums[t - off] : 0;
    __syncthreads();
    sums[t] += v;
    __syncthreads();
  }
  if (i < N) {
    mapping[i] = u ? (cstart[blockIdx.x] + sums[t] - 1) : -1;
    outBatch[i] = u ? (float)batch[i] : -1.0f;
  }
}

__global__ __launch_bounds__(256) void k_edge_out(const int* __restrict__ ei, const int* __restrict__ mapping,
                                                  float* __restrict__ outE) {
  int e = blockIdx.x * 256 + threadIdx.x;
  if (e >= E_) return;
  int m0 = mapping[ei[e]], m1 = mapping[ei[E_ + e]];
  bool valid = (m0 >= 0) && (m1 >= 0);
  outE[e] = valid ? (float)m0 : -1.f;
  outE[E_ + e] = valid ? (float)m1 : -1.f;
}

// ======================= fused GCN transform + scatter =======================
__global__ __launch_bounds__(128, 2) void k_fuse64(const float* __restrict__ x, const float* __restrict__ tw,
                                                   const float* __restrict__ tb, const float* __restrict__ SW,
                                                   const float* __restrict__ HW, const float* __restrict__ gdot,
                                                   const float* __restrict__ aDot, const int* __restrict__ cid,
                                                   const int* __restrict__ srcL, const int* __restrict__ tgtL,
                                                   const float* __restrict__ attb, const int* __restrict__ rankF,
                                                   float* __restrict__ Fp, int accum) {
  __shared__ float xld[64 * D];   // 32 KB
  __shared__ float pq[64 * 2];
  __shared__ int mt[64 * 2];
  int tid = threadIdx.x;
  int base = blockIdx.x * 64;
  if (tid < 64) {
    int ws = srcL[base + tid];
    int cc = cid[ws];
    mt[tid * 2] = cc;
    mt[tid * 2 + 1] = tgtL[base + tid];
    float s = aDot[ws] + gdot[cc] + attb[0];
    float mx = fmaxf(s, 0.f);
    float esm = expf(s - mx), eom = expf(-mx);
    float dn = esm + 255.f * eom;
    pq[tid * 2] = esm / dn;
    pq[tid * 2 + 1] = eom / dn;
  }
#pragma unroll
  for (int k = 0; k < 16; ++k) {
    int i = k * 128 + tid;
    int r = i >> 5, off = i & 31;
    int ws = srcL[base + r];
    ((float4*)xld)[i] = ((const float4*)(x + (size_t)ws * D))[off];
  }
  __syncthreads();

  int rg = tid >> 4;        // 8 row-groups of 8 rows
  int cg = tid & 15;        // 16 col-groups of 8 cols
  int c8 = cg * 8;
  float acc[8][8] = {};
  const float* xb = xld + rg * 8 * D;
  for (int d4 = 0; d4 < D; d4 += 4) {
    float tww[4][8];
#pragma unroll
    for (int dd = 0; dd < 4; ++dd) {
      *(float4*)&tww[dd][0] = *(const float4*)(tw + (size_t)(d4 + dd) * D + c8);
      *(float4*)&tww[dd][4] = *(const float4*)(tw + (size_t)(d4 + dd) * D + c8 + 4);
    }
#pragma unroll
    for (int r = 0; r < 8; ++r) {
      float4 xv = *(const float4*)(xb + r * D + d4);
      float xs[4] = {xv.x, xv.y, xv.z, xv.w};
#pragma unroll
      for (int dd = 0; dd < 4; ++dd)
#pragma unroll
        for (int c = 0; c < 8; ++c)
          acc[r][c] = fmaf(xs[dd], tww[dd][c], acc[r][c]);
    }
  }

  float4 tb0 = *(const float4*)(tb + c8);
  float4 tb1 = *(const float4*)(tb + c8 + 4);
  float4 sw0 = *(const float4*)(SW + c8);
  float4 sw1 = *(const float4*)(SW + c8 + 4);
#pragma unroll
  for (int r = 0; r < 8; ++r) {
    int row = rg * 8 + r;
    float p = pq[row * 2], q = pq[row * 2 + 1];
    int cc = mt[row * 2];
    int tgt = mt[row * 2 + 1];
    float4 hw0 = *(const float4*)(HW + (size_t)cc * D + c8);
    float4 hw1 = *(const float4*)(HW + (size_t)cc * D + c8 + 4);
    float4 o0, o1;
    o0.x = fmaxf(acc[r][0] + tb0.x + q * sw0.x + (p - q) * hw0.x, 0.f);
    o0.y = fmaxf(acc[r][1] + tb0.y + q * sw0.y + (p - q) * hw0.y, 0.f);
    o0.z = fmaxf(acc[r][2] + tb0.z + q * sw0.z + (p - q) * hw0.z, 0.f);
    o0.w = fmaxf(acc[r][3] + tb0.w + q * sw0.w + (p - q) * hw0.w, 0.f);
    o1.x = fmaxf(acc[r][4] + tb1.x + q * sw1.x + (p - q) * hw1.x, 0.f);
    o1.y = fmaxf(acc[r][5] + tb1.y + q * sw1.y + (p - q) * hw1.y, 0.f);
    o1.z = fmaxf(acc[r][6] + tb1.z + q * sw1.z + (p - q) * hw1.z, 0.f);
    o1.w = fmaxf(acc[r][7] + tb1.w + q * sw1.w + (p - q) * hw1.w, 0.f);
    float4* dst0 = (float4*)(Fp + (size_t)tgt * D + c8);
    float4* dst1 = (float4*)(Fp + (size_t)tgt * D + c8 + 4);
    if (accum) {
      float4 a0 = *dst0, a1 = *dst1;
      o0.x += a0.x; o0.y += a0.y; o0.z += a0.z; o0.w += a0.w;
      o1.x += a1.x; o1.y += a1.y; o1.z += a1.z; o1.w += a1.w;
      if (rankF[tgt] < KSEL) {
        o0.x *= 0.5f; o0.y *= 0.5f; o0.z *= 0.5f; o0.w *= 0.5f;
        o1.x *= 0.5f; o1.y *= 0.5f; o1.z *= 0.5f; o1.w *= 0.5f;
      }
    }
    *dst0 = o0;
    *dst1 = o1;
  }
}

// ======================= launcher =======================
extern "C" void kernel_launch(void* const* d_in, const int* in_sizes, int n_in,
                              void* d_out, int out_size, void* d_ws, size_t ws_size,
                              hipStream_t stream) {
  const float* x   = (const float*)d_in[0];
  const int* ei    = (const int*)d_in[1];
  const int* batch = (const int*)d_in[2];
  const int* cid   = (const int*)d_in[3];
  const float* w1  = (const float*)d_in[4];
  const float* b1  = (const float*)d_in[5];
  const float* w2  = (const float*)d_in[6];
  const float* b2  = (const float*)d_in[7];
  const float* gw  = (const float*)d_in[8];
  const float* gas = (const float*)d_in[9];
  const float* gad = (const float*)d_in[10];
  const float* gb  = (const float*)d_in[11];
  const float* wa  = (const float*)d_in[12];
  const float* wb  = (const float*)d_in[13];
  const float* ab  = (const float*)d_in[14];
  const float* tw  = (const float*)d_in[15];
  const float* tb  = (const float*)d_in[16];
  (void)in_sizes; (void)n_in; (void)ws_size; (void)out_size;

  char* p = (char*)d_ws;
  auto alloc = [&](size_t bytes) -> char* {
    char* r = p;
    p += (bytes + 255) & ~(size_t)255;
    return r;
  };
  // ---- zero-init region ----
  int* ccount    = (int*)alloc(C_ * 4);
  int* ccur      = (int*)alloc(C_ * 4);
  unsigned* mm   = (unsigned*)alloc(16);                // [maxF,maxL,minF,minL]
  int* hist2     = (int*)alloc(2 * NB * 4);
  int* cur2      = (int*)alloc(2 * NB * 4);
  float* Hc      = (float*)alloc((size_t)C_ * D * 4);   // atomic accumulator
  int* gcnt      = (int*)alloc(NBK * 4);
  size_t zeroBytes = (size_t)(p - (char*)d_ws);
  // ---- rest (fully written before read) ----
  int* cstart   = (int*)alloc(C_ * 4);
  int* cslot    = (int*)alloc((size_t)N * 4);
  float* gdot   = (float*)alloc(C_ * 4);
  float* SW     = (float*)alloc(D * 4);
  float* HW     = (float*)alloc((size_t)C_ * D * 4);
  float* score2 = (float*)alloc((size_t)2 * N * 4);     // [scoreF | scoreL]
  float* hg     = (float*)alloc((size_t)N * 4);
  float* aDot   = (float*)alloc((size_t)N * 4);
  uint2* payload = (uint2*)alloc((size_t)NBK * BCAP * 8);
  int* bucket2  = (int*)alloc((size_t)2 * N * 4);
  int* start2   = (int*)alloc(2 * NB * 4);
  int* slot2    = (int*)alloc((size_t)2 * N * 4);
  int* sorted2  = (int*)alloc((size_t)2 * N * 4);
  int* rank2    = (int*)alloc((size_t)2 * N * 4);
  int* csums    = (int*)alloc(NCHUNK * 4);
  int* cstarts  = (int*)alloc(NCHUNK * 4);
  int* mapping  = (int*)alloc((size_t)N * 4);

  float* scoreF = score2;
  float* scoreL = score2 + N;
  int* sortedF  = sorted2;
  int* sortedL  = sorted2 + N;
  int* rankF    = rank2;
  int* rankL    = rank2 + N;

  float* outF = (float*)d_out;             // [N, D]
  float* outE = outF + (size_t)N * D;      // [2, E]  (fully written by k_edge_out)
  float* outB = outE + (size_t)2 * E_;     // [N]     (fully written by k_union_map)

  hipMemsetAsync(d_ws, 0, zeroBytes, stream);
  hipMemsetAsync(outF, 0, (size_t)N * D * 4, stream);   // only outF needs zeroing
  hipMemsetAsync(mm + 2, 0xFF, 8, stream);              // minF,minL -> 0xFFFFFFFF

  // cluster means + derived
  k_hist_cluster<<<(N + 255) / 256, 256, 0, stream>>>(cid, ccount);
  k_scan_small<<<1, 1024, 0, stream>>>(ccount, cstart, C_);
  k_scatter_cluster<<<(N + 255) / 256, 256, 0, stream>>>(cid, cstart, ccur, cslot);
  k_cluster_partial<<<C_ * CSEG, 128, 0, stream>>>(x, cstart, ccount, cslot, Hc);
  k_mean_gdot<<<C_, 128, 0, stream>>>(ccount, wb, Hc, gdot);
  k_S_SW_HW<<<C_ + 1, 128, 0, stream>>>(Hc, tw, SW, HW);

  // fused per-node scores (MLP + GAT projections) + edge softmax
  k_score64<<<(N + 63) / 64, 256, 0, stream>>>(x, w1, b1, w2, b2, gw, wa, scoreF, hg, aDot);
  k_escatter<<<(E_ + 8191) / 8192, 1024, 0, stream>>>(ei, hg, gas, gad, gcnt, payload);
  k_esoftmax<<<NBK, 256, 0, stream>>>(payload, gcnt, hg, gb, scoreL);

  // exact ranking, both views per launch
  dim3 g2((N + 255) / 256, 2);
  k_minmax2<<<g2, 256, 0, stream>>>(score2, mm);
  k_bucket_hist2<<<g2, 256, 0, stream>>>(score2, mm, bucket2, hist2);
  k_scan_small<<<2, 1024, 0, stream>>>(hist2, start2, NB);
  k_bucket_scatter2<<<g2, 256, 0, stream>>>(bucket2, start2, cur2, slot2);
  dim3 gr(NB, 2);
  k_bucket_rank3<<<gr, 64, 0, stream>>>(score2, start2, hist2, slot2, rank2, sorted2);

  // union mapping + edge remap + batch
  k_union_chunksum<<<NCHUNK, 1024, 0, stream>>>(rankF, rankL, csums);
  k_scan_small<<<1, 1024, 0, stream>>>(csums, cstarts, NCHUNK);
  k_union_map<<<NCHUNK, 1024, 0, stream>>>(rankF, rankL, cstarts, batch, mapping, outB);
  k_edge_out<<<(E_ + 255) / 256, 256, 0, stream>>>(ei, mapping, outE);

  // fused features: launch 1 pure-stores; launch 2 accumulates + folds *0.5
  k_fuse64<<<KSEL / 64, 128, 0, stream>>>(x, tw, tb, SW, HW, gdot, aDot, cid, sortedL, sortedF, ab, rankF, outF, 0);
  k_fuse64<<<KSEL / 64, 128, 0, stream>>>(x, tw, tb, SW, HW, gdot, aDot, cid, sortedF, sortedL, ab, rankF, outF, 1);
}

// Round 8
// 578.856 us; speedup vs baseline: 2.1258x; 1.0178x over previous
//
#include <hip/hip_runtime.h>
#include <hip/hip_bf16.h>
#include <stdint.h>

#define N 100000
#define E_ 1600000
#define D 128
#define C_ 256
#define HID 64
#define KSEL 80000
#define NB 4096
#define CHUNK 1024
#define NCHUNK ((N + CHUNK - 1) / CHUNK)   // 98
#define CSEG 32                            // segments per cluster for mean reduction
#define NBK 782                            // ceil(N/128) dst-buckets of 128 nodes
#define BCAP 2560                          // per-bucket capacity (avg 2046 + >11 sigma)
#define RMAX 2048                          // LDS key capacity for in-bucket ranking

// ---- ordered-float encoding (monotonic increasing uint) ----
__device__ __forceinline__ unsigned enc_f(float f) {
  unsigned b = __float_as_uint(f);
  return (b & 0x80000000u) ? ~b : (b | 0x80000000u);
}
__device__ __forceinline__ float dec_f(unsigned u) {
  unsigned b = (u & 0x80000000u) ? (u ^ 0x80000000u) : ~u;
  return __uint_as_float(b);
}

// ======================= cluster CSR + means =======================
__global__ __launch_bounds__(256) void k_hist_cluster(const int* __restrict__ cid, int* __restrict__ ccount) {
  int n = blockIdx.x * 256 + threadIdx.x;
  if (n < N) atomicAdd(&ccount[cid[n]], 1);
}

// generic small scan; block b scans in[b*n .. b*n+n) -> out exclusive
__global__ __launch_bounds__(1024) void k_scan_small(const int* __restrict__ in0, int* __restrict__ out0, int n) {
  __shared__ int sums[1024];
  const int* in = in0 + (size_t)blockIdx.x * n;
  int* out = out0 + (size_t)blockIdx.x * n;
  int t = threadIdx.x;
  int per = (n + 1023) / 1024;
  int base = t * per;
  int loc = 0;
  for (int k = 0; k < per; ++k) { int i = base + k; if (i < n) loc += in[i]; }
  sums[t] = loc; __syncthreads();
  for (int off = 1; off < 1024; off <<= 1) {
    int v = (t >= off) ? sums[t - off] : 0;
    __syncthreads();
    sums[t] += v;
    __syncthreads();
  }
  int run = (t == 0) ? 0 : sums[t - 1];
  for (int k = 0; k < per; ++k) { int i = base + k; if (i < n) { out[i] = run; run += in[i]; } }
}

__global__ __launch_bounds__(256) void k_scatter_cluster(const int* __restrict__ cid, const int* __restrict__ cstart,
                                                         int* __restrict__ ccur, int* __restrict__ cslot) {
  int n = blockIdx.x * 256 + threadIdx.x;
  if (n < N) {
    int c = cid[n];
    int p = cstart[c] + atomicAdd(&ccur[c], 1);
    cslot[p] = n;
  }
}

__global__ __launch_bounds__(128) void k_cluster_partial(const float* __restrict__ x, const int* __restrict__ cstart,
                                                         const int* __restrict__ ccount, const int* __restrict__ cslot,
                                                         float* __restrict__ Hc) {
  int c = blockIdx.x >> 5;
  int s = blockIdx.x & (CSEG - 1);
  int d = threadIdx.x;
  int st = cstart[c], cnt = ccount[c];
  int seg = (cnt + CSEG - 1) / CSEG;
  int lo = s * seg;
  int hi = min(cnt, lo + seg);
  if (lo >= hi) return;
  float acc = 0.f;
  int k = lo;
  for (; k + 2 <= hi; k += 2) {
    int n0 = cslot[st + k], n1 = cslot[st + k + 1];
    float v0 = x[(size_t)n0 * D + d];
    float v1 = x[(size_t)n1 * D + d];
    acc += v0 + v1;
  }
  if (k < hi) acc += x[(size_t)cslot[st + k] * D + d];
  atomicAdd(&Hc[(size_t)c * D + d], acc);
}

// divide Hc by counts, then gdot[c] = Hc[c] . wb  (merged, one launch)
__global__ __launch_bounds__(128) void k_mean_gdot(const int* __restrict__ ccount, const float* __restrict__ wb,
                                                   float* __restrict__ Hc, float* __restrict__ gdot) {
  __shared__ float red[128];
  int c = blockIdx.x, d = threadIdx.x;
  float hv = Hc[(size_t)c * D + d] / (float)max(ccount[c], 1);
  Hc[(size_t)c * D + d] = hv;
  red[d] = hv * wb[d];
  __syncthreads();
  if (d < 64) {
    float v = red[d] + red[d + 64];
    for (int off = 32; off; off >>= 1) v += __shfl_down(v, off);
    if (d == 0) gdot[c] = v;
  }
}

// block 0: S = sum_c Hc[c], SW = S @ tw ; blocks 1..C_: HW[b-1] = Hc[b-1] @ tw
__global__ __launch_bounds__(128) void k_S_SW_HW(const float* __restrict__ Hc, const float* __restrict__ tw,
                                                 float* __restrict__ SW, float* __restrict__ HW) {
  __shared__ float Sl[128];
  int b = blockIdx.x, t = threadIdx.x;
  if (b == 0) {
    float s = 0.f;
    for (int c = 0; c < C_; ++c) s += Hc[(size_t)c * D + t];
    Sl[t] = s;
    __syncthreads();
    float acc = 0.f;
    for (int d = 0; d < D; ++d) acc = fmaf(Sl[d], tw[(size_t)d * D + t], acc);
    SW[t] = acc;
  } else {
    const float* src = Hc + (size_t)(b - 1) * D;
    float acc = 0.f;
    for (int d = 0; d < D; ++d) acc = fmaf(src[d], tw[(size_t)d * D + t], acc);
    HW[(size_t)(b - 1) * D + t] = acc;
  }
}

// ======== fused per-node scores: MLP (feature view) + GAT h/aDot ========
__global__ __launch_bounds__(256, 4) void k_score64(const float* __restrict__ x, const float* __restrict__ w1,
                                                    const float* __restrict__ b1, const float* __restrict__ w2,
                                                    const float* __restrict__ b2, const float* __restrict__ gw,
                                                    const float* __restrict__ wa, float* __restrict__ scoreF,
                                                    float* __restrict__ hg, float* __restrict__ aDot) {
  __shared__ float xld[64 * D];  // 32 KB
  int tid = threadIdx.x;
  int base = blockIdx.x * 64;
#pragma unroll
  for (int k = 0; k < 8; ++k) {
    int i = k * 256 + tid;
    int r = i >> 5, off = i & 31;
    int n = base + r;
    float4 v = make_float4(0.f, 0.f, 0.f, 0.f);
    if (n < N) v = ((const float4*)(x + (size_t)n * D))[off];
    ((float4*)xld)[i] = v;
  }
  __syncthreads();

  int rg = tid >> 5;        // 8 row-groups of 8 rows
  int cg = tid & 31;        // 32 col-groups of 2 hid cols
  int c2 = cg * 2;
  float acc[8][2] = {};
  const float* xb = xld + rg * 8 * D;
  for (int d4 = 0; d4 < D; d4 += 4) {
    float2 wv0 = *(const float2*)(w1 + (size_t)(d4 + 0) * HID + c2);
    float2 wv1 = *(const float2*)(w1 + (size_t)(d4 + 1) * HID + c2);
    float2 wv2 = *(const float2*)(w1 + (size_t)(d4 + 2) * HID + c2);
    float2 wv3 = *(const float2*)(w1 + (size_t)(d4 + 3) * HID + c2);
#pragma unroll
    for (int r = 0; r < 8; ++r) {
      float4 xv = *(const float4*)(xb + r * D + d4);
      acc[r][0] = fmaf(xv.x, wv0.x, acc[r][0]);
      acc[r][1] = fmaf(xv.x, wv0.y, acc[r][1]);
      acc[r][0] = fmaf(xv.y, wv1.x, acc[r][0]);
      acc[r][1] = fmaf(xv.y, wv1.y, acc[r][1]);
      acc[r][0] = fmaf(xv.z, wv2.x, acc[r][0]);
      acc[r][1] = fmaf(xv.z, wv2.y, acc[r][1]);
      acc[r][0] = fmaf(xv.w, wv3.x, acc[r][0]);
      acc[r][1] = fmaf(xv.w, wv3.y, acc[r][1]);
    }
  }
  float2 b1v = *(const float2*)(b1 + c2);
  float2 w2v = *(const float2*)(w2 + c2);
  float bb = b2[0];
#pragma unroll
  for (int r = 0; r < 8; ++r) {
    float p = fmaxf(acc[r][0] + b1v.x, 0.f) * w2v.x + fmaxf(acc[r][1] + b1v.y, 0.f) * w2v.y;
#pragma unroll
    for (int off = 16; off; off >>= 1) p += __shfl_xor(p, off);
    if (cg == 0) {
      int n = base + rg * 8 + r;
      if (n < N) scoreF[n] = p + bb;
    }
  }
  float4 gwv = *(const float4*)(gw + cg * 4);
  float4 wav = *(const float4*)(wa + cg * 4);
#pragma unroll
  for (int r = 0; r < 8; ++r) {
    int row = rg * 8 + r;
    float4 xv = *(const float4*)(xld + row * D + cg * 4);
    float hp = xv.x * gwv.x + xv.y * gwv.y + xv.z * gwv.z + xv.w * gwv.w;
    float ap = xv.x * wav.x + xv.y * wav.y + xv.z * wav.z + xv.w * wav.w;
#pragma unroll
    for (int off = 16; off; off >>= 1) {
      hp += __shfl_xor(hp, off);
      ap += __shfl_xor(ap, off);
    }
    if (cg == 0) {
      int n = base + row;
      if (n < N) { hg[n] = hp; aDot[n] = ap; }
    }
  }
}

// Bucket edges by dst>>7 with LDS-aggregated reservation.
__global__ __launch_bounds__(1024) void k_escatter(const int* __restrict__ ei, const float* __restrict__ hg,
                                                   const float* __restrict__ asrc, const float* __restrict__ adst,
                                                   int* __restrict__ gcnt, uint2* __restrict__ payload) {
  __shared__ int lcnt[NBK];
  __shared__ int lbase[NBK];
  int tid = threadIdx.x;
  for (int i = tid; i < NBK; i += 1024) lcnt[i] = 0;
  int e0 = blockIdx.x * 8192;
  int es[8], ed[8];
#pragma unroll
  for (int k = 0; k < 8; ++k) {
    int e = e0 + k * 1024 + tid;
    bool v = (e < E_);
    es[k] = v ? ei[e] : -1;
    ed[k] = v ? ei[E_ + e] : -1;
  }
  __syncthreads();
#pragma unroll
  for (int k = 0; k < 8; ++k)
    if (ed[k] >= 0) atomicAdd(&lcnt[ed[k] >> 7], 1);
  __syncthreads();
  for (int i = tid; i < NBK; i += 1024) {
    int c = lcnt[i];
    lbase[i] = c ? atomicAdd(&gcnt[i], c) : 0;
    lcnt[i] = 0;
  }
  __syncthreads();
  float as = asrc[0], ad = adst[0];
#pragma unroll
  for (int k = 0; k < 8; ++k) {
    if (ed[k] < 0) continue;
    int s = es[k], d = ed[k];
    int b = d >> 7, dl = d & 127;
    float z = as * hg[s] + ad * hg[d];
    float ev = (z > 0.f) ? z : 0.2f * z;
    int pos = lbase[b] + atomicAdd(&lcnt[b], 1);
    if (pos < BCAP) {
      uint2 rec;
      rec.x = __float_as_uint(ev);
      rec.y = (unsigned)s | ((unsigned)dl << 24);
      payload[(size_t)b * BCAP + pos] = rec;
    }
  }
}

// Per-bucket GAT softmax in LDS; writes scoreL.
__global__ __launch_bounds__(256) void k_esoftmax(const uint2* __restrict__ payload, const int* __restrict__ gcnt,
                                                  const float* __restrict__ hg, const float* __restrict__ gb,
                                                  float* __restrict__ scoreL) {
  __shared__ unsigned mS[128];
  __shared__ float dS[128];
  __shared__ float nS[128];
  int b = blockIdx.x;
  int tid = threadIdx.x;
  if (tid < 128) { mS[tid] = 0u; dS[tid] = 0.f; nS[tid] = 0.f; }
  __syncthreads();
  int cnt = min(gcnt[b], BCAP);
  const uint2* bp = payload + (size_t)b * BCAP;
  for (int i = tid; i < cnt; i += 256) {
    uint2 r = bp[i];
    atomicMax(&mS[r.y >> 24], enc_f(__uint_as_float(r.x)));
  }
  __syncthreads();
  for (int i = tid; i < cnt; i += 256) {
    uint2 r = bp[i];
    int d = r.y >> 24;
    float ex = expf(__uint_as_float(r.x) - dec_f(mS[d]));
    atomicAdd(&dS[d], ex);
  }
  __syncthreads();
  for (int i = tid; i < cnt; i += 256) {
    uint2 r = bp[i];
    int d = r.y >> 24;
    float ex = expf(__uint_as_float(r.x) - dec_f(mS[d]));
    float alpha = ex / fmaxf(dS[d], 1e-16f);
    float h = hg[r.y & 0xFFFFFFu];
    atomicAdd(&nS[d], alpha * h);
  }
  __syncthreads();
  if (tid < 128) {
    int dst = b * 128 + tid;
    if (dst < N) scoreL[dst] = nS[tid] + gb[0];
  }
}

// ========== exact top-k ranking, both views per launch (blockIdx.y) ==========
// mm layout: [maxF, maxL, minF, minL]
__global__ __launch_bounds__(256) void k_minmax2(const float* __restrict__ sc2, unsigned* __restrict__ mm) {
  __shared__ unsigned smx[256], smn[256];
  int v = blockIdx.y;
  const float* sc = sc2 + (size_t)v * N;
  int t = threadIdx.x; int n = blockIdx.x * 256 + t;
  unsigned val = (n < N) ? enc_f(sc[n]) : 0u;
  smx[t] = (n < N) ? val : 0u;
  smn[t] = (n < N) ? val : 0xFFFFFFFFu;
  __syncthreads();
  for (int off = 128; off; off >>= 1) {
    if (t < off) {
      smx[t] = max(smx[t], smx[t + off]);
      smn[t] = min(smn[t], smn[t + off]);
    }
    __syncthreads();
  }
  if (t == 0) { atomicMax(&mm[v], smx[0]); atomicMin(&mm[2 + v], smn[0]); }
}

__global__ __launch_bounds__(256) void k_bucket_hist2(const float* __restrict__ sc2, const unsigned* __restrict__ mm,
                                                      int* __restrict__ bucket2, int* __restrict__ hist2) {
  int v = blockIdx.y;
  int n = blockIdx.x * 256 + threadIdx.x;
  if (n >= N) return;
  const float* sc = sc2 + (size_t)v * N;
  float smax = dec_f(mm[v]), smin = dec_f(mm[2 + v]);
  float range = smax - smin;
  float scale = (range > 0.f) ? ((float)NB / range) : 0.f;
  float t = (smax - sc[n]) * scale;
  int b = (int)t;
  b = b < 0 ? 0 : (b > NB - 1 ? NB - 1 : b);
  bucket2[(size_t)v * N + n] = b;
  atomicAdd(&hist2[v * NB + b], 1);
}

__global__ __launch_bounds__(256) void k_bucket_scatter2(const int* __restrict__ bucket2, const int* __restrict__ start2,
                                                         int* __restrict__ cur2, int* __restrict__ slot2) {
  int v = blockIdx.y;
  int n = blockIdx.x * 256 + threadIdx.x;
  if (n >= N) return;
  int b = bucket2[(size_t)v * N + n];
  slot2[(size_t)v * N + start2[v * NB + b] + atomicAdd(&cur2[v * NB + b], 1)] = n;
}

// Bucket-centric exact ranking: one wave per bucket, keys staged in LDS once.
__global__ __launch_bounds__(64) void k_bucket_rank3(const float* __restrict__ sc2, const int* __restrict__ start2,
                                                     const int* __restrict__ hist2, const int* __restrict__ slot2,
                                                     int* __restrict__ rank2, int* __restrict__ sorted2) {
  __shared__ unsigned long long keys[RMAX];
  int v = blockIdx.y;
  int b = blockIdx.x;
  int st = start2[v * NB + b], cnt = hist2[v * NB + b];
  if (cnt == 0) return;
  const float* sc = sc2 + (size_t)v * N;
  const int* slot = slot2 + (size_t)v * N;
  int* rank = rank2 + (size_t)v * N;
  int* sorted = sorted2 + (size_t)v * N;
  int tid = threadIdx.x;
  if (cnt <= RMAX) {
    for (int i = tid; i < cnt; i += 64) {
      int m = slot[st + i];
      keys[i] = (((unsigned long long)(~enc_f(sc[m]))) << 32) | (unsigned)m;
    }
    __syncthreads();
    for (int i = tid; i < cnt; i += 64) {
      unsigned long long mykey = keys[i];
      int r = 0;
      for (int j = 0; j < cnt; ++j) r += (keys[j] < mykey) ? 1 : 0;
      int m = (int)(mykey & 0xFFFFFFFFu);
      rank[m] = st + r;
      sorted[st + r] = m;
    }
  } else {  // degenerate-distribution fallback
    for (int i = tid; i < cnt; i += 64) {
      int m = slot[st + i];
      unsigned long long mykey = (((unsigned long long)(~enc_f(sc[m]))) << 32) | (unsigned)m;
      int r = 0;
      for (int j = 0; j < cnt; ++j) {
        int mj = slot[st + j];
        unsigned long long k = (((unsigned long long)(~enc_f(sc[mj]))) << 32) | (unsigned)mj;
        r += (k < mykey) ? 1 : 0;
      }
      rank[m] = st + r;
      sorted[st + r] = m;
    }
  }
}

// ======================= union mapping =======================
__global__ __launch_bounds__(1024) void k_union_chunksum(const int* __restrict__ rankF, const int* __restrict__ rankL,
                                                         int* __restrict__ csum) {
  __shared__ int red[1024];
  int t = threadIdx.x; int i = blockIdx.x * 1024 + t;
  int u = (i < N) ? (((rankF[i] < KSEL) || (rankL[i] < KSEL)) ? 1 : 0) : 0;
  red[t] = u; __syncthreads();
  for (int off = 512; off; off >>= 1) { if (t < off) red[t] += red[t + off]; __syncthreads(); }
  if (t == 0) csum[blockIdx.x] = red[0];
}

__global__ __launch_bounds__(1024) void k_union_map(const int* __restrict__ rankF, const int* __restrict__ rankL,
                                                    const int* __restrict__ cstart, const int* __restrict__ batch,
                                                    int* __restrict__ mapping, float* __restrict__ outBatch) {
  __shared__ int sums[1024];
  int t = threadIdx.x; int i = blockIdx.x * 1024 + t;
  int u = (i < N) ? (((rankF[i] < KSEL) || (rankL[i] < KSEL)) ? 1 : 0) : 0;
  sums[t] = u; __syncthreads();
  for (int off = 1; off < 1024; off <<= 1) {
    int v = (t >= off) ? sums[t - off] : 0;
    __syncthreads();
    sums[t] += v;
    __syncthreads();
  }
  if (i < N) {
    mapping[i] = u ? (cstart[blockIdx.x] + sums[t] - 1) : -1;
    outBatch[i] = u ? (float)batch[i] : -1.0f;
  }
}

__global__ __launch_bounds__(256) void k_edge_out(const int* __restrict__ ei, const int* __restrict__ mapping,
                                                  float* __restrict__ outE) {
  int e = blockIdx.x * 256 + threadIdx.x;
  if (e >= E_) return;
  int m0 = mapping[ei[e]], m1 = mapping[ei[E_ + e]];
  bool valid = (m0 >= 0) && (m1 >= 0);
  outE[e] = valid ? (float)m0 : -1.f;
  outE[E_ + e] = valid ? (float)m1 : -1.f;
}

// zero Fp rows outside the union (replaces the 51 MB full-output memset)
__global__ __launch_bounds__(256) void k_zero_rows(const int* __restrict__ mapping, float* __restrict__ Fp) {
  int i = blockIdx.x * 256 + threadIdx.x;  // over N*32 float4s
  int n = i >> 5;
  if (n < N && mapping[n] < 0) ((float4*)Fp)[i] = make_float4(0.f, 0.f, 0.f, 0.f);
}

// ======================= fused GCN transform + scatter =======================
// Fp[tgtL[i]] (+)= relu( x[srcL[i]] @ tw + tb + q*SW + (p-q)*HW[cid[srcL[i]]] )
// 256 threads, 64 rows/block, 8x4 tile (2-way LDS aliasing = free; the 8x8/128t
// variant hit 4-way conflicts at stride 4096 and halved occupancy -> regressed).
// tw double-buffered: next d4's 4 float4s prefetched before the 128-FMA block.
// accum launch: accumulate+halve only where tgt is in the feat set (launch 1
// wrote it); else pure store -> no Fp pre-zeroing needed for union rows.
__global__ __launch_bounds__(256, 4) void k_fuse64(const float* __restrict__ x, const float* __restrict__ tw,
                                                   const float* __restrict__ tb, const float* __restrict__ SW,
                                                   const float* __restrict__ HW, const float* __restrict__ gdot,
                                                   const float* __restrict__ aDot, const int* __restrict__ cid,
                                                   const int* __restrict__ srcL, const int* __restrict__ tgtL,
                                                   const float* __restrict__ attb, const int* __restrict__ rankF,
                                                   float* __restrict__ Fp, int accum) {
  __shared__ float xld[64 * D];   // 32 KB
  __shared__ float pq[64 * 2];
  __shared__ int mt[64 * 2];
  __shared__ int ft[64];
  int tid = threadIdx.x;
  int base = blockIdx.x * 64;
  if (tid < 64) {
    int ws = srcL[base + tid];
    int cc = cid[ws];
    int tg = tgtL[base + tid];
    mt[tid * 2] = cc;
    mt[tid * 2 + 1] = tg;
    ft[tid] = (rankF[tg] < KSEL) ? 1 : 0;
    float s = aDot[ws] + gdot[cc] + attb[0];
    float mx = fmaxf(s, 0.f);
    float esm = expf(s - mx), eom = expf(-mx);
    float dn = esm + 255.f * eom;
    pq[tid * 2] = esm / dn;
    pq[tid * 2 + 1] = eom / dn;
  }
  // stage 64 x-rows (2048 float4, 8 per thread)
#pragma unroll
  for (int k = 0; k < 8; ++k) {
    int i = k * 256 + tid;
    int r = i >> 5, off = i & 31;
    int ws = srcL[base + r];
    ((float4*)xld)[i] = ((const float4*)(x + (size_t)ws * D))[off];
  }
  __syncthreads();

  int rg = tid >> 5;        // 8 row-groups of 8 rows (2 per wave -> free 2-way)
  int c4 = (tid & 31) * 4;  // 32 col-groups of 4 cols
  float acc[8][4] = {};
  const float* xb = xld + rg * 8 * D;
  float4 t0 = *(const float4*)(tw + (size_t)0 * D + c4);
  float4 t1 = *(const float4*)(tw + (size_t)1 * D + c4);
  float4 t2 = *(const float4*)(tw + (size_t)2 * D + c4);
  float4 t3 = *(const float4*)(tw + (size_t)3 * D + c4);
  for (int d4 = 0; d4 < D; d4 += 4) {
    float4 u0, u1, u2, u3;
    if (d4 + 4 < D) {  // prefetch next tw slab: ~256 VALU cyc load->use distance
      u0 = *(const float4*)(tw + (size_t)(d4 + 4) * D + c4);
      u1 = *(const float4*)(tw + (size_t)(d4 + 5) * D + c4);
      u2 = *(const float4*)(tw + (size_t)(d4 + 6) * D + c4);
      u3 = *(const float4*)(tw + (size_t)(d4 + 7) * D + c4);
    } else {
      u0 = u1 = u2 = u3 = make_float4(0.f, 0.f, 0.f, 0.f);
    }
#pragma unroll
    for (int r = 0; r < 8; ++r) {
      float4 xv = *(const float4*)(xb + r * D + d4);
      acc[r][0] = fmaf(xv.x, t0.x, acc[r][0]);
      acc[r][1] = fmaf(xv.x, t0.y, acc[r][1]);
      acc[r][2] = fmaf(xv.x, t0.z, acc[r][2]);
      acc[r][3] = fmaf(xv.x, t0.w, acc[r][3]);
      acc[r][0] = fmaf(xv.y, t1.x, acc[r][0]);
      acc[r][1] = fmaf(xv.y, t1.y, acc[r][1]);
      acc[r][2] = fmaf(xv.y, t1.z, acc[r][2]);
      acc[r][3] = fmaf(xv.y, t1.w, acc[r][3]);
      acc[r][0] = fmaf(xv.z, t2.x, acc[r][0]);
      acc[r][1] = fmaf(xv.z, t2.y, acc[r][1]);
      acc[r][2] = fmaf(xv.z, t2.z, acc[r][2]);
      acc[r][3] = fmaf(xv.z, t2.w, acc[r][3]);
      acc[r][0] = fmaf(xv.w, t3.x, acc[r][0]);
      acc[r][1] = fmaf(xv.w, t3.y, acc[r][1]);
      acc[r][2] = fmaf(xv.w, t3.z, acc[r][2]);
      acc[r][3] = fmaf(xv.w, t3.w, acc[r][3]);
    }
    t0 = u0; t1 = u1; t2 = u2; t3 = u3;
  }

  float4 tbv = *(const float4*)(tb + c4);
  float4 swv = *(const float4*)(SW + c4);
#pragma unroll
  for (int r = 0; r < 8; ++r) {
    int row = rg * 8 + r;
    float p = pq[row * 2], q = pq[row * 2 + 1];
    int cc = mt[row * 2];
    int tgt = mt[row * 2 + 1];
    float4 hw = *(const float4*)(HW + (size_t)cc * D + c4);
    float4 o;
    o.x = fmaxf(acc[r][0] + tbv.x + q * swv.x + (p - q) * hw.x, 0.f);
    o.y = fmaxf(acc[r][1] + tbv.y + q * swv.y + (p - q) * hw.y, 0.f);
    o.z = fmaxf(acc[r][2] + tbv.z + q * swv.z + (p - q) * hw.z, 0.f);
    o.w = fmaxf(acc[r][3] + tbv.w + q * swv.w + (p - q) * hw.w, 0.f);
    float4* dst = (float4*)(Fp + (size_t)tgt * D + c4);
    if (accum && ft[row]) {
      float4 old = *dst;
      o.x = (o.x + old.x) * 0.5f;
      o.y = (o.y + old.y) * 0.5f;
      o.z = (o.z + old.z) * 0.5f;
      o.w = (o.w + old.w) * 0.5f;
    }
    *dst = o;
  }
}

// ======================= launcher =======================
extern "C" void kernel_launch(void* const* d_in, const int* in_sizes, int n_in,
                              void* d_out, int out_size, void* d_ws, size_t ws_size,
                              hipStream_t stream) {
  const float* x   = (const float*)d_in[0];
  const int* ei    = (const int*)d_in[1];
  const int* batch = (const int*)d_in[2];
  const int* cid   = (const int*)d_in[3];
  const float* w1  = (const float*)d_in[4];
  const float* b1  = (const float*)d_in[5];
  const float* w2  = (const float*)d_in[6];
  const float* b2  = (const float*)d_in[7];
  const float* gw  = (const float*)d_in[8];
  const float* gas = (const float*)d_in[9];
  const float* gad = (const float*)d_in[10];
  const float* gb  = (const float*)d_in[11];
  const float* wa  = (const float*)d_in[12];
  const float* wb  = (const float*)d_in[13];
  const float* ab  = (const float*)d_in[14];
  const float* tw  = (const float*)d_in[15];
  const float* tb  = (const float*)d_in[16];
  (void)in_sizes; (void)n_in; (void)ws_size; (void)out_size;

  char* p = (char*)d_ws;
  auto alloc = [&](size_t bytes) -> char* {
    char* r = p;
    p += (bytes + 255) & ~(size_t)255;
    return r;
  };
  // ---- zero-init region ----
  int* ccount    = (int*)alloc(C_ * 4);
  int* ccur      = (int*)alloc(C_ * 4);
  unsigned* mm   = (unsigned*)alloc(16);                // [maxF,maxL,minF,minL]
  int* hist2     = (int*)alloc(2 * NB * 4);
  int* cur2      = (int*)alloc(2 * NB * 4);
  float* Hc      = (float*)alloc((size_t)C_ * D * 4);   // atomic accumulator
  int* gcnt      = (int*)alloc(NBK * 4);
  size_t zeroBytes = (size_t)(p - (char*)d_ws);
  // ---- rest (fully written before read) ----
  int* cstart   = (int*)alloc(C_ * 4);
  int* cslot    = (int*)alloc((size_t)N * 4);
  float* gdot   = (float*)alloc(C_ * 4);
  float* SW     = (float*)alloc(D * 4);
  float* HW     = (float*)alloc((size_t)C_ * D * 4);
  float* score2 = (float*)alloc((size_t)2 * N * 4);     // [scoreF | scoreL]
  float* hg     = (float*)alloc((size_t)N * 4);
  float* aDot   = (float*)alloc((size_t)N * 4);
  uint2* payload = (uint2*)alloc((size_t)NBK * BCAP * 8);
  int* bucket2  = (int*)alloc((size_t)2 * N * 4);
  int* start2   = (int*)alloc(2 * NB * 4);
  int* slot2    = (int*)alloc((size_t)2 * N * 4);
  int* sorted2  = (int*)alloc((size_t)2 * N * 4);
  int* rank2    = (int*)alloc((size_t)2 * N * 4);
  int* csums    = (int*)alloc(NCHUNK * 4);
  int* cstarts  = (int*)alloc(NCHUNK * 4);
  int* mapping  = (int*)alloc((size_t)N * 4);

  float* scoreF = score2;
  float* scoreL = score2 + N;
  int* sortedF  = sorted2;
  int* sortedL  = sorted2 + N;
  int* rankF    = rank2;
  int* rankL    = rank2 + N;

  float* outF = (float*)d_out;             // [N, D]
  float* outE = outF + (size_t)N * D;      // [2, E]  (fully written by k_edge_out)
  float* outB = outE + (size_t)2 * E_;     // [N]     (fully written by k_union_map)

  hipMemsetAsync(d_ws, 0, zeroBytes, stream);
  hipMemsetAsync(mm + 2, 0xFF, 8, stream);              // minF,minL -> 0xFFFFFFFF
  // outF: union rows fully written by the two fuse launches (store / cond-accum);
  // non-union rows zeroed by k_zero_rows -> no 51 MB memset.

  // cluster means + derived
  k_hist_cluster<<<(N + 255) / 256, 256, 0, stream>>>(cid, ccount);
  k_scan_small<<<1, 1024, 0, stream>>>(ccount, cstart, C_);
  k_scatter_cluster<<<(N + 255) / 256, 256, 0, stream>>>(cid, cstart, ccur, cslot);
  k_cluster_partial<<<C_ * CSEG, 128, 0, stream>>>(x, cstart, ccount, cslot, Hc);
  k_mean_gdot<<<C_, 128, 0, stream>>>(ccount, wb, Hc, gdot);
  k_S_SW_HW<<<C_ + 1, 128, 0, stream>>>(Hc, tw, SW, HW);

  // fused per-node scores (MLP + GAT projections) + edge softmax
  k_score64<<<(N + 63) / 64, 256, 0, stream>>>(x, w1, b1, w2, b2, gw, wa, scoreF, hg, aDot);
  k_escatter<<<(E_ + 8191) / 8192, 1024, 0, stream>>>(ei, hg, gas, gad, gcnt, payload);
  k_esoftmax<<<NBK, 256, 0, stream>>>(payload, gcnt, hg, gb, scoreL);

  // exact ranking, both views per launch
  dim3 g2((N + 255) / 256, 2);
  k_minmax2<<<g2, 256, 0, stream>>>(score2, mm);
  k_bucket_hist2<<<g2, 256, 0, stream>>>(score2, mm, bucket2, hist2);
  k_scan_small<<<2, 1024, 0, stream>>>(hist2, start2, NB);
  k_bucket_scatter2<<<g2, 256, 0, stream>>>(bucket2, start2, cur2, slot2);
  dim3 gr(NB, 2);
  k_bucket_rank3<<<gr, 64, 0, stream>>>(score2, start2, hist2, slot2, rank2, sorted2);

  // union mapping + edge remap + batch + zero non-union rows
  k_union_chunksum<<<NCHUNK, 1024, 0, stream>>>(rankF, rankL, csums);
  k_scan_small<<<1, 1024, 0, stream>>>(csums, cstarts, NCHUNK);
  k_union_map<<<NCHUNK, 1024, 0, stream>>>(rankF, rankL, cstarts, batch, mapping, outB);
  k_edge_out<<<(E_ + 255) / 256, 256, 0, stream>>>(ei, mapping, outE);
  k_zero_rows<<<(N * 32 + 255) / 256, 256, 0, stream>>>(mapping, outF);

  // fused features: launch 1 pure-stores (feat rows); launch 2 stores or
  // accumulates+halves (local rows) depending on feat membership.
  k_fuse64<<<KSEL / 64, 256, 0, stream>>>(x, tw, tb, SW, HW, gdot, aDot, cid, sortedL, sortedF, ab, rankF, outF, 0);
  k_fuse64<<<KSEL / 64, 256, 0, stream>>>(x, tw, tb, SW, HW, gdot, aDot, cid, sortedF, sortedL, ab, rankF, outF, 1);
}